// Round 5
// baseline (3014.499 us; speedup 1.0000x reference)
//
#include <hip/hip_runtime.h>

#define NN 50000
#define NE 800000
#define OUTC 176  // 11 * 16

typedef unsigned int uint32;

// ---------- bf16 helpers (manual, RNE) ----------
__device__ __forceinline__ uint32 f2bf_rne(float f) {
  union { float f; uint32 u; } v; v.f = f;
  uint32 u = v.u;
  return (u + 0x7FFFu + ((u >> 16) & 1u)) >> 16;
}
__device__ __forceinline__ uint32 packbf2(float a, float b) {
  return f2bf_rne(a) | (f2bf_rne(b) << 16);
}
__device__ __forceinline__ float blo(uint32 u) {
  union { uint32 x; float f; } t; t.x = u << 16; return t.f;
}
__device__ __forceinline__ float bhi(uint32 u) {
  union { uint32 x; float f; } t; t.x = u & 0xFFFF0000u; return t.f;
}
__device__ __forceinline__ float bf2f(unsigned short v) {
  union { uint32 x; float f; } t; t.x = ((uint32)v) << 16; return t.f;
}
// signed byte b (0..3) of packed word -> float
__device__ __forceinline__ float sb2f(uint32 w, int b) {
  return (float)((int)(w << (24 - 8 * b)) >> 24);
}

// ---------- small kernels ----------
__global__ __launch_bounds__(256) void deg_count_kernel(const int* __restrict__ edst,
                                                        float* __restrict__ deg) {
  int e = blockIdx.x * 256 + threadIdx.x;
  if (e < NE) atomicAdd(&deg[edst[e]], 1.0f);
}

__global__ __launch_bounds__(256) void deg_inv_kernel(float* __restrict__ deg) {
  int n = blockIdx.x * 256 + threadIdx.x;
  if (n < NN) deg[n] = 1.0f / fmaxf(deg[n], 1.0f);
}

__global__ __launch_bounds__(256) void copy_col0_kernel(const float* __restrict__ hx,
                                                        float* __restrict__ out) {
  int n = blockIdx.x * 256 + threadIdx.x;
  if (n >= NN) return;
  const float4* s = reinterpret_cast<const float4*>(hx + (size_t)n * 16);
  float4* d = reinterpret_cast<float4*>(out + (size_t)n * OUTC);
  d[0] = s[0]; d[1] = s[1]; d[2] = s[2]; d[3] = s[3];
}

// ---------- filter-generating network ----------
// W[e,c,d] = w_flat[e, c*16+d]; stored d-major: row(e,d) = {W[e,c,d]}_c contiguous.
__device__ __forceinline__ void fnet_layer1(const float* __restrict__ ef, long long e,
                                            const float* __restrict__ w1,
                                            const float* __restrict__ b1,
                                            float* u) {
  float f[13];
#pragma unroll
  for (int i = 0; i < 13; ++i) f[i] = ef[(size_t)e * 13 + i];
#pragma unroll
  for (int k = 0; k < 64; ++k) u[k] = b1[k];
#pragma unroll
  for (int i = 0; i < 13; ++i) {
    float fi = f[i];
#pragma unroll
    for (int k = 0; k < 64; ++k) u[k] = fmaf(fi, w1[i * 64 + k], u[k]);
  }
#pragma unroll
  for (int k = 0; k < 64; ++k) u[k] = fmaxf(u[k], 0.0f);
}

__global__ __launch_bounds__(256) void fnet_bf16_kernel(
    const float* __restrict__ ef, const float* __restrict__ w1, const float* __restrict__ b1,
    const float* __restrict__ w2, const float* __restrict__ b2,
    unsigned short* __restrict__ W, long long ebase, int ecnt) {
  int t = blockIdx.x * 256 + threadIdx.x;
  if (t >= ecnt) return;
  float u[64];
  fnet_layer1(ef, ebase + t, w1, b1, u);
  // two d's per tile -> 2 rows x 32B = 64B burst store (full sectors, no RMW)
  for (int dt = 0; dt < 8; ++dt) {
    uint32 p[16];
#pragma unroll
    for (int dd = 0; dd < 2; ++dd) {
      int d = dt * 2 + dd;
      float acc[16];
#pragma unroll
      for (int c = 0; c < 16; ++c) acc[c] = b2[c * 16 + d];
#pragma unroll 8
      for (int k = 0; k < 64; ++k) {
        float uk = u[k];
#pragma unroll
        for (int c = 0; c < 16; ++c) acc[c] = fmaf(uk, w2[k * 256 + c * 16 + d], acc[c]);
      }
#pragma unroll
      for (int q = 0; q < 8; ++q) p[dd * 8 + q] = packbf2(acc[2 * q], acc[2 * q + 1]);
    }
    uint4* dp = reinterpret_cast<uint4*>(W + ((size_t)t << 8) + (dt << 5));
    dp[0] = make_uint4(p[0], p[1], p[2], p[3]);
    dp[1] = make_uint4(p[4], p[5], p[6], p[7]);
    dp[2] = make_uint4(p[8], p[9], p[10], p[11]);
    dp[3] = make_uint4(p[12], p[13], p[14], p[15]);
  }
}

// int8 with per-(e,d)-row bf16 scale: q = clamp(rint(W/s'),-127,127), s' = bf16(rowmax/127).
// d processed in tiles of 4 -> 4 rows x 16B = 64B contiguous burst store; scales
// buffered in regs and written as one 32B burst (avoids partial-line RMW traffic).
__global__ __launch_bounds__(256) void fnet_i8_kernel(
    const float* __restrict__ ef, const float* __restrict__ w1, const float* __restrict__ b1,
    const float* __restrict__ w2, const float* __restrict__ b2,
    unsigned char* __restrict__ W, unsigned short* __restrict__ S) {
  int t = blockIdx.x * 256 + threadIdx.x;
  if (t >= NE) return;
  float u[64];
  fnet_layer1(ef, t, w1, b1, u);
  uint32 scw[8];
  for (int dt = 0; dt < 4; ++dt) {
    uint32 p[16];
#pragma unroll
    for (int dd = 0; dd < 4; ++dd) {
      int d = dt * 4 + dd;
      float acc[16];
#pragma unroll
      for (int c = 0; c < 16; ++c) acc[c] = b2[c * 16 + d];
#pragma unroll 8
      for (int k = 0; k < 64; ++k) {
        float uk = u[k];
#pragma unroll
        for (int c = 0; c < 16; ++c) acc[c] = fmaf(uk, w2[k * 256 + c * 16 + d], acc[c]);
      }
      float m = 0.0f;
#pragma unroll
      for (int c = 0; c < 16; ++c) m = fmaxf(m, fabsf(acc[c]));
      uint32 sbits = f2bf_rne(m * (1.0f / 127.0f));
      if (d & 1) scw[d >> 1] |= sbits << 16;
      else       scw[d >> 1] = sbits;
      float sdec = bf2f((unsigned short)sbits);
      float inv = (sdec > 0.0f) ? (1.0f / sdec) : 0.0f;
#pragma unroll
      for (int q = 0; q < 4; ++q) {
        uint32 w = 0;
#pragma unroll
        for (int b = 0; b < 4; ++b) {
          float qf = fminf(127.0f, fmaxf(-127.0f, rintf(acc[q * 4 + b] * inv)));
          w |= ((uint32)((int)qf & 255)) << (8 * b);
        }
        p[dd * 4 + q] = w;
      }
    }
    uint4* dp = reinterpret_cast<uint4*>(W + ((size_t)t << 8) + (dt << 6));
    dp[0] = make_uint4(p[0], p[1], p[2], p[3]);
    dp[1] = make_uint4(p[4], p[5], p[6], p[7]);
    dp[2] = make_uint4(p[8], p[9], p[10], p[11]);
    dp[3] = make_uint4(p[12], p[13], p[14], p[15]);
  }
  uint4* sp = reinterpret_cast<uint4*>(S + (size_t)t * 16);
  sp[0] = make_uint4(scw[0], scw[1], scw[2], scw[3]);
  sp[1] = make_uint4(scw[4], scw[5], scw[6], scw[7]);
}

// ---------- gconv message + aggregate ----------
// 16 lanes (d) per strip of 16 consecutive edges; sorted edge_dst -> register run
// accumulation, flush via atomicAdd on dst change.
__global__ __launch_bounds__(256) void msg_bf16_kernel(
    const float* __restrict__ h, int h_ld,
    const unsigned short* __restrict__ W, long long ebase, int ecnt,
    const int* __restrict__ idxn, const int* __restrict__ edst,
    float* __restrict__ agg) {
  int t = blockIdx.x * 256 + threadIdx.x;
  if (t >= ecnt) return;
  int g = t >> 4, d = t & 15;
  int cur = -1;
  float acc = 0.0f;
  for (int s = 0; s < 16; ++s) {
    int erel = g * 16 + s;
    long long e = ebase + erel;
    int dst = edst[e];
    if (dst != cur) {
      if (cur >= 0) atomicAdd(&agg[(size_t)cur * 16 + d], acc);
      cur = dst; acc = 0.0f;
    }
    int src = idxn[e];
    const float4* hp = reinterpret_cast<const float4*>(h + (size_t)src * h_ld);
    float4 a0 = hp[0], a1 = hp[1], a2 = hp[2], a3 = hp[3];
    const uint4* wp = reinterpret_cast<const uint4*>(W + ((size_t)erel << 8) + (d << 4));
    uint4 w0 = wp[0], w1 = wp[1];
    acc = fmaf(a0.x, blo(w0.x), acc); acc = fmaf(a0.y, bhi(w0.x), acc);
    acc = fmaf(a0.z, blo(w0.y), acc); acc = fmaf(a0.w, bhi(w0.y), acc);
    acc = fmaf(a1.x, blo(w0.z), acc); acc = fmaf(a1.y, bhi(w0.z), acc);
    acc = fmaf(a1.z, blo(w0.w), acc); acc = fmaf(a1.w, bhi(w0.w), acc);
    acc = fmaf(a2.x, blo(w1.x), acc); acc = fmaf(a2.y, bhi(w1.x), acc);
    acc = fmaf(a2.z, blo(w1.y), acc); acc = fmaf(a2.w, bhi(w1.y), acc);
    acc = fmaf(a3.x, blo(w1.z), acc); acc = fmaf(a3.y, bhi(w1.z), acc);
    acc = fmaf(a3.z, blo(w1.w), acc); acc = fmaf(a3.w, bhi(w1.w), acc);
  }
  if (cur >= 0) atomicAdd(&agg[(size_t)cur * 16 + d], acc);
}

__global__ __launch_bounds__(256) void msg_i8_kernel(
    const float* __restrict__ h, int h_ld,
    const unsigned char* __restrict__ W, const unsigned short* __restrict__ S,
    const int* __restrict__ idxn, const int* __restrict__ edst,
    float* __restrict__ agg) {
  int t = blockIdx.x * 256 + threadIdx.x;
  if (t >= NE) return;
  int g = t >> 4, d = t & 15;
  int cur = -1;
  float acc = 0.0f;
  for (int s = 0; s < 16; ++s) {
    int e = g * 16 + s;
    int dst = edst[e];
    if (dst != cur) {
      if (cur >= 0) atomicAdd(&agg[(size_t)cur * 16 + d], acc);
      cur = dst; acc = 0.0f;
    }
    int src = idxn[e];
    const float4* hp = reinterpret_cast<const float4*>(h + (size_t)src * h_ld);
    float4 a0 = hp[0], a1 = hp[1], a2 = hp[2], a3 = hp[3];
    uint4 wv = *reinterpret_cast<const uint4*>(W + ((size_t)e << 8) + (d << 4));
    float sc = bf2f(S[(size_t)e * 16 + d]);
    float r = 0.0f;
    r = fmaf(a0.x, sb2f(wv.x, 0), r); r = fmaf(a0.y, sb2f(wv.x, 1), r);
    r = fmaf(a0.z, sb2f(wv.x, 2), r); r = fmaf(a0.w, sb2f(wv.x, 3), r);
    r = fmaf(a1.x, sb2f(wv.y, 0), r); r = fmaf(a1.y, sb2f(wv.y, 1), r);
    r = fmaf(a1.z, sb2f(wv.y, 2), r); r = fmaf(a1.w, sb2f(wv.y, 3), r);
    r = fmaf(a2.x, sb2f(wv.z, 0), r); r = fmaf(a2.y, sb2f(wv.z, 1), r);
    r = fmaf(a2.z, sb2f(wv.z, 2), r); r = fmaf(a2.w, sb2f(wv.z, 3), r);
    r = fmaf(a3.x, sb2f(wv.w, 0), r); r = fmaf(a3.y, sb2f(wv.w, 1), r);
    r = fmaf(a3.z, sb2f(wv.w, 2), r); r = fmaf(a3.w, sb2f(wv.w, 3), r);
    acc = fmaf(r, sc, acc);
  }
  if (cur >= 0) atomicAdd(&agg[(size_t)cur * 16 + d], acc);
}

// ---------- fused degree-normalize + GRU cell + optional skip-add ----------
// hout/sprev may alias (col10 stash) -> no __restrict__, sprev read before hout write.
__global__ __launch_bounds__(256) void cell_kernel(
    const float* __restrict__ agg, const float* __restrict__ invd,
    const float* __restrict__ hin, int hin_ld,
    const float* __restrict__ wih, const float* __restrict__ whh,
    const float* __restrict__ bih, const float* __restrict__ bhh,
    float* hout, int hout_ld,
    const float* sprev, int sprev_ld,
    float* sout, int sout_ld) {
  int n = blockIdx.x * 256 + threadIdx.x;
  if (n >= NN) return;
  float x[16], h[16];
  float inv = invd[n];
  const float4* ap = reinterpret_cast<const float4*>(agg + (size_t)n * 16);
  const float4* hp = reinterpret_cast<const float4*>(hin + (size_t)n * hin_ld);
#pragma unroll
  for (int q = 0; q < 4; ++q) {
    float4 a = ap[q];
    x[4 * q + 0] = a.x * inv; x[4 * q + 1] = a.y * inv;
    x[4 * q + 2] = a.z * inv; x[4 * q + 3] = a.w * inv;
    float4 hv = hp[q];
    h[4 * q + 0] = hv.x; h[4 * q + 1] = hv.y; h[4 * q + 2] = hv.z; h[4 * q + 3] = hv.w;
  }
  float r[16], z[16], nn[16];
#pragma unroll
  for (int j = 0; j < 16; ++j) {
    float gi = bih[j], gh = bhh[j];
#pragma unroll
    for (int c = 0; c < 16; ++c) {
      gi = fmaf(x[c], wih[j * 16 + c], gi);
      gh = fmaf(h[c], whh[j * 16 + c], gh);
    }
    r[j] = 1.0f / (1.0f + expf(-(gi + gh)));
  }
#pragma unroll
  for (int j = 0; j < 16; ++j) {
    float gi = bih[16 + j], gh = bhh[16 + j];
#pragma unroll
    for (int c = 0; c < 16; ++c) {
      gi = fmaf(x[c], wih[(16 + j) * 16 + c], gi);
      gh = fmaf(h[c], whh[(16 + j) * 16 + c], gh);
    }
    z[j] = 1.0f / (1.0f + expf(-(gi + gh)));
  }
#pragma unroll
  for (int j = 0; j < 16; ++j) {
    float gi = bih[32 + j], gh = bhh[32 + j];
#pragma unroll
    for (int c = 0; c < 16; ++c) {
      gi = fmaf(x[c], wih[(32 + j) * 16 + c], gi);
      gh = fmaf(h[c], whh[(32 + j) * 16 + c], gh);
    }
    nn[j] = tanhf(gi + r[j] * gh);
  }
  float hv[16];
#pragma unroll
  for (int j = 0; j < 16; ++j) hv[j] = (1.0f - z[j]) * nn[j] + z[j] * h[j];

  float sv[16];
  bool do_s = (sprev != nullptr);
  if (do_s) {
    const float4* pp = reinterpret_cast<const float4*>(sprev + (size_t)n * sprev_ld);
#pragma unroll
    for (int q = 0; q < 4; ++q) {
      float4 p = pp[q];
      sv[4 * q + 0] = hv[4 * q + 0] + p.x; sv[4 * q + 1] = hv[4 * q + 1] + p.y;
      sv[4 * q + 2] = hv[4 * q + 2] + p.z; sv[4 * q + 3] = hv[4 * q + 3] + p.w;
    }
  }
  float4* hop = reinterpret_cast<float4*>(hout + (size_t)n * hout_ld);
#pragma unroll
  for (int q = 0; q < 4; ++q)
    hop[q] = make_float4(hv[4 * q], hv[4 * q + 1], hv[4 * q + 2], hv[4 * q + 3]);
  if (do_s) {
    float4* sp = reinterpret_cast<float4*>(sout + (size_t)n * sout_ld);
#pragma unroll
    for (int q = 0; q < 4; ++q)
      sp[q] = make_float4(sv[4 * q], sv[4 * q + 1], sv[4 * q + 2], sv[4 * q + 3]);
  }
}

extern "C" void kernel_launch(void* const* d_in, const int* in_sizes, int n_in,
                              void* d_out, int out_size, void* d_ws, size_t ws_size,
                              hipStream_t stream) {
  const float* hx   = (const float*)d_in[0];
  const float* ef   = (const float*)d_in[1];
  const int*   idxn = (const int*)d_in[2];
  const int*   edst = (const int*)d_in[3];
  const float* w1   = (const float*)d_in[4];
  const float* b1   = (const float*)d_in[5];
  const float* w2   = (const float*)d_in[6];
  const float* b2   = (const float*)d_in[7];
  const float* wih  = (const float*)d_in[8];
  const float* whh  = (const float*)d_in[9];
  const float* bih  = (const float*)d_in[10];
  const float* bhh  = (const float*)d_in[11];
  float* out = (float*)d_out;

  // workspace: invd [NN f32] | agg [NN*16 f32] | W (+ scales for int8 plan)
  const size_t INV_OFF = 0;
  const size_t AGG_OFF = 200064;              // NN*4 rounded up to 64
  const size_t W_OFF   = 3400192;             // AGG end rounded up to 256
  if (ws_size < W_OFF + 1600 * 512) return;
  char* wsb = (char*)d_ws;
  float* invd = (float*)(wsb + INV_OFF);
  float* agg  = (float*)(wsb + AGG_OFF);
  unsigned short* W16 = (unsigned short*)(wsb + W_OFF);
  unsigned char*  W8  = (unsigned char*)(wsb + W_OFF);
  unsigned short* S16 = (unsigned short*)(wsb + W_OFF + (size_t)NE * 256);
  size_t wrem = ws_size - W_OFF;

  int plan;       // 0 = full bf16, 1 = int8+row scale, 2 = chunked bf16
  size_t chunk = NE;
  if (wrem >= (size_t)NE * 512)      plan = 0;
  else if (wrem >= (size_t)NE * 288) plan = 1;
  else {
    plan = 2;
    chunk = (wrem / 512) & ~(size_t)15;
    if (chunk > NE) chunk = NE;
  }

  const int NB = (NN + 255) / 256;
  const int EB = (NE + 255) / 256;

  hipMemsetAsync(invd, 0, (size_t)NN * 4, stream);
  deg_count_kernel<<<EB, 256, 0, stream>>>(edst, invd);
  deg_inv_kernel<<<NB, 256, 0, stream>>>(invd);
  copy_col0_kernel<<<NB, 256, 0, stream>>>(hx, out);

  if (plan == 0)
    fnet_bf16_kernel<<<EB, 256, 0, stream>>>(ef, w1, b1, w2, b2, W16, 0, NE);
  else if (plan == 1)
    fnet_i8_kernel<<<EB, 256, 0, stream>>>(ef, w1, b1, w2, b2, W8, S16);

  auto col = [&](int c) { return out + (size_t)c * 16; };

  auto step = [&](const float* hin, int hin_ld, float* hout,
                  const float* sprev, float* sout) {
    hipMemsetAsync(agg, 0, (size_t)NN * 64, stream);
    if (plan == 0) {
      msg_bf16_kernel<<<EB, 256, 0, stream>>>(hin, hin_ld, W16, 0, NE, idxn, edst, agg);
    } else if (plan == 1) {
      msg_i8_kernel<<<EB, 256, 0, stream>>>(hin, hin_ld, W8, S16, idxn, edst, agg);
    } else {
      for (size_t e0 = 0; e0 < NE; e0 += chunk) {
        int cnt = (int)(((size_t)NE - e0) < chunk ? ((size_t)NE - e0) : chunk);
        fnet_bf16_kernel<<<(cnt + 255) / 256, 256, 0, stream>>>(ef, w1, b1, w2, b2, W16,
                                                                (long long)e0, cnt);
        msg_bf16_kernel<<<(cnt + 255) / 256, 256, 0, stream>>>(hin, hin_ld, W16,
                                                               (long long)e0, cnt,
                                                               idxn, edst, agg);
      }
    }
    cell_kernel<<<NB, 256, 0, stream>>>(agg, invd, hin, hin_ld, wih, whh, bih, bhh,
                                        hout, OUTC, sprev, OUTC, sout, OUTC);
  };

  // cols 0..10 = [hx,h1,h2,s1,h4,s2,h6,s3,h8,s4,h10]; col10 is the rotating stash
  // for h3/h5/h7/h9 (each overwritten after last use; h10 lands there finally).
  step(hx,      16,  col(1),  nullptr, nullptr);   // h1
  step(col(1), OUTC, col(2),  nullptr, nullptr);   // h2
  step(col(2), OUTC, col(10), col(1),  col(3));    // h3 -> stash, s1 = h1 + h3
  step(col(3), OUTC, col(4),  nullptr, nullptr);   // h4
  step(col(4), OUTC, col(10), col(10), col(5));    // h5 -> stash, s2 = h3 + h5
  step(col(5), OUTC, col(6),  nullptr, nullptr);   // h6
  step(col(6), OUTC, col(10), col(10), col(7));    // h7 -> stash, s3 = h5 + h7
  step(col(7), OUTC, col(8),  nullptr, nullptr);   // h8
  step(col(8), OUTC, col(10), col(10), col(9));    // h9 -> stash, s4 = h7 + h9
  step(col(9), OUTC, col(10), nullptr, nullptr);   // h10 (final, overwrites stash)
}

// Round 6
// 1635.097 us; speedup vs baseline: 1.8436x; 1.8436x over previous
//
#include <hip/hip_runtime.h>

#define NN 50000
#define NE 800000
#define OUTC 176  // 11 * 16

typedef unsigned int uint32;

// ---------- bf16 helpers (manual, RNE) ----------
__device__ __forceinline__ uint32 f2bf_rne(float f) {
  union { float f; uint32 u; } v; v.f = f;
  uint32 u = v.u;
  return (u + 0x7FFFu + ((u >> 16) & 1u)) >> 16;
}
__device__ __forceinline__ uint32 packbf2(float a, float b) {
  return f2bf_rne(a) | (f2bf_rne(b) << 16);
}
__device__ __forceinline__ float blo(uint32 u) {
  union { uint32 x; float f; } t; t.x = u << 16; return t.f;
}
__device__ __forceinline__ float bhi(uint32 u) {
  union { uint32 x; float f; } t; t.x = u & 0xFFFF0000u; return t.f;
}
__device__ __forceinline__ float bf2f(unsigned short v) {
  union { uint32 x; float f; } t; t.x = ((uint32)v) << 16; return t.f;
}
// signed byte b (0..3) of packed word -> float
__device__ __forceinline__ float sb2f(uint32 w, int b) {
  return (float)((int)(w << (24 - 8 * b)) >> 24);
}

// ---------- small kernels ----------
__global__ __launch_bounds__(256) void deg_count_kernel(const int* __restrict__ edst,
                                                        float* __restrict__ deg) {
  int e = blockIdx.x * 256 + threadIdx.x;
  if (e < NE) atomicAdd(&deg[edst[e]], 1.0f);
}

__global__ __launch_bounds__(256) void deg_inv_kernel(float* __restrict__ deg) {
  int n = blockIdx.x * 256 + threadIdx.x;
  if (n < NN) deg[n] = 1.0f / fmaxf(deg[n], 1.0f);
}

__global__ __launch_bounds__(256) void copy_col0_kernel(const float* __restrict__ hx,
                                                        float* __restrict__ out) {
  int n = blockIdx.x * 256 + threadIdx.x;
  if (n >= NN) return;
  const float4* s = reinterpret_cast<const float4*>(hx + (size_t)n * 16);
  float4* d = reinterpret_cast<float4*>(out + (size_t)n * OUTC);
  d[0] = s[0]; d[1] = s[1]; d[2] = s[2]; d[3] = s[3];
}

// w2t[d][k][c] = w2[k*256 + c*16 + d]  (contiguous in (k,c) for fixed d ->
// wave-uniform scalar loads merge into s_load_dwordx16)
__global__ __launch_bounds__(256) void repack_w2_kernel(const float* __restrict__ w2,
                                                        float* __restrict__ w2t) {
  int i = blockIdx.x * 256 + threadIdx.x;
  if (i >= 256 * 1024) return;
  int d = i >> 10, r = i & 1023, k = r >> 4, c = r & 15;
  w2t[i] = w2[k * 256 + c * 16 + d];
}

// ---------- filter-generating network ----------
// W[e,c,d] = w_flat[e, c*16+d]; stored d-major: row(e,d) = {W[e,c,d]}_c contiguous.
// CRITICAL: every u[] access must be compile-time indexed (full unroll) or it
// spills to scratch (R5: 1.6 GB of scratch traffic, 10x slowdown).
__device__ __forceinline__ void fnet_layer1(const float* __restrict__ ef, long long e,
                                            const float* __restrict__ w1,
                                            const float* __restrict__ b1,
                                            float* u) {
  float f[13];
#pragma unroll
  for (int i = 0; i < 13; ++i) f[i] = ef[(size_t)e * 13 + i];
#pragma unroll
  for (int k = 0; k < 64; ++k) u[k] = b1[k];
#pragma unroll
  for (int i = 0; i < 13; ++i) {
    float fi = f[i];
#pragma unroll
    for (int k = 0; k < 64; ++k) u[k] = fmaf(fi, w1[i * 64 + k], u[k]);
  }
#pragma unroll
  for (int k = 0; k < 64; ++k) u[k] = fmaxf(u[k], 0.0f);
}

__global__ __launch_bounds__(256) void fnet_bf16_kernel(
    const float* __restrict__ ef, const float* __restrict__ w1, const float* __restrict__ b1,
    const float* __restrict__ w2t, const float* __restrict__ b2,
    unsigned short* __restrict__ W, long long ebase, int ecnt) {
  int t = blockIdx.x * 256 + threadIdx.x;
  if (t >= ecnt) return;
  float u[64];
  fnet_layer1(ef, ebase + t, w1, b1, u);
#pragma unroll 1
  for (int dt = 0; dt < 8; ++dt) {  // 2 d's per tile -> 64B burst store
    uint32 p[16];
#pragma unroll
    for (int dd = 0; dd < 2; ++dd) {
      const int d = dt * 2 + dd;
      const float* wr = w2t + ((size_t)d << 10);
      float acc[16];
#pragma unroll
      for (int c = 0; c < 16; ++c) acc[c] = b2[c * 16 + d];
#pragma unroll
      for (int k = 0; k < 64; ++k) {
        float uk = u[k];
#pragma unroll
        for (int c = 0; c < 16; ++c) acc[c] = fmaf(uk, wr[k * 16 + c], acc[c]);
      }
#pragma unroll
      for (int q = 0; q < 8; ++q) p[dd * 8 + q] = packbf2(acc[2 * q], acc[2 * q + 1]);
    }
    uint4* dp = reinterpret_cast<uint4*>(W + ((size_t)t << 8) + (dt << 5));
    dp[0] = make_uint4(p[0], p[1], p[2], p[3]);
    dp[1] = make_uint4(p[4], p[5], p[6], p[7]);
    dp[2] = make_uint4(p[8], p[9], p[10], p[11]);
    dp[3] = make_uint4(p[12], p[13], p[14], p[15]);
  }
}

// int8, per-(e,d)-row bf16 scale. W rows 64B-burst stored; scales stored in
// d-plane-transposed layout S[dt][e][4] so each wave store is full-sector.
__global__ __launch_bounds__(256) void fnet_i8_kernel(
    const float* __restrict__ ef, const float* __restrict__ w1, const float* __restrict__ b1,
    const float* __restrict__ w2t, const float* __restrict__ b2,
    unsigned char* __restrict__ W, unsigned short* __restrict__ S) {
  int t = blockIdx.x * 256 + threadIdx.x;
  if (t >= NE) return;
  float u[64];
  fnet_layer1(ef, t, w1, b1, u);
#pragma unroll 1
  for (int dt = 0; dt < 4; ++dt) {
    uint32 p[16];
    uint32 s0 = 0, s1 = 0;
#pragma unroll
    for (int dd = 0; dd < 4; ++dd) {
      const int d = dt * 4 + dd;
      const float* wr = w2t + ((size_t)d << 10);
      float acc[16];
#pragma unroll
      for (int c = 0; c < 16; ++c) acc[c] = b2[c * 16 + d];
#pragma unroll
      for (int k = 0; k < 64; ++k) {
        float uk = u[k];
#pragma unroll
        for (int c = 0; c < 16; ++c) acc[c] = fmaf(uk, wr[k * 16 + c], acc[c]);
      }
      float m = 0.0f;
#pragma unroll
      for (int c = 0; c < 16; ++c) m = fmaxf(m, fabsf(acc[c]));
      uint32 sbits = f2bf_rne(m * (1.0f / 127.0f));
      if (dd == 0)      s0 = sbits;
      else if (dd == 1) s0 |= sbits << 16;
      else if (dd == 2) s1 = sbits;
      else              s1 |= sbits << 16;
      float sdec = bf2f((unsigned short)sbits);
      float inv = (sdec > 0.0f) ? (1.0f / sdec) : 0.0f;
#pragma unroll
      for (int q = 0; q < 4; ++q) {
        uint32 w = 0;
#pragma unroll
        for (int b = 0; b < 4; ++b) {
          float qf = fminf(127.0f, fmaxf(-127.0f, rintf(acc[q * 4 + b] * inv)));
          w |= ((uint32)((int)qf & 255)) << (8 * b);
        }
        p[dd * 4 + q] = w;
      }
    }
    uint4* dp = reinterpret_cast<uint4*>(W + ((size_t)t << 8) + (dt << 6));
    dp[0] = make_uint4(p[0], p[1], p[2], p[3]);
    dp[1] = make_uint4(p[4], p[5], p[6], p[7]);
    dp[2] = make_uint4(p[8], p[9], p[10], p[11]);
    dp[3] = make_uint4(p[12], p[13], p[14], p[15]);
    *reinterpret_cast<uint2*>(S + ((size_t)dt * NE + t) * 4) = make_uint2(s0, s1);
  }
}

// ---------- gconv message + aggregate ----------
// 16 lanes (d) per strip of 16 consecutive edges; sorted edge_dst -> register run
// accumulation, flush via atomicAdd on dst change.
__global__ __launch_bounds__(256) void msg_bf16_kernel(
    const float* __restrict__ h, int h_ld,
    const unsigned short* __restrict__ W, long long ebase, int ecnt,
    const int* __restrict__ idxn, const int* __restrict__ edst,
    float* __restrict__ agg) {
  int t = blockIdx.x * 256 + threadIdx.x;
  if (t >= ecnt) return;
  int g = t >> 4, d = t & 15;
  int cur = -1;
  float acc = 0.0f;
  for (int s = 0; s < 16; ++s) {
    int erel = g * 16 + s;
    long long e = ebase + erel;
    int dst = edst[e];
    if (dst != cur) {
      if (cur >= 0) atomicAdd(&agg[(size_t)cur * 16 + d], acc);
      cur = dst; acc = 0.0f;
    }
    int src = idxn[e];
    const float4* hp = reinterpret_cast<const float4*>(h + (size_t)src * h_ld);
    float4 a0 = hp[0], a1 = hp[1], a2 = hp[2], a3 = hp[3];
    const uint4* wp = reinterpret_cast<const uint4*>(W + ((size_t)erel << 8) + (d << 4));
    uint4 w0 = wp[0], w1 = wp[1];
    acc = fmaf(a0.x, blo(w0.x), acc); acc = fmaf(a0.y, bhi(w0.x), acc);
    acc = fmaf(a0.z, blo(w0.y), acc); acc = fmaf(a0.w, bhi(w0.y), acc);
    acc = fmaf(a1.x, blo(w0.z), acc); acc = fmaf(a1.y, bhi(w0.z), acc);
    acc = fmaf(a1.z, blo(w0.w), acc); acc = fmaf(a1.w, bhi(w0.w), acc);
    acc = fmaf(a2.x, blo(w1.x), acc); acc = fmaf(a2.y, bhi(w1.x), acc);
    acc = fmaf(a2.z, blo(w1.y), acc); acc = fmaf(a2.w, bhi(w1.y), acc);
    acc = fmaf(a3.x, blo(w1.z), acc); acc = fmaf(a3.y, bhi(w1.z), acc);
    acc = fmaf(a3.z, blo(w1.w), acc); acc = fmaf(a3.w, bhi(w1.w), acc);
  }
  if (cur >= 0) atomicAdd(&agg[(size_t)cur * 16 + d], acc);
}

__global__ __launch_bounds__(256) void msg_i8_kernel(
    const float* __restrict__ h, int h_ld,
    const unsigned char* __restrict__ W, const unsigned short* __restrict__ S,
    const int* __restrict__ idxn, const int* __restrict__ edst,
    float* __restrict__ agg) {
  int t = blockIdx.x * 256 + threadIdx.x;
  if (t >= NE) return;
  int g = t >> 4, d = t & 15;
  const size_t splane = (size_t)(d >> 2) * NE;
  const int dsub = d & 3;
  int cur = -1;
  float acc = 0.0f;
  for (int s = 0; s < 16; ++s) {
    int e = g * 16 + s;
    int dst = edst[e];
    if (dst != cur) {
      if (cur >= 0) atomicAdd(&agg[(size_t)cur * 16 + d], acc);
      cur = dst; acc = 0.0f;
    }
    int src = idxn[e];
    const float4* hp = reinterpret_cast<const float4*>(h + (size_t)src * h_ld);
    float4 a0 = hp[0], a1 = hp[1], a2 = hp[2], a3 = hp[3];
    uint4 wv = *reinterpret_cast<const uint4*>(W + ((size_t)e << 8) + (d << 4));
    float sc = bf2f(S[(splane + e) * 4 + dsub]);
    float r = 0.0f;
    r = fmaf(a0.x, sb2f(wv.x, 0), r); r = fmaf(a0.y, sb2f(wv.x, 1), r);
    r = fmaf(a0.z, sb2f(wv.x, 2), r); r = fmaf(a0.w, sb2f(wv.x, 3), r);
    r = fmaf(a1.x, sb2f(wv.y, 0), r); r = fmaf(a1.y, sb2f(wv.y, 1), r);
    r = fmaf(a1.z, sb2f(wv.y, 2), r); r = fmaf(a1.w, sb2f(wv.y, 3), r);
    r = fmaf(a2.x, sb2f(wv.z, 0), r); r = fmaf(a2.y, sb2f(wv.z, 1), r);
    r = fmaf(a2.z, sb2f(wv.z, 2), r); r = fmaf(a2.w, sb2f(wv.z, 3), r);
    r = fmaf(a3.x, sb2f(wv.w, 0), r); r = fmaf(a3.y, sb2f(wv.w, 1), r);
    r = fmaf(a3.z, sb2f(wv.w, 2), r); r = fmaf(a3.w, sb2f(wv.w, 3), r);
    acc = fmaf(r, sc, acc);
  }
  if (cur >= 0) atomicAdd(&agg[(size_t)cur * 16 + d], acc);
}

// ---------- fused degree-normalize + GRU cell + optional skip-add ----------
// hout/sprev may alias (col10 stash) -> no __restrict__, sprev read before hout write.
__global__ __launch_bounds__(256) void cell_kernel(
    const float* __restrict__ agg, const float* __restrict__ invd,
    const float* __restrict__ hin, int hin_ld,
    const float* __restrict__ wih, const float* __restrict__ whh,
    const float* __restrict__ bih, const float* __restrict__ bhh,
    float* hout, int hout_ld,
    const float* sprev, int sprev_ld,
    float* sout, int sout_ld) {
  int n = blockIdx.x * 256 + threadIdx.x;
  if (n >= NN) return;
  float x[16], h[16];
  float inv = invd[n];
  const float4* ap = reinterpret_cast<const float4*>(agg + (size_t)n * 16);
  const float4* hp = reinterpret_cast<const float4*>(hin + (size_t)n * hin_ld);
#pragma unroll
  for (int q = 0; q < 4; ++q) {
    float4 a = ap[q];
    x[4 * q + 0] = a.x * inv; x[4 * q + 1] = a.y * inv;
    x[4 * q + 2] = a.z * inv; x[4 * q + 3] = a.w * inv;
    float4 hv = hp[q];
    h[4 * q + 0] = hv.x; h[4 * q + 1] = hv.y; h[4 * q + 2] = hv.z; h[4 * q + 3] = hv.w;
  }
  float r[16], z[16], nn[16];
#pragma unroll
  for (int j = 0; j < 16; ++j) {
    float gi = bih[j], gh = bhh[j];
#pragma unroll
    for (int c = 0; c < 16; ++c) {
      gi = fmaf(x[c], wih[j * 16 + c], gi);
      gh = fmaf(h[c], whh[j * 16 + c], gh);
    }
    r[j] = 1.0f / (1.0f + expf(-(gi + gh)));
  }
#pragma unroll
  for (int j = 0; j < 16; ++j) {
    float gi = bih[16 + j], gh = bhh[16 + j];
#pragma unroll
    for (int c = 0; c < 16; ++c) {
      gi = fmaf(x[c], wih[(16 + j) * 16 + c], gi);
      gh = fmaf(h[c], whh[(16 + j) * 16 + c], gh);
    }
    z[j] = 1.0f / (1.0f + expf(-(gi + gh)));
  }
#pragma unroll
  for (int j = 0; j < 16; ++j) {
    float gi = bih[32 + j], gh = bhh[32 + j];
#pragma unroll
    for (int c = 0; c < 16; ++c) {
      gi = fmaf(x[c], wih[(32 + j) * 16 + c], gi);
      gh = fmaf(h[c], whh[(32 + j) * 16 + c], gh);
    }
    nn[j] = tanhf(gi + r[j] * gh);
  }
  float hv[16];
#pragma unroll
  for (int j = 0; j < 16; ++j) hv[j] = (1.0f - z[j]) * nn[j] + z[j] * h[j];

  float sv[16];
  bool do_s = (sprev != nullptr);
  if (do_s) {
    const float4* pp = reinterpret_cast<const float4*>(sprev + (size_t)n * sprev_ld);
#pragma unroll
    for (int q = 0; q < 4; ++q) {
      float4 p = pp[q];
      sv[4 * q + 0] = hv[4 * q + 0] + p.x; sv[4 * q + 1] = hv[4 * q + 1] + p.y;
      sv[4 * q + 2] = hv[4 * q + 2] + p.z; sv[4 * q + 3] = hv[4 * q + 3] + p.w;
    }
  }
  float4* hop = reinterpret_cast<float4*>(hout + (size_t)n * hout_ld);
#pragma unroll
  for (int q = 0; q < 4; ++q)
    hop[q] = make_float4(hv[4 * q], hv[4 * q + 1], hv[4 * q + 2], hv[4 * q + 3]);
  if (do_s) {
    float4* sp = reinterpret_cast<float4*>(sout + (size_t)n * sout_ld);
#pragma unroll
    for (int q = 0; q < 4; ++q)
      sp[q] = make_float4(sv[4 * q], sv[4 * q + 1], sv[4 * q + 2], sv[4 * q + 3]);
  }
}

extern "C" void kernel_launch(void* const* d_in, const int* in_sizes, int n_in,
                              void* d_out, int out_size, void* d_ws, size_t ws_size,
                              hipStream_t stream) {
  const float* hx   = (const float*)d_in[0];
  const float* ef   = (const float*)d_in[1];
  const int*   idxn = (const int*)d_in[2];
  const int*   edst = (const int*)d_in[3];
  const float* w1   = (const float*)d_in[4];
  const float* b1   = (const float*)d_in[5];
  const float* w2   = (const float*)d_in[6];
  const float* b2   = (const float*)d_in[7];
  const float* wih  = (const float*)d_in[8];
  const float* whh  = (const float*)d_in[9];
  const float* bih  = (const float*)d_in[10];
  const float* bhh  = (const float*)d_in[11];
  float* out = (float*)d_out;

  // workspace: invd [NN f32] | agg [NN*16 f32] | w2t [256K f32] | W (+ scales)
  const size_t INV_OFF = 0;
  const size_t AGG_OFF = 200064;              // NN*4 rounded up to 64
  const size_t W2T_OFF = 3400192;             // agg end rounded up to 256
  const size_t W_OFF   = W2T_OFF + 1048576;   // 4448768
  if (ws_size < W_OFF + 1600 * 512) return;
  char* wsb = (char*)d_ws;
  float* invd = (float*)(wsb + INV_OFF);
  float* agg  = (float*)(wsb + AGG_OFF);
  float* w2t  = (float*)(wsb + W2T_OFF);
  unsigned short* W16 = (unsigned short*)(wsb + W_OFF);
  unsigned char*  W8  = (unsigned char*)(wsb + W_OFF);
  unsigned short* S16 = (unsigned short*)(wsb + W_OFF + (size_t)NE * 256);
  size_t wrem = ws_size - W_OFF;

  int plan;       // 0 = full bf16, 1 = int8+row scale, 2 = chunked bf16
  size_t chunk = NE;
  if (wrem >= (size_t)NE * 512)      plan = 0;
  else if (wrem >= (size_t)NE * 288) plan = 1;
  else {
    plan = 2;
    chunk = (wrem / 512) & ~(size_t)15;
    if (chunk > NE) chunk = NE;
  }

  const int NB = (NN + 255) / 256;
  const int EB = (NE + 255) / 256;

  hipMemsetAsync(invd, 0, (size_t)NN * 4, stream);
  deg_count_kernel<<<EB, 256, 0, stream>>>(edst, invd);
  deg_inv_kernel<<<NB, 256, 0, stream>>>(invd);
  copy_col0_kernel<<<NB, 256, 0, stream>>>(hx, out);
  repack_w2_kernel<<<1024, 256, 0, stream>>>(w2, w2t);

  if (plan == 0)
    fnet_bf16_kernel<<<EB, 256, 0, stream>>>(ef, w1, b1, w2t, b2, W16, 0, NE);
  else if (plan == 1)
    fnet_i8_kernel<<<EB, 256, 0, stream>>>(ef, w1, b1, w2t, b2, W8, S16);

  auto col = [&](int c) { return out + (size_t)c * 16; };

  auto step = [&](const float* hin, int hin_ld, float* hout,
                  const float* sprev, float* sout) {
    hipMemsetAsync(agg, 0, (size_t)NN * 64, stream);
    if (plan == 0) {
      msg_bf16_kernel<<<EB, 256, 0, stream>>>(hin, hin_ld, W16, 0, NE, idxn, edst, agg);
    } else if (plan == 1) {
      msg_i8_kernel<<<EB, 256, 0, stream>>>(hin, hin_ld, W8, S16, idxn, edst, agg);
    } else {
      for (size_t e0 = 0; e0 < NE; e0 += chunk) {
        int cnt = (int)(((size_t)NE - e0) < chunk ? ((size_t)NE - e0) : chunk);
        fnet_bf16_kernel<<<(cnt + 255) / 256, 256, 0, stream>>>(ef, w1, b1, w2t, b2, W16,
                                                                (long long)e0, cnt);
        msg_bf16_kernel<<<(cnt + 255) / 256, 256, 0, stream>>>(hin, hin_ld, W16,
                                                               (long long)e0, cnt,
                                                               idxn, edst, agg);
      }
    }
    cell_kernel<<<NB, 256, 0, stream>>>(agg, invd, hin, hin_ld, wih, whh, bih, bhh,
                                        hout, OUTC, sprev, OUTC, sout, OUTC);
  };

  // cols 0..10 = [hx,h1,h2,s1,h4,s2,h6,s3,h8,s4,h10]; col10 is the rotating stash
  // for h3/h5/h7/h9 (each overwritten after last use; h10 lands there finally).
  step(hx,      16,  col(1),  nullptr, nullptr);   // h1
  step(col(1), OUTC, col(2),  nullptr, nullptr);   // h2
  step(col(2), OUTC, col(10), col(1),  col(3));    // h3 -> stash, s1 = h1 + h3
  step(col(3), OUTC, col(4),  nullptr, nullptr);   // h4
  step(col(4), OUTC, col(10), col(10), col(5));    // h5 -> stash, s2 = h3 + h5
  step(col(5), OUTC, col(6),  nullptr, nullptr);   // h6
  step(col(6), OUTC, col(10), col(10), col(7));    // h7 -> stash, s3 = h5 + h7
  step(col(7), OUTC, col(8),  nullptr, nullptr);   // h8
  step(col(8), OUTC, col(10), col(10), col(9));    // h9 -> stash, s4 = h7 + h9
  step(col(9), OUTC, col(10), nullptr, nullptr);   // h10 (final, overwrites stash)
}

// Round 7
// 1097.671 us; speedup vs baseline: 2.7463x; 1.4896x over previous
//
#include <hip/hip_runtime.h>

#define NN 50000
#define NE 800000
#define OUTC 176  // 11 * 16

typedef unsigned int uint32;
typedef short bf16x8 __attribute__((ext_vector_type(8)));
typedef float f32x4 __attribute__((ext_vector_type(4)));

// ---------- bf16 helpers (manual, RNE) ----------
__device__ __forceinline__ uint32 f2bf_rne(float f) {
  union { float f; uint32 u; } v; v.f = f;
  uint32 u = v.u;
  return (u + 0x7FFFu + ((u >> 16) & 1u)) >> 16;
}
__device__ __forceinline__ uint32 packbf2(float a, float b) {
  return f2bf_rne(a) | (f2bf_rne(b) << 16);
}
__device__ __forceinline__ float blo(uint32 u) {
  union { uint32 x; float f; } t; t.x = u << 16; return t.f;
}
__device__ __forceinline__ float bhi(uint32 u) {
  union { uint32 x; float f; } t; t.x = u & 0xFFFF0000u; return t.f;
}
__device__ __forceinline__ float bf2f(unsigned short v) {
  union { uint32 x; float f; } t; t.x = ((uint32)v) << 16; return t.f;
}
// signed byte b (0..3) of packed word -> float
__device__ __forceinline__ float sb2f(uint32 w, int b) {
  return (float)((int)(w << (24 - 8 * b)) >> 24);
}

// ---------- small kernels ----------
__global__ __launch_bounds__(256) void deg_count_kernel(const int* __restrict__ edst,
                                                        float* __restrict__ deg) {
  int e = blockIdx.x * 256 + threadIdx.x;
  if (e < NE) atomicAdd(&deg[edst[e]], 1.0f);
}

__global__ __launch_bounds__(256) void deg_inv_kernel(float* __restrict__ deg) {
  int n = blockIdx.x * 256 + threadIdx.x;
  if (n < NN) deg[n] = 1.0f / fmaxf(deg[n], 1.0f);
}

__global__ __launch_bounds__(256) void copy_col0_kernel(const float* __restrict__ hx,
                                                        float* __restrict__ out) {
  int n = blockIdx.x * 256 + threadIdx.x;
  if (n >= NN) return;
  const float4* s = reinterpret_cast<const float4*>(hx + (size_t)n * 16);
  float4* d = reinterpret_cast<float4*>(out + (size_t)n * OUTC);
  d[0] = s[0]; d[1] = s[1]; d[2] = s[2]; d[3] = s[3];
}

// w2t[d][k][c] = w2[k*256 + c*16 + d]  (for the chunked-bf16 fallback plan)
__global__ __launch_bounds__(256) void repack_w2_kernel(const float* __restrict__ w2,
                                                        float* __restrict__ w2t) {
  int i = blockIdx.x * 256 + threadIdx.x;
  if (i >= 256 * 1024) return;
  int d = i >> 10, r = i & 1023, k = r >> 4, c = r & 15;
  w2t[i] = w2[k * 256 + c * 16 + d];
}

// w2 -> bf16 MFMA B-fragment layout (32 KB): lane l of frag (nb,m) holds
// col j = nb*16 + (l&15), k = m*32 + (l>>4)*8 + jj, jj=0..7 packed consecutively.
__global__ __launch_bounds__(256) void repack_w2f_kernel(const float* __restrict__ w2,
                                                         unsigned short* __restrict__ w2f) {
  int i = blockIdx.x * 256 + threadIdx.x;  // 0..16383
  if (i >= 16384) return;
  int jj = i & 7;
  int l = (i >> 3) & 63;
  int nbm = i >> 9;  // nb*2+m
  int m = nbm & 1, nb = nbm >> 1;
  int k = m * 32 + (l >> 4) * 8 + jj;
  int j = nb * 16 + (l & 15);
  w2f[i] = (unsigned short)f2bf_rne(w2[k * 256 + j]);
}

// ---------- MFMA fnet: fused layer1 + 16x256x64 GEMM + int8 quantize ----------
// One wave per 16-edge tile. Layer1: lane l computes u[k] for edge (l&15),
// k = (l>>4)*8+j and 32+(l>>4)*8+j  == exactly its A-fragments (no redundancy).
// D-layout (m89-verified): col=lane&15 (=d), row=(lane>>4)*4+reg (=edge-in-tile)
// -> each lane holds a full (e,d) row of 16 c-values across its 16 acc blocks,
// so rowmax+quant+pack are lane-local and stores are 16B/lane coalesced.
__global__ __launch_bounds__(256) void fnet_mfma_i8_kernel(
    const float* __restrict__ ef, const float* __restrict__ w1, const float* __restrict__ b1,
    const unsigned short* __restrict__ w2f, const float* __restrict__ b2,
    unsigned char* __restrict__ W, unsigned short* __restrict__ S) {
  int wid = (blockIdx.x * 256 + threadIdx.x) >> 6;
  int l = threadIdx.x & 63;
  if (wid >= NE / 16) return;
  const int d = l & 15, kg = l >> 4;

  // ---- layer1 ----
  size_t e1 = (size_t)wid * 16 + d;
  float f[13];
#pragma unroll
  for (int i = 0; i < 13; ++i) f[i] = ef[e1 * 13 + i];
  float ua[8], ub[8];
#pragma unroll
  for (int j = 0; j < 8; ++j) { ua[j] = b1[kg * 8 + j]; ub[j] = b1[32 + kg * 8 + j]; }
#pragma unroll
  for (int i = 0; i < 13; ++i) {
    const float4* wa = reinterpret_cast<const float4*>(w1 + i * 64 + kg * 8);
    const float4* wb = reinterpret_cast<const float4*>(w1 + i * 64 + 32 + kg * 8);
    float4 a0 = wa[0], a1 = wa[1], c0 = wb[0], c1 = wb[1];
    float fi = f[i];
    ua[0] = fmaf(fi, a0.x, ua[0]); ua[1] = fmaf(fi, a0.y, ua[1]);
    ua[2] = fmaf(fi, a0.z, ua[2]); ua[3] = fmaf(fi, a0.w, ua[3]);
    ua[4] = fmaf(fi, a1.x, ua[4]); ua[5] = fmaf(fi, a1.y, ua[5]);
    ua[6] = fmaf(fi, a1.z, ua[6]); ua[7] = fmaf(fi, a1.w, ua[7]);
    ub[0] = fmaf(fi, c0.x, ub[0]); ub[1] = fmaf(fi, c0.y, ub[1]);
    ub[2] = fmaf(fi, c0.z, ub[2]); ub[3] = fmaf(fi, c0.w, ub[3]);
    ub[4] = fmaf(fi, c1.x, ub[4]); ub[5] = fmaf(fi, c1.y, ub[5]);
    ub[6] = fmaf(fi, c1.z, ub[6]); ub[7] = fmaf(fi, c1.w, ub[7]);
  }
  bf16x8 afrag0, afrag1;
#pragma unroll
  for (int j = 0; j < 8; ++j) {
    afrag0[j] = (short)f2bf_rne(fmaxf(ua[j], 0.0f));
    afrag1[j] = (short)f2bf_rne(fmaxf(ub[j], 0.0f));
  }

  // ---- GEMM: 16 edges x 256 outputs, K=64 (2 MFMA per 16-col block) ----
  const bf16x8* Bp = reinterpret_cast<const bf16x8*>(w2f);
  f32x4 acc[16];
#pragma unroll
  for (int nb = 0; nb < 16; ++nb) {
    float bias = b2[nb * 16 + d];
    f32x4 c; c[0] = bias; c[1] = bias; c[2] = bias; c[3] = bias;
    bf16x8 bf0 = Bp[(nb * 2 + 0) * 64 + l];
    bf16x8 bf1 = Bp[(nb * 2 + 1) * 64 + l];
    c = __builtin_amdgcn_mfma_f32_16x16x32_bf16(afrag0, bf0, c, 0, 0, 0);
    c = __builtin_amdgcn_mfma_f32_16x16x32_bf16(afrag1, bf1, c, 0, 0, 0);
    acc[nb] = c;
  }

  // ---- int8 quantize + store (lane-local rows) ----
#pragma unroll
  for (int r = 0; r < 4; ++r) {
    size_t er = (size_t)wid * 16 + kg * 4 + r;
    float w[16];
#pragma unroll
    for (int c = 0; c < 16; ++c) w[c] = acc[c][r];
    float mx = 0.0f;
#pragma unroll
    for (int c = 0; c < 16; ++c) mx = fmaxf(mx, fabsf(w[c]));
    uint32 sbits = f2bf_rne(mx * (1.0f / 127.0f));
    float sdec = bf2f((unsigned short)sbits);
    float inv = (sdec > 0.0f) ? (1.0f / sdec) : 0.0f;
    uint32 p[4];
#pragma unroll
    for (int q = 0; q < 4; ++q) {
      uint32 wv = 0;
#pragma unroll
      for (int b = 0; b < 4; ++b) {
        float qf = fminf(127.0f, fmaxf(-127.0f, rintf(w[q * 4 + b] * inv)));
        wv |= ((uint32)((int)qf & 255)) << (8 * b);
      }
      p[q] = wv;
    }
    *reinterpret_cast<uint4*>(W + (er << 8) + (d << 4)) = make_uint4(p[0], p[1], p[2], p[3]);
    S[er * 16 + d] = (unsigned short)sbits;
  }
}

// ---------- chunked-bf16 fallback fnet (plan 2) ----------
__device__ __forceinline__ void fnet_layer1(const float* __restrict__ ef, long long e,
                                            const float* __restrict__ w1,
                                            const float* __restrict__ b1,
                                            float* u) {
  float f[13];
#pragma unroll
  for (int i = 0; i < 13; ++i) f[i] = ef[(size_t)e * 13 + i];
#pragma unroll
  for (int k = 0; k < 64; ++k) u[k] = b1[k];
#pragma unroll
  for (int i = 0; i < 13; ++i) {
    float fi = f[i];
#pragma unroll
    for (int k = 0; k < 64; ++k) u[k] = fmaf(fi, w1[i * 64 + k], u[k]);
  }
#pragma unroll
  for (int k = 0; k < 64; ++k) u[k] = fmaxf(u[k], 0.0f);
}

__global__ __launch_bounds__(256) void fnet_bf16_kernel(
    const float* __restrict__ ef, const float* __restrict__ w1, const float* __restrict__ b1,
    const float* __restrict__ w2t, const float* __restrict__ b2,
    unsigned short* __restrict__ W, long long ebase, int ecnt) {
  int t = blockIdx.x * 256 + threadIdx.x;
  if (t >= ecnt) return;
  float u[64];
  fnet_layer1(ef, ebase + t, w1, b1, u);
#pragma unroll 1
  for (int dt = 0; dt < 8; ++dt) {  // 2 d's per tile -> 64B burst store
    uint32 p[16];
#pragma unroll
    for (int dd = 0; dd < 2; ++dd) {
      const int d = dt * 2 + dd;
      const float* wr = w2t + ((size_t)d << 10);
      float acc[16];
#pragma unroll
      for (int c = 0; c < 16; ++c) acc[c] = b2[c * 16 + d];
#pragma unroll
      for (int k = 0; k < 64; ++k) {
        float uk = u[k];
#pragma unroll
        for (int c = 0; c < 16; ++c) acc[c] = fmaf(uk, wr[k * 16 + c], acc[c]);
      }
#pragma unroll
      for (int q = 0; q < 8; ++q) p[dd * 8 + q] = packbf2(acc[2 * q], acc[2 * q + 1]);
    }
    uint4* dp = reinterpret_cast<uint4*>(W + ((size_t)t << 8) + (dt << 5));
    dp[0] = make_uint4(p[0], p[1], p[2], p[3]);
    dp[1] = make_uint4(p[4], p[5], p[6], p[7]);
    dp[2] = make_uint4(p[8], p[9], p[10], p[11]);
    dp[3] = make_uint4(p[12], p[13], p[14], p[15]);
  }
}

// ---------- gconv message + aggregate ----------
// 16 lanes (d) per strip of 16 consecutive edges; sorted edge_dst -> register run
// accumulation, flush via atomicAdd on dst change.
__global__ __launch_bounds__(256) void msg_bf16_kernel(
    const float* __restrict__ h, int h_ld,
    const unsigned short* __restrict__ W, long long ebase, int ecnt,
    const int* __restrict__ idxn, const int* __restrict__ edst,
    float* __restrict__ agg) {
  int t = blockIdx.x * 256 + threadIdx.x;
  if (t >= ecnt) return;
  int g = t >> 4, d = t & 15;
  int cur = -1;
  float acc = 0.0f;
  for (int s = 0; s < 16; ++s) {
    int erel = g * 16 + s;
    long long e = ebase + erel;
    int dst = edst[e];
    if (dst != cur) {
      if (cur >= 0) atomicAdd(&agg[(size_t)cur * 16 + d], acc);
      cur = dst; acc = 0.0f;
    }
    int src = idxn[e];
    const float4* hp = reinterpret_cast<const float4*>(h + (size_t)src * h_ld);
    float4 a0 = hp[0], a1 = hp[1], a2 = hp[2], a3 = hp[3];
    const uint4* wp = reinterpret_cast<const uint4*>(W + ((size_t)erel << 8) + (d << 4));
    uint4 w0 = wp[0], w1 = wp[1];
    acc = fmaf(a0.x, blo(w0.x), acc); acc = fmaf(a0.y, bhi(w0.x), acc);
    acc = fmaf(a0.z, blo(w0.y), acc); acc = fmaf(a0.w, bhi(w0.y), acc);
    acc = fmaf(a1.x, blo(w0.z), acc); acc = fmaf(a1.y, bhi(w0.z), acc);
    acc = fmaf(a1.z, blo(w0.w), acc); acc = fmaf(a1.w, bhi(w0.w), acc);
    acc = fmaf(a2.x, blo(w1.x), acc); acc = fmaf(a2.y, bhi(w1.x), acc);
    acc = fmaf(a2.z, blo(w1.y), acc); acc = fmaf(a2.w, bhi(w1.y), acc);
    acc = fmaf(a3.x, blo(w1.z), acc); acc = fmaf(a3.y, bhi(w1.z), acc);
    acc = fmaf(a3.z, blo(w1.w), acc); acc = fmaf(a3.w, bhi(w1.w), acc);
  }
  if (cur >= 0) atomicAdd(&agg[(size_t)cur * 16 + d], acc);
}

__global__ __launch_bounds__(256) void msg_i8_kernel(
    const float* __restrict__ h, int h_ld,
    const unsigned char* __restrict__ W, const unsigned short* __restrict__ S,
    const int* __restrict__ idxn, const int* __restrict__ edst,
    float* __restrict__ agg) {
  int t = blockIdx.x * 256 + threadIdx.x;
  if (t >= NE) return;
  int g = t >> 4, d = t & 15;
  int cur = -1;
  float acc = 0.0f;
  for (int s = 0; s < 16; ++s) {
    int e = g * 16 + s;
    int dst = edst[e];
    if (dst != cur) {
      if (cur >= 0) atomicAdd(&agg[(size_t)cur * 16 + d], acc);
      cur = dst; acc = 0.0f;
    }
    int src = idxn[e];
    const float4* hp = reinterpret_cast<const float4*>(h + (size_t)src * h_ld);
    float4 a0 = hp[0], a1 = hp[1], a2 = hp[2], a3 = hp[3];
    uint4 wv = *reinterpret_cast<const uint4*>(W + ((size_t)e << 8) + (d << 4));
    float sc = bf2f(S[(size_t)e * 16 + d]);
    float r = 0.0f;
    r = fmaf(a0.x, sb2f(wv.x, 0), r); r = fmaf(a0.y, sb2f(wv.x, 1), r);
    r = fmaf(a0.z, sb2f(wv.x, 2), r); r = fmaf(a0.w, sb2f(wv.x, 3), r);
    r = fmaf(a1.x, sb2f(wv.y, 0), r); r = fmaf(a1.y, sb2f(wv.y, 1), r);
    r = fmaf(a1.z, sb2f(wv.y, 2), r); r = fmaf(a1.w, sb2f(wv.y, 3), r);
    r = fmaf(a2.x, sb2f(wv.z, 0), r); r = fmaf(a2.y, sb2f(wv.z, 1), r);
    r = fmaf(a2.z, sb2f(wv.z, 2), r); r = fmaf(a2.w, sb2f(wv.z, 3), r);
    r = fmaf(a3.x, sb2f(wv.w, 0), r); r = fmaf(a3.y, sb2f(wv.w, 1), r);
    r = fmaf(a3.z, sb2f(wv.w, 2), r); r = fmaf(a3.w, sb2f(wv.w, 3), r);
    acc = fmaf(r, sc, acc);
  }
  if (cur >= 0) atomicAdd(&agg[(size_t)cur * 16 + d], acc);
}

// ---------- fused degree-normalize + GRU cell + optional skip-add ----------
// hout/sprev may alias (col10 stash) -> no __restrict__, sprev read before hout write.
__global__ __launch_bounds__(256) void cell_kernel(
    const float* __restrict__ agg, const float* __restrict__ invd,
    const float* __restrict__ hin, int hin_ld,
    const float* __restrict__ wih, const float* __restrict__ whh,
    const float* __restrict__ bih, const float* __restrict__ bhh,
    float* hout, int hout_ld,
    const float* sprev, int sprev_ld,
    float* sout, int sout_ld) {
  int n = blockIdx.x * 256 + threadIdx.x;
  if (n >= NN) return;
  float x[16], h[16];
  float inv = invd[n];
  const float4* ap = reinterpret_cast<const float4*>(agg + (size_t)n * 16);
  const float4* hp = reinterpret_cast<const float4*>(hin + (size_t)n * hin_ld);
#pragma unroll
  for (int q = 0; q < 4; ++q) {
    float4 a = ap[q];
    x[4 * q + 0] = a.x * inv; x[4 * q + 1] = a.y * inv;
    x[4 * q + 2] = a.z * inv; x[4 * q + 3] = a.w * inv;
    float4 hv = hp[q];
    h[4 * q + 0] = hv.x; h[4 * q + 1] = hv.y; h[4 * q + 2] = hv.z; h[4 * q + 3] = hv.w;
  }
  float r[16], z[16], nn[16];
#pragma unroll
  for (int j = 0; j < 16; ++j) {
    float gi = bih[j], gh = bhh[j];
#pragma unroll
    for (int c = 0; c < 16; ++c) {
      gi = fmaf(x[c], wih[j * 16 + c], gi);
      gh = fmaf(h[c], whh[j * 16 + c], gh);
    }
    r[j] = 1.0f / (1.0f + expf(-(gi + gh)));
  }
#pragma unroll
  for (int j = 0; j < 16; ++j) {
    float gi = bih[16 + j], gh = bhh[16 + j];
#pragma unroll
    for (int c = 0; c < 16; ++c) {
      gi = fmaf(x[c], wih[(16 + j) * 16 + c], gi);
      gh = fmaf(h[c], whh[(16 + j) * 16 + c], gh);
    }
    z[j] = 1.0f / (1.0f + expf(-(gi + gh)));
  }
#pragma unroll
  for (int j = 0; j < 16; ++j) {
    float gi = bih[32 + j], gh = bhh[32 + j];
#pragma unroll
    for (int c = 0; c < 16; ++c) {
      gi = fmaf(x[c], wih[(32 + j) * 16 + c], gi);
      gh = fmaf(h[c], whh[(32 + j) * 16 + c], gh);
    }
    nn[j] = tanhf(gi + r[j] * gh);
  }
  float hv[16];
#pragma unroll
  for (int j = 0; j < 16; ++j) hv[j] = (1.0f - z[j]) * nn[j] + z[j] * h[j];

  float sv[16];
  bool do_s = (sprev != nullptr);
  if (do_s) {
    const float4* pp = reinterpret_cast<const float4*>(sprev + (size_t)n * sprev_ld);
#pragma unroll
    for (int q = 0; q < 4; ++q) {
      float4 p = pp[q];
      sv[4 * q + 0] = hv[4 * q + 0] + p.x; sv[4 * q + 1] = hv[4 * q + 1] + p.y;
      sv[4 * q + 2] = hv[4 * q + 2] + p.z; sv[4 * q + 3] = hv[4 * q + 3] + p.w;
    }
  }
  float4* hop = reinterpret_cast<float4*>(hout + (size_t)n * hout_ld);
#pragma unroll
  for (int q = 0; q < 4; ++q)
    hop[q] = make_float4(hv[4 * q], hv[4 * q + 1], hv[4 * q + 2], hv[4 * q + 3]);
  if (do_s) {
    float4* sp = reinterpret_cast<float4*>(sout + (size_t)n * sout_ld);
#pragma unroll
    for (int q = 0; q < 4; ++q)
      sp[q] = make_float4(sv[4 * q], sv[4 * q + 1], sv[4 * q + 2], sv[4 * q + 3]);
  }
}

extern "C" void kernel_launch(void* const* d_in, const int* in_sizes, int n_in,
                              void* d_out, int out_size, void* d_ws, size_t ws_size,
                              hipStream_t stream) {
  const float* hx   = (const float*)d_in[0];
  const float* ef   = (const float*)d_in[1];
  const int*   idxn = (const int*)d_in[2];
  const int*   edst = (const int*)d_in[3];
  const float* w1   = (const float*)d_in[4];
  const float* b1   = (const float*)d_in[5];
  const float* w2   = (const float*)d_in[6];
  const float* b2   = (const float*)d_in[7];
  const float* wih  = (const float*)d_in[8];
  const float* whh  = (const float*)d_in[9];
  const float* bih  = (const float*)d_in[10];
  const float* bhh  = (const float*)d_in[11];
  float* out = (float*)d_out;

  // workspace: invd | agg | w2f/w2t | W (+ scales)
  const size_t INV_OFF = 0;
  const size_t AGG_OFF = 200064;              // NN*4 rounded up to 64
  const size_t W2T_OFF = 3400192;             // agg end rounded up to 256
  const size_t W_OFF   = W2T_OFF + 1048576;   // holds w2t (1MB) or w2f (32KB)
  if (ws_size < W_OFF + 1600 * 512) return;
  char* wsb = (char*)d_ws;
  float* invd = (float*)(wsb + INV_OFF);
  float* agg  = (float*)(wsb + AGG_OFF);
  float* w2t  = (float*)(wsb + W2T_OFF);
  unsigned short* w2f = (unsigned short*)(wsb + W2T_OFF);
  unsigned short* W16 = (unsigned short*)(wsb + W_OFF);
  unsigned char*  W8  = (unsigned char*)(wsb + W_OFF);
  unsigned short* S16 = (unsigned short*)(wsb + W_OFF + (size_t)NE * 256);
  size_t wrem = ws_size - W_OFF;

  int plan;       // 1 = int8 + MFMA fnet, 2 = chunked bf16
  size_t chunk = NE;
  if (wrem >= (size_t)NE * 288) plan = 1;
  else {
    plan = 2;
    chunk = (wrem / 512) & ~(size_t)15;
    if (chunk > NE) chunk = NE;
  }

  const int NB = (NN + 255) / 256;
  const int EB = (NE + 255) / 256;

  hipMemsetAsync(invd, 0, (size_t)NN * 4, stream);
  deg_count_kernel<<<EB, 256, 0, stream>>>(edst, invd);
  deg_inv_kernel<<<NB, 256, 0, stream>>>(invd);
  copy_col0_kernel<<<NB, 256, 0, stream>>>(hx, out);

  if (plan == 1) {
    repack_w2f_kernel<<<64, 256, 0, stream>>>(w2, w2f);
    fnet_mfma_i8_kernel<<<(NE / 16) / 4, 256, 0, stream>>>(ef, w1, b1, w2f, b2, W8, S16);
  } else {
    repack_w2_kernel<<<1024, 256, 0, stream>>>(w2, w2t);
  }

  auto col = [&](int c) { return out + (size_t)c * 16; };

  auto step = [&](const float* hin, int hin_ld, float* hout,
                  const float* sprev, float* sout) {
    hipMemsetAsync(agg, 0, (size_t)NN * 64, stream);
    if (plan == 1) {
      msg_i8_kernel<<<EB, 256, 0, stream>>>(hin, hin_ld, W8, S16, idxn, edst, agg);
    } else {
      for (size_t e0 = 0; e0 < NE; e0 += chunk) {
        int cnt = (int)(((size_t)NE - e0) < chunk ? ((size_t)NE - e0) : chunk);
        fnet_bf16_kernel<<<(cnt + 255) / 256, 256, 0, stream>>>(ef, w1, b1, w2t, b2, W16,
                                                                (long long)e0, cnt);
        msg_bf16_kernel<<<(cnt + 255) / 256, 256, 0, stream>>>(hin, hin_ld, W16,
                                                               (long long)e0, cnt,
                                                               idxn, edst, agg);
      }
    }
    cell_kernel<<<NB, 256, 0, stream>>>(agg, invd, hin, hin_ld, wih, whh, bih, bhh,
                                        hout, OUTC, sprev, OUTC, sout, OUTC);
  };

  // cols 0..10 = [hx,h1,h2,s1,h4,s2,h6,s3,h8,s4,h10]; col10 is the rotating stash
  // for h3/h5/h7/h9 (each overwritten after last use; h10 lands there finally).
  step(hx,      16,  col(1),  nullptr, nullptr);   // h1
  step(col(1), OUTC, col(2),  nullptr, nullptr);   // h2
  step(col(2), OUTC, col(10), col(1),  col(3));    // h3 -> stash, s1 = h1 + h3
  step(col(3), OUTC, col(4),  nullptr, nullptr);   // h4
  step(col(4), OUTC, col(10), col(10), col(5));    // h5 -> stash, s2 = h3 + h5
  step(col(5), OUTC, col(6),  nullptr, nullptr);   // h6
  step(col(6), OUTC, col(10), col(10), col(7));    // h7 -> stash, s3 = h5 + h7
  step(col(7), OUTC, col(8),  nullptr, nullptr);   // h8
  step(col(8), OUTC, col(10), col(10), col(9));    // h9 -> stash, s4 = h7 + h9
  step(col(9), OUTC, col(10), nullptr, nullptr);   // h10 (final, overwrites stash)
}

// Round 8
// 1090.270 us; speedup vs baseline: 2.7649x; 1.0068x over previous
//
#include <hip/hip_runtime.h>

#define NN 50000
#define NE 800000
#define OUTC 176  // 11 * 16

typedef unsigned int uint32;
typedef short bf16x8 __attribute__((ext_vector_type(8)));
typedef float f32x4 __attribute__((ext_vector_type(4)));

// ---------- bf16 helpers (manual, RNE) ----------
__device__ __forceinline__ uint32 f2bf_rne(float f) {
  union { float f; uint32 u; } v; v.f = f;
  uint32 u = v.u;
  return (u + 0x7FFFu + ((u >> 16) & 1u)) >> 16;
}
__device__ __forceinline__ uint32 packbf2(float a, float b) {
  return f2bf_rne(a) | (f2bf_rne(b) << 16);
}
__device__ __forceinline__ float blo(uint32 u) {
  union { uint32 x; float f; } t; t.x = u << 16; return t.f;
}
__device__ __forceinline__ float bhi(uint32 u) {
  union { uint32 x; float f; } t; t.x = u & 0xFFFF0000u; return t.f;
}
__device__ __forceinline__ float bf2f(unsigned short v) {
  union { uint32 x; float f; } t; t.x = ((uint32)v) << 16; return t.f;
}
// signed byte b (0..3) of packed word -> float
__device__ __forceinline__ float sb2f(uint32 w, int b) {
  return (float)((int)(w << (24 - 8 * b)) >> 24);
}

// ---------- small kernels ----------
__global__ __launch_bounds__(256) void deg_count_kernel(const int* __restrict__ edst,
                                                        float* __restrict__ deg) {
  int e = blockIdx.x * 256 + threadIdx.x;
  if (e < NE) atomicAdd(&deg[edst[e]], 1.0f);
}

__global__ __launch_bounds__(256) void deg_inv_kernel(float* __restrict__ deg) {
  int n = blockIdx.x * 256 + threadIdx.x;
  if (n < NN) deg[n] = 1.0f / fmaxf(deg[n], 1.0f);
}

__global__ __launch_bounds__(256) void copy_col0_kernel(const float* __restrict__ hx,
                                                        float* __restrict__ out) {
  int n = blockIdx.x * 256 + threadIdx.x;
  if (n >= NN) return;
  const float4* s = reinterpret_cast<const float4*>(hx + (size_t)n * 16);
  float4* d = reinterpret_cast<float4*>(out + (size_t)n * OUTC);
  d[0] = s[0]; d[1] = s[1]; d[2] = s[2]; d[3] = s[3];
}

// w2t[d][k][c] = w2[k*256 + c*16 + d]  (for the chunked-bf16 fallback plan)
__global__ __launch_bounds__(256) void repack_w2_kernel(const float* __restrict__ w2,
                                                        float* __restrict__ w2t) {
  int i = blockIdx.x * 256 + threadIdx.x;
  if (i >= 256 * 1024) return;
  int d = i >> 10, r = i & 1023, k = r >> 4, c = r & 15;
  w2t[i] = w2[k * 256 + c * 16 + d];
}

// w2 -> bf16 MFMA B-fragment layout (32 KB): lane l of frag (nb,m) holds
// col j = nb*16 + (l&15), k = m*32 + (l>>4)*8 + jj, jj=0..7 packed consecutively.
__global__ __launch_bounds__(256) void repack_w2f_kernel(const float* __restrict__ w2,
                                                         unsigned short* __restrict__ w2f) {
  int i = blockIdx.x * 256 + threadIdx.x;  // 0..16383
  if (i >= 16384) return;
  int jj = i & 7;
  int l = (i >> 3) & 63;
  int nbm = i >> 9;  // nb*2+m
  int m = nbm & 1, nb = nbm >> 1;
  int k = m * 32 + (l >> 4) * 8 + jj;
  int j = nb * 16 + (l & 15);
  w2f[i] = (unsigned short)f2bf_rne(w2[k * 256 + j]);
}

// ---------- MFMA fnet: fused layer1 + 16x256x64 GEMM + int8 quantize ----------
// One wave per 16-edge tile. D-layout (m89-verified): col=lane&15 (=d),
// row=(lane>>4)*4+reg (=edge-in-tile) -> quant rows are lane-local.
__global__ __launch_bounds__(256) void fnet_mfma_i8_kernel(
    const float* __restrict__ ef, const float* __restrict__ w1, const float* __restrict__ b1,
    const unsigned short* __restrict__ w2f, const float* __restrict__ b2,
    unsigned char* __restrict__ W, unsigned short* __restrict__ S) {
  int wid = (blockIdx.x * 256 + threadIdx.x) >> 6;
  int l = threadIdx.x & 63;
  if (wid >= NE / 16) return;
  const int d = l & 15, kg = l >> 4;

  // ---- layer1 ----
  size_t e1 = (size_t)wid * 16 + d;
  float f[13];
#pragma unroll
  for (int i = 0; i < 13; ++i) f[i] = ef[e1 * 13 + i];
  float ua[8], ub[8];
#pragma unroll
  for (int j = 0; j < 8; ++j) { ua[j] = b1[kg * 8 + j]; ub[j] = b1[32 + kg * 8 + j]; }
#pragma unroll
  for (int i = 0; i < 13; ++i) {
    const float4* wa = reinterpret_cast<const float4*>(w1 + i * 64 + kg * 8);
    const float4* wb = reinterpret_cast<const float4*>(w1 + i * 64 + 32 + kg * 8);
    float4 a0 = wa[0], a1 = wa[1], c0 = wb[0], c1 = wb[1];
    float fi = f[i];
    ua[0] = fmaf(fi, a0.x, ua[0]); ua[1] = fmaf(fi, a0.y, ua[1]);
    ua[2] = fmaf(fi, a0.z, ua[2]); ua[3] = fmaf(fi, a0.w, ua[3]);
    ua[4] = fmaf(fi, a1.x, ua[4]); ua[5] = fmaf(fi, a1.y, ua[5]);
    ua[6] = fmaf(fi, a1.z, ua[6]); ua[7] = fmaf(fi, a1.w, ua[7]);
    ub[0] = fmaf(fi, c0.x, ub[0]); ub[1] = fmaf(fi, c0.y, ub[1]);
    ub[2] = fmaf(fi, c0.z, ub[2]); ub[3] = fmaf(fi, c0.w, ub[3]);
    ub[4] = fmaf(fi, c1.x, ub[4]); ub[5] = fmaf(fi, c1.y, ub[5]);
    ub[6] = fmaf(fi, c1.z, ub[6]); ub[7] = fmaf(fi, c1.w, ub[7]);
  }
  bf16x8 afrag0, afrag1;
#pragma unroll
  for (int j = 0; j < 8; ++j) {
    afrag0[j] = (short)f2bf_rne(fmaxf(ua[j], 0.0f));
    afrag1[j] = (short)f2bf_rne(fmaxf(ub[j], 0.0f));
  }

  // ---- GEMM: 16 edges x 256 outputs, K=64 (2 MFMA per 16-col block) ----
  const bf16x8* Bp = reinterpret_cast<const bf16x8*>(w2f);
  f32x4 acc[16];
#pragma unroll
  for (int nb = 0; nb < 16; ++nb) {
    float bias = b2[nb * 16 + d];
    f32x4 c; c[0] = bias; c[1] = bias; c[2] = bias; c[3] = bias;
    bf16x8 bf0 = Bp[(nb * 2 + 0) * 64 + l];
    bf16x8 bf1 = Bp[(nb * 2 + 1) * 64 + l];
    c = __builtin_amdgcn_mfma_f32_16x16x32_bf16(afrag0, bf0, c, 0, 0, 0);
    c = __builtin_amdgcn_mfma_f32_16x16x32_bf16(afrag1, bf1, c, 0, 0, 0);
    acc[nb] = c;
  }

  // ---- int8 quantize + store (lane-local rows) ----
#pragma unroll
  for (int r = 0; r < 4; ++r) {
    size_t er = (size_t)wid * 16 + kg * 4 + r;
    float w[16];
#pragma unroll
    for (int c = 0; c < 16; ++c) w[c] = acc[c][r];
    float mx = 0.0f;
#pragma unroll
    for (int c = 0; c < 16; ++c) mx = fmaxf(mx, fabsf(w[c]));
    uint32 sbits = f2bf_rne(mx * (1.0f / 127.0f));
    float sdec = bf2f((unsigned short)sbits);
    float inv = (sdec > 0.0f) ? (1.0f / sdec) : 0.0f;
    uint32 p[4];
#pragma unroll
    for (int q = 0; q < 4; ++q) {
      uint32 wv = 0;
#pragma unroll
      for (int b = 0; b < 4; ++b) {
        float qf = fminf(127.0f, fmaxf(-127.0f, rintf(w[q * 4 + b] * inv)));
        wv |= ((uint32)((int)qf & 255)) << (8 * b);
      }
      p[q] = wv;
    }
    *reinterpret_cast<uint4*>(W + (er << 8) + (d << 4)) = make_uint4(p[0], p[1], p[2], p[3]);
    S[er * 16 + d] = (unsigned short)sbits;
  }
}

// ---------- chunked-bf16 fallback fnet (plan 2) ----------
__device__ __forceinline__ void fnet_layer1(const float* __restrict__ ef, long long e,
                                            const float* __restrict__ w1,
                                            const float* __restrict__ b1,
                                            float* u) {
  float f[13];
#pragma unroll
  for (int i = 0; i < 13; ++i) f[i] = ef[(size_t)e * 13 + i];
#pragma unroll
  for (int k = 0; k < 64; ++k) u[k] = b1[k];
#pragma unroll
  for (int i = 0; i < 13; ++i) {
    float fi = f[i];
#pragma unroll
    for (int k = 0; k < 64; ++k) u[k] = fmaf(fi, w1[i * 64 + k], u[k]);
  }
#pragma unroll
  for (int k = 0; k < 64; ++k) u[k] = fmaxf(u[k], 0.0f);
}

__global__ __launch_bounds__(256) void fnet_bf16_kernel(
    const float* __restrict__ ef, const float* __restrict__ w1, const float* __restrict__ b1,
    const float* __restrict__ w2t, const float* __restrict__ b2,
    unsigned short* __restrict__ W, long long ebase, int ecnt) {
  int t = blockIdx.x * 256 + threadIdx.x;
  if (t >= ecnt) return;
  float u[64];
  fnet_layer1(ef, ebase + t, w1, b1, u);
#pragma unroll 1
  for (int dt = 0; dt < 8; ++dt) {  // 2 d's per tile -> 64B burst store
    uint32 p[16];
#pragma unroll
    for (int dd = 0; dd < 2; ++dd) {
      const int d = dt * 2 + dd;
      const float* wr = w2t + ((size_t)d << 10);
      float acc[16];
#pragma unroll
      for (int c = 0; c < 16; ++c) acc[c] = b2[c * 16 + d];
#pragma unroll
      for (int k = 0; k < 64; ++k) {
        float uk = u[k];
#pragma unroll
        for (int c = 0; c < 16; ++c) acc[c] = fmaf(uk, wr[k * 16 + c], acc[c]);
      }
#pragma unroll
      for (int q = 0; q < 8; ++q) p[dd * 8 + q] = packbf2(acc[2 * q], acc[2 * q + 1]);
    }
    uint4* dp = reinterpret_cast<uint4*>(W + ((size_t)t << 8) + (dt << 5));
    dp[0] = make_uint4(p[0], p[1], p[2], p[3]);
    dp[1] = make_uint4(p[4], p[5], p[6], p[7]);
    dp[2] = make_uint4(p[8], p[9], p[10], p[11]);
    dp[3] = make_uint4(p[12], p[13], p[14], p[15]);
  }
}

// ---------- gconv message + aggregate ----------
// 16 lanes (d) per strip of 16 consecutive edges. Strip idx preloaded once per
// lane and shfl-broadcast; h/W/S prefetched one edge ahead (hides gather
// latency under FMA+decode). Sorted edge_dst -> register run accumulation.
__global__ __launch_bounds__(256) void msg_bf16_kernel(
    const float* __restrict__ h, int h_ld,
    const unsigned short* __restrict__ W, long long ebase, int ecnt,
    const int* __restrict__ idxn, const int* __restrict__ edst,
    float* __restrict__ agg) {
  int t = blockIdx.x * 256 + threadIdx.x;
  if (t >= ecnt) return;
  int g = t >> 4, d = t & 15;
  int cur = -1;
  float acc = 0.0f;
  for (int s = 0; s < 16; ++s) {
    int erel = g * 16 + s;
    long long e = ebase + erel;
    int dst = edst[e];
    if (dst != cur) {
      if (cur >= 0) atomicAdd(&agg[(size_t)cur * 16 + d], acc);
      cur = dst; acc = 0.0f;
    }
    int src = idxn[e];
    const float4* hp = reinterpret_cast<const float4*>(h + (size_t)src * h_ld);
    float4 a0 = hp[0], a1 = hp[1], a2 = hp[2], a3 = hp[3];
    const uint4* wp = reinterpret_cast<const uint4*>(W + ((size_t)erel << 8) + (d << 4));
    uint4 w0 = wp[0], w1 = wp[1];
    acc = fmaf(a0.x, blo(w0.x), acc); acc = fmaf(a0.y, bhi(w0.x), acc);
    acc = fmaf(a0.z, blo(w0.y), acc); acc = fmaf(a0.w, bhi(w0.y), acc);
    acc = fmaf(a1.x, blo(w0.z), acc); acc = fmaf(a1.y, bhi(w0.z), acc);
    acc = fmaf(a1.z, blo(w0.w), acc); acc = fmaf(a1.w, bhi(w0.w), acc);
    acc = fmaf(a2.x, blo(w1.x), acc); acc = fmaf(a2.y, bhi(w1.x), acc);
    acc = fmaf(a2.z, blo(w1.y), acc); acc = fmaf(a2.w, bhi(w1.y), acc);
    acc = fmaf(a3.x, blo(w1.z), acc); acc = fmaf(a3.y, bhi(w1.z), acc);
    acc = fmaf(a3.z, blo(w1.w), acc); acc = fmaf(a3.w, bhi(w1.w), acc);
  }
  if (cur >= 0) atomicAdd(&agg[(size_t)cur * 16 + d], acc);
}

__global__ __launch_bounds__(256) void msg_i8_kernel(
    const float* __restrict__ h, int h_ld,
    const unsigned char* __restrict__ W, const unsigned short* __restrict__ S,
    const int* __restrict__ idxn, const int* __restrict__ edst,
    float* __restrict__ agg) {
  int t = blockIdx.x * 256 + threadIdx.x;
  if (t >= NE) return;
  const int g = t >> 4, d = t & 15;
  const int base = threadIdx.x & 48;  // first lane of this 16-group in the wave
  const int e0 = g * 16;

  // per-lane preload of the strip's edge indices (lane d owns edge e0+d)
  int my_dst = edst[e0 + d];
  int my_src = idxn[e0 + d];

  // prefetch edge 0
  int srcn = __shfl(my_src, base);
  const float4* hp = reinterpret_cast<const float4*>(h + (size_t)srcn * h_ld);
  float4 na0 = hp[0], na1 = hp[1], na2 = hp[2], na3 = hp[3];
  uint4 nwv = *reinterpret_cast<const uint4*>(W + ((size_t)e0 << 8) + (d << 4));
  float nsc = bf2f(S[(size_t)e0 * 16 + d]);

  int cur = -1;
  float acc = 0.0f;
#pragma unroll
  for (int s = 0; s < 16; ++s) {
    float4 a0 = na0, a1 = na1, a2 = na2, a3 = na3;
    uint4 wv = nwv;
    float sc = nsc;
    int dst = __shfl(my_dst, base + s);
    if (s < 15) {  // issue next-edge loads before computing (depth-1 pipeline)
      int sn = __shfl(my_src, base + s + 1);
      const float4* hq = reinterpret_cast<const float4*>(h + (size_t)sn * h_ld);
      na0 = hq[0]; na1 = hq[1]; na2 = hq[2]; na3 = hq[3];
      nwv = *reinterpret_cast<const uint4*>(W + ((size_t)(e0 + s + 1) << 8) + (d << 4));
      nsc = bf2f(S[(size_t)(e0 + s + 1) * 16 + d]);
    }
    if (dst != cur) {
      if (cur >= 0) atomicAdd(&agg[(size_t)cur * 16 + d], acc);
      cur = dst; acc = 0.0f;
    }
    float r = 0.0f;
    r = fmaf(a0.x, sb2f(wv.x, 0), r); r = fmaf(a0.y, sb2f(wv.x, 1), r);
    r = fmaf(a0.z, sb2f(wv.x, 2), r); r = fmaf(a0.w, sb2f(wv.x, 3), r);
    r = fmaf(a1.x, sb2f(wv.y, 0), r); r = fmaf(a1.y, sb2f(wv.y, 1), r);
    r = fmaf(a1.z, sb2f(wv.y, 2), r); r = fmaf(a1.w, sb2f(wv.y, 3), r);
    r = fmaf(a2.x, sb2f(wv.z, 0), r); r = fmaf(a2.y, sb2f(wv.z, 1), r);
    r = fmaf(a2.z, sb2f(wv.z, 2), r); r = fmaf(a2.w, sb2f(wv.z, 3), r);
    r = fmaf(a3.x, sb2f(wv.w, 0), r); r = fmaf(a3.y, sb2f(wv.w, 1), r);
    r = fmaf(a3.z, sb2f(wv.w, 2), r); r = fmaf(a3.w, sb2f(wv.w, 3), r);
    acc = fmaf(r, sc, acc);
  }
  atomicAdd(&agg[(size_t)cur * 16 + d], acc);
}

// ---------- fused degree-normalize + GRU cell + skip-add + agg re-zero ----------
// hout/sprev may alias (col10 stash) -> no __restrict__, sprev read before hout write.
// agg is read then re-zeroed (same thread, same row) so the next step's msg
// kernel starts from zeros without a separate memset dispatch.
__global__ __launch_bounds__(256) void cell_kernel(
    float* agg, const float* __restrict__ invd,
    const float* __restrict__ hin, int hin_ld,
    const float* __restrict__ wih, const float* __restrict__ whh,
    const float* __restrict__ bih, const float* __restrict__ bhh,
    float* hout, int hout_ld,
    const float* sprev, int sprev_ld,
    float* sout, int sout_ld) {
  int n = blockIdx.x * 256 + threadIdx.x;
  if (n >= NN) return;
  float x[16], h[16];
  float inv = invd[n];
  float4* ap = reinterpret_cast<float4*>(agg + (size_t)n * 16);
  const float4* hp = reinterpret_cast<const float4*>(hin + (size_t)n * hin_ld);
#pragma unroll
  for (int q = 0; q < 4; ++q) {
    float4 a = ap[q];
    x[4 * q + 0] = a.x * inv; x[4 * q + 1] = a.y * inv;
    x[4 * q + 2] = a.z * inv; x[4 * q + 3] = a.w * inv;
    float4 hv = hp[q];
    h[4 * q + 0] = hv.x; h[4 * q + 1] = hv.y; h[4 * q + 2] = hv.z; h[4 * q + 3] = hv.w;
  }
  float4 zz = make_float4(0.f, 0.f, 0.f, 0.f);
#pragma unroll
  for (int q = 0; q < 4; ++q) ap[q] = zz;  // re-zero for next step
  float r[16], z[16], nn[16];
#pragma unroll
  for (int j = 0; j < 16; ++j) {
    float gi = bih[j], gh = bhh[j];
#pragma unroll
    for (int c = 0; c < 16; ++c) {
      gi = fmaf(x[c], wih[j * 16 + c], gi);
      gh = fmaf(h[c], whh[j * 16 + c], gh);
    }
    r[j] = 1.0f / (1.0f + expf(-(gi + gh)));
  }
#pragma unroll
  for (int j = 0; j < 16; ++j) {
    float gi = bih[16 + j], gh = bhh[16 + j];
#pragma unroll
    for (int c = 0; c < 16; ++c) {
      gi = fmaf(x[c], wih[(16 + j) * 16 + c], gi);
      gh = fmaf(h[c], whh[(16 + j) * 16 + c], gh);
    }
    z[j] = 1.0f / (1.0f + expf(-(gi + gh)));
  }
#pragma unroll
  for (int j = 0; j < 16; ++j) {
    float gi = bih[32 + j], gh = bhh[32 + j];
#pragma unroll
    for (int c = 0; c < 16; ++c) {
      gi = fmaf(x[c], wih[(32 + j) * 16 + c], gi);
      gh = fmaf(h[c], whh[(32 + j) * 16 + c], gh);
    }
    nn[j] = tanhf(gi + r[j] * gh);
  }
  float hv[16];
#pragma unroll
  for (int j = 0; j < 16; ++j) hv[j] = (1.0f - z[j]) * nn[j] + z[j] * h[j];

  float sv[16];
  bool do_s = (sprev != nullptr);
  if (do_s) {
    const float4* pp = reinterpret_cast<const float4*>(sprev + (size_t)n * sprev_ld);
#pragma unroll
    for (int q = 0; q < 4; ++q) {
      float4 p = pp[q];
      sv[4 * q + 0] = hv[4 * q + 0] + p.x; sv[4 * q + 1] = hv[4 * q + 1] + p.y;
      sv[4 * q + 2] = hv[4 * q + 2] + p.z; sv[4 * q + 3] = hv[4 * q + 3] + p.w;
    }
  }
  float4* hop = reinterpret_cast<float4*>(hout + (size_t)n * hout_ld);
#pragma unroll
  for (int q = 0; q < 4; ++q)
    hop[q] = make_float4(hv[4 * q], hv[4 * q + 1], hv[4 * q + 2], hv[4 * q + 3]);
  if (do_s) {
    float4* sp = reinterpret_cast<float4*>(sout + (size_t)n * sout_ld);
#pragma unroll
    for (int q = 0; q < 4; ++q)
      sp[q] = make_float4(sv[4 * q], sv[4 * q + 1], sv[4 * q + 2], sv[4 * q + 3]);
  }
}

extern "C" void kernel_launch(void* const* d_in, const int* in_sizes, int n_in,
                              void* d_out, int out_size, void* d_ws, size_t ws_size,
                              hipStream_t stream) {
  const float* hx   = (const float*)d_in[0];
  const float* ef   = (const float*)d_in[1];
  const int*   idxn = (const int*)d_in[2];
  const int*   edst = (const int*)d_in[3];
  const float* w1   = (const float*)d_in[4];
  const float* b1   = (const float*)d_in[5];
  const float* w2   = (const float*)d_in[6];
  const float* b2   = (const float*)d_in[7];
  const float* wih  = (const float*)d_in[8];
  const float* whh  = (const float*)d_in[9];
  const float* bih  = (const float*)d_in[10];
  const float* bhh  = (const float*)d_in[11];
  float* out = (float*)d_out;

  // workspace: invd | agg | w2f/w2t | W (+ scales)
  const size_t INV_OFF = 0;
  const size_t AGG_OFF = 200064;              // NN*4 rounded up to 64
  const size_t W2T_OFF = 3400192;             // agg end rounded up to 256
  const size_t W_OFF   = W2T_OFF + 1048576;   // holds w2t (1MB) or w2f (32KB)
  if (ws_size < W_OFF + 1600 * 512) return;
  char* wsb = (char*)d_ws;
  float* invd = (float*)(wsb + INV_OFF);
  float* agg  = (float*)(wsb + AGG_OFF);
  float* w2t  = (float*)(wsb + W2T_OFF);
  unsigned short* w2f = (unsigned short*)(wsb + W2T_OFF);
  unsigned short* W16 = (unsigned short*)(wsb + W_OFF);
  unsigned char*  W8  = (unsigned char*)(wsb + W_OFF);
  unsigned short* S16 = (unsigned short*)(wsb + W_OFF + (size_t)NE * 256);
  size_t wrem = ws_size - W_OFF;

  int plan;       // 1 = int8 + MFMA fnet, 2 = chunked bf16
  size_t chunk = NE;
  if (wrem >= (size_t)NE * 288) plan = 1;
  else {
    plan = 2;
    chunk = (wrem / 512) & ~(size_t)15;
    if (chunk > NE) chunk = NE;
  }

  const int NB = (NN + 255) / 256;
  const int EB = (NE + 255) / 256;

  hipMemsetAsync(invd, 0, (size_t)NN * 4, stream);
  hipMemsetAsync(agg, 0, (size_t)NN * 64, stream);  // once; cell re-zeroes per step
  deg_count_kernel<<<EB, 256, 0, stream>>>(edst, invd);
  deg_inv_kernel<<<NB, 256, 0, stream>>>(invd);
  copy_col0_kernel<<<NB, 256, 0, stream>>>(hx, out);

  if (plan == 1) {
    repack_w2f_kernel<<<64, 256, 0, stream>>>(w2, w2f);
    fnet_mfma_i8_kernel<<<(NE / 16) / 4, 256, 0, stream>>>(ef, w1, b1, w2f, b2, W8, S16);
  } else {
    repack_w2_kernel<<<1024, 256, 0, stream>>>(w2, w2t);
  }

  auto col = [&](int c) { return out + (size_t)c * 16; };

  auto step = [&](const float* hin, int hin_ld, float* hout,
                  const float* sprev, float* sout) {
    if (plan == 1) {
      msg_i8_kernel<<<EB, 256, 0, stream>>>(hin, hin_ld, W8, S16, idxn, edst, agg);
    } else {
      for (size_t e0 = 0; e0 < NE; e0 += chunk) {
        int cnt = (int)(((size_t)NE - e0) < chunk ? ((size_t)NE - e0) : chunk);
        fnet_bf16_kernel<<<(cnt + 255) / 256, 256, 0, stream>>>(ef, w1, b1, w2t, b2, W16,
                                                                (long long)e0, cnt);
        msg_bf16_kernel<<<(cnt + 255) / 256, 256, 0, stream>>>(hin, hin_ld, W16,
                                                               (long long)e0, cnt,
                                                               idxn, edst, agg);
      }
    }
    cell_kernel<<<NB, 256, 0, stream>>>(agg, invd, hin, hin_ld, wih, whh, bih, bhh,
                                        hout, OUTC, sprev, OUTC, sout, OUTC);
  };

  // cols 0..10 = [hx,h1,h2,s1,h4,s2,h6,s3,h8,s4,h10]; col10 is the rotating stash
  // for h3/h5/h7/h9 (each overwritten after last use; h10 lands there finally).
  step(hx,      16,  col(1),  nullptr, nullptr);   // h1
  step(col(1), OUTC, col(2),  nullptr, nullptr);   // h2
  step(col(2), OUTC, col(10), col(1),  col(3));    // h3 -> stash, s1 = h1 + h3
  step(col(3), OUTC, col(4),  nullptr, nullptr);   // h4
  step(col(4), OUTC, col(10), col(10), col(5));    // h5 -> stash, s2 = h3 + h5
  step(col(5), OUTC, col(6),  nullptr, nullptr);   // h6
  step(col(6), OUTC, col(10), col(10), col(7));    // h7 -> stash, s3 = h5 + h7
  step(col(7), OUTC, col(8),  nullptr, nullptr);   // h8
  step(col(8), OUTC, col(10), col(10), col(9));    // h9 -> stash, s4 = h7 + h9
  step(col(9), OUTC, col(10), nullptr, nullptr);   // h10 (final, overwrites stash)
}

// Round 9
// 1055.547 us; speedup vs baseline: 2.8559x; 1.0329x over previous
//
#include <hip/hip_runtime.h>

#define NN 50000
#define NE 800000
#define OUTC 176  // 11 * 16

typedef unsigned int uint32;
typedef short bf16x8 __attribute__((ext_vector_type(8)));
typedef float f32x4 __attribute__((ext_vector_type(4)));

// ---------- bf16 helpers (manual, RNE) ----------
__device__ __forceinline__ uint32 f2bf_rne(float f) {
  union { float f; uint32 u; } v; v.f = f;
  uint32 u = v.u;
  return (u + 0x7FFFu + ((u >> 16) & 1u)) >> 16;
}
__device__ __forceinline__ uint32 packbf2(float a, float b) {
  return f2bf_rne(a) | (f2bf_rne(b) << 16);
}
__device__ __forceinline__ float blo(uint32 u) {
  union { uint32 x; float f; } t; t.x = u << 16; return t.f;
}
__device__ __forceinline__ float bhi(uint32 u) {
  union { uint32 x; float f; } t; t.x = u & 0xFFFF0000u; return t.f;
}
__device__ __forceinline__ float bf2f(unsigned short v) {
  union { uint32 x; float f; } t; t.x = ((uint32)v) << 16; return t.f;
}
// signed byte b (0..3) of packed word -> float
__device__ __forceinline__ float sb2f(uint32 w, int b) {
  return (float)((int)(w << (24 - 8 * b)) >> 24);
}

// ---------- small kernels ----------
__global__ __launch_bounds__(256) void deg_count_kernel(const int* __restrict__ edst,
                                                        float* __restrict__ deg) {
  int e = blockIdx.x * 256 + threadIdx.x;
  if (e < NE) atomicAdd(&deg[edst[e]], 1.0f);
}

__global__ __launch_bounds__(256) void deg_inv_kernel(float* __restrict__ deg) {
  int n = blockIdx.x * 256 + threadIdx.x;
  if (n < NN) deg[n] = 1.0f / fmaxf(deg[n], 1.0f);
}

__global__ __launch_bounds__(256) void copy_col0_kernel(const float* __restrict__ hx,
                                                        float* __restrict__ out) {
  int n = blockIdx.x * 256 + threadIdx.x;
  if (n >= NN) return;
  const float4* s = reinterpret_cast<const float4*>(hx + (size_t)n * 16);
  float4* d = reinterpret_cast<float4*>(out + (size_t)n * OUTC);
  d[0] = s[0]; d[1] = s[1]; d[2] = s[2]; d[3] = s[3];
}

// w2t[d][k][c] = w2[k*256 + c*16 + d]  (for the chunked-bf16 fallback plan)
__global__ __launch_bounds__(256) void repack_w2_kernel(const float* __restrict__ w2,
                                                        float* __restrict__ w2t) {
  int i = blockIdx.x * 256 + threadIdx.x;
  if (i >= 256 * 1024) return;
  int d = i >> 10, r = i & 1023, k = r >> 4, c = r & 15;
  w2t[i] = w2[k * 256 + c * 16 + d];
}

// w2 -> bf16 MFMA B-fragment layout (32 KB): lane l of frag (nb,m) holds
// col j = nb*16 + (l&15), k = m*32 + (l>>4)*8 + jj, jj=0..7 packed consecutively.
__global__ __launch_bounds__(256) void repack_w2f_kernel(const float* __restrict__ w2,
                                                         unsigned short* __restrict__ w2f) {
  int i = blockIdx.x * 256 + threadIdx.x;  // 0..16383
  if (i >= 16384) return;
  int jj = i & 7;
  int l = (i >> 3) & 63;
  int nbm = i >> 9;  // nb*2+m
  int m = nbm & 1, nb = nbm >> 1;
  int k = m * 32 + (l >> 4) * 8 + jj;
  int j = nb * 16 + (l & 15);
  w2f[i] = (unsigned short)f2bf_rne(w2[k * 256 + j]);
}

// ---------- MFMA fnet: fused layer1 + 16x256x64 GEMM + int8 quantize ----------
// One wave per 16-edge tile. D-layout (m89-verified): col=lane&15 (=d),
// row=(lane>>4)*4+reg (=edge-in-tile) -> quant rows are lane-local.
// Per-EDGE scale: edge e's 16 rows live in one kg-group -> 4x shfl_xor reduce.
__global__ __launch_bounds__(256) void fnet_mfma_i8_kernel(
    const float* __restrict__ ef, const float* __restrict__ w1, const float* __restrict__ b1,
    const unsigned short* __restrict__ w2f, const float* __restrict__ b2,
    unsigned char* __restrict__ W, unsigned short* __restrict__ S) {
  int wid = (blockIdx.x * 256 + threadIdx.x) >> 6;
  int l = threadIdx.x & 63;
  if (wid >= NE / 16) return;
  const int d = l & 15, kg = l >> 4;

  // ---- layer1 ----
  size_t e1 = (size_t)wid * 16 + d;
  float f[13];
#pragma unroll
  for (int i = 0; i < 13; ++i) f[i] = ef[e1 * 13 + i];
  float ua[8], ub[8];
#pragma unroll
  for (int j = 0; j < 8; ++j) { ua[j] = b1[kg * 8 + j]; ub[j] = b1[32 + kg * 8 + j]; }
#pragma unroll
  for (int i = 0; i < 13; ++i) {
    const float4* wa = reinterpret_cast<const float4*>(w1 + i * 64 + kg * 8);
    const float4* wb = reinterpret_cast<const float4*>(w1 + i * 64 + 32 + kg * 8);
    float4 a0 = wa[0], a1 = wa[1], c0 = wb[0], c1 = wb[1];
    float fi = f[i];
    ua[0] = fmaf(fi, a0.x, ua[0]); ua[1] = fmaf(fi, a0.y, ua[1]);
    ua[2] = fmaf(fi, a0.z, ua[2]); ua[3] = fmaf(fi, a0.w, ua[3]);
    ua[4] = fmaf(fi, a1.x, ua[4]); ua[5] = fmaf(fi, a1.y, ua[5]);
    ua[6] = fmaf(fi, a1.z, ua[6]); ua[7] = fmaf(fi, a1.w, ua[7]);
    ub[0] = fmaf(fi, c0.x, ub[0]); ub[1] = fmaf(fi, c0.y, ub[1]);
    ub[2] = fmaf(fi, c0.z, ub[2]); ub[3] = fmaf(fi, c0.w, ub[3]);
    ub[4] = fmaf(fi, c1.x, ub[4]); ub[5] = fmaf(fi, c1.y, ub[5]);
    ub[6] = fmaf(fi, c1.z, ub[6]); ub[7] = fmaf(fi, c1.w, ub[7]);
  }
  bf16x8 afrag0, afrag1;
#pragma unroll
  for (int j = 0; j < 8; ++j) {
    afrag0[j] = (short)f2bf_rne(fmaxf(ua[j], 0.0f));
    afrag1[j] = (short)f2bf_rne(fmaxf(ub[j], 0.0f));
  }

  // ---- GEMM: 16 edges x 256 outputs, K=64 (2 MFMA per 16-col block) ----
  const bf16x8* Bp = reinterpret_cast<const bf16x8*>(w2f);
  f32x4 acc[16];
#pragma unroll
  for (int nb = 0; nb < 16; ++nb) {
    float bias = b2[nb * 16 + d];
    f32x4 c; c[0] = bias; c[1] = bias; c[2] = bias; c[3] = bias;
    bf16x8 bf0 = Bp[(nb * 2 + 0) * 64 + l];
    bf16x8 bf1 = Bp[(nb * 2 + 1) * 64 + l];
    c = __builtin_amdgcn_mfma_f32_16x16x32_bf16(afrag0, bf0, c, 0, 0, 0);
    c = __builtin_amdgcn_mfma_f32_16x16x32_bf16(afrag1, bf1, c, 0, 0, 0);
    acc[nb] = c;
  }

  // ---- per-edge scale (reduce across the 16 d-lanes of this kg-group) ----
  float mx[4];
#pragma unroll
  for (int r = 0; r < 4; ++r) {
    float m = 0.0f;
#pragma unroll
    for (int c = 0; c < 16; ++c) m = fmaxf(m, fabsf(acc[c][r]));
    mx[r] = m;
  }
#pragma unroll
  for (int mask = 1; mask < 16; mask <<= 1) {
#pragma unroll
    for (int r = 0; r < 4; ++r) mx[r] = fmaxf(mx[r], __shfl_xor(mx[r], mask));
  }
  uint32 sb[4]; float sinv[4];
#pragma unroll
  for (int r = 0; r < 4; ++r) {
    sb[r] = f2bf_rne(mx[r] * (1.0f / 127.0f));
    float sd = bf2f((unsigned short)sb[r]);
    sinv[r] = (sd > 0.0f) ? (1.0f / sd) : 0.0f;
  }
  if (d == 0) {  // 4 edge scales (8B) for edges wid*16+kg*4 .. +3
    uint32 lo = sb[0] | (sb[1] << 16), hi = sb[2] | (sb[3] << 16);
    *reinterpret_cast<uint2*>(S + (size_t)wid * 16 + kg * 4) = make_uint2(lo, hi);
  }

  // ---- int8 quantize + store (lane-local rows) ----
#pragma unroll
  for (int r = 0; r < 4; ++r) {
    size_t er = (size_t)wid * 16 + kg * 4 + r;
    uint32 p[4];
#pragma unroll
    for (int q = 0; q < 4; ++q) {
      uint32 wv = 0;
#pragma unroll
      for (int b = 0; b < 4; ++b) {
        float qf = fminf(127.0f, fmaxf(-127.0f, rintf(acc[q * 4 + b][r] * sinv[r])));
        wv |= ((uint32)((int)qf & 255)) << (8 * b);
      }
      p[q] = wv;
    }
    *reinterpret_cast<uint4*>(W + (er << 8) + (d << 4)) = make_uint4(p[0], p[1], p[2], p[3]);
  }
}

// ---------- chunked-bf16 fallback fnet (plan 2) ----------
__device__ __forceinline__ void fnet_layer1(const float* __restrict__ ef, long long e,
                                            const float* __restrict__ w1,
                                            const float* __restrict__ b1,
                                            float* u) {
  float f[13];
#pragma unroll
  for (int i = 0; i < 13; ++i) f[i] = ef[(size_t)e * 13 + i];
#pragma unroll
  for (int k = 0; k < 64; ++k) u[k] = b1[k];
#pragma unroll
  for (int i = 0; i < 13; ++i) {
    float fi = f[i];
#pragma unroll
    for (int k = 0; k < 64; ++k) u[k] = fmaf(fi, w1[i * 64 + k], u[k]);
  }
#pragma unroll
  for (int k = 0; k < 64; ++k) u[k] = fmaxf(u[k], 0.0f);
}

__global__ __launch_bounds__(256) void fnet_bf16_kernel(
    const float* __restrict__ ef, const float* __restrict__ w1, const float* __restrict__ b1,
    const float* __restrict__ w2t, const float* __restrict__ b2,
    unsigned short* __restrict__ W, long long ebase, int ecnt) {
  int t = blockIdx.x * 256 + threadIdx.x;
  if (t >= ecnt) return;
  float u[64];
  fnet_layer1(ef, ebase + t, w1, b1, u);
#pragma unroll 1
  for (int dt = 0; dt < 8; ++dt) {  // 2 d's per tile -> 64B burst store
    uint32 p[16];
#pragma unroll
    for (int dd = 0; dd < 2; ++dd) {
      const int d = dt * 2 + dd;
      const float* wr = w2t + ((size_t)d << 10);
      float acc[16];
#pragma unroll
      for (int c = 0; c < 16; ++c) acc[c] = b2[c * 16 + d];
#pragma unroll
      for (int k = 0; k < 64; ++k) {
        float uk = u[k];
#pragma unroll
        for (int c = 0; c < 16; ++c) acc[c] = fmaf(uk, wr[k * 16 + c], acc[c]);
      }
#pragma unroll
      for (int q = 0; q < 8; ++q) p[dd * 8 + q] = packbf2(acc[2 * q], acc[2 * q + 1]);
    }
    uint4* dp = reinterpret_cast<uint4*>(W + ((size_t)t << 8) + (dt << 5));
    dp[0] = make_uint4(p[0], p[1], p[2], p[3]);
    dp[1] = make_uint4(p[4], p[5], p[6], p[7]);
    dp[2] = make_uint4(p[8], p[9], p[10], p[11]);
    dp[3] = make_uint4(p[12], p[13], p[14], p[15]);
  }
}

// ---------- gconv message + aggregate ----------
__global__ __launch_bounds__(256) void msg_bf16_kernel(
    const float* __restrict__ h, int h_ld,
    const unsigned short* __restrict__ W, long long ebase, int ecnt,
    const int* __restrict__ idxn, const int* __restrict__ edst,
    float* __restrict__ agg) {
  int t = blockIdx.x * 256 + threadIdx.x;
  if (t >= ecnt) return;
  int g = t >> 4, d = t & 15;
  int cur = -1;
  float acc = 0.0f;
  for (int s = 0; s < 16; ++s) {
    int erel = g * 16 + s;
    long long e = ebase + erel;
    int dst = edst[e];
    if (dst != cur) {
      if (cur >= 0) atomicAdd(&agg[(size_t)cur * 16 + d], acc);
      cur = dst; acc = 0.0f;
    }
    int src = idxn[e];
    const float4* hp = reinterpret_cast<const float4*>(h + (size_t)src * h_ld);
    float4 a0 = hp[0], a1 = hp[1], a2 = hp[2], a3 = hp[3];
    const uint4* wp = reinterpret_cast<const uint4*>(W + ((size_t)erel << 8) + (d << 4));
    uint4 w0 = wp[0], w1 = wp[1];
    acc = fmaf(a0.x, blo(w0.x), acc); acc = fmaf(a0.y, bhi(w0.x), acc);
    acc = fmaf(a0.z, blo(w0.y), acc); acc = fmaf(a0.w, bhi(w0.y), acc);
    acc = fmaf(a1.x, blo(w0.z), acc); acc = fmaf(a1.y, bhi(w0.z), acc);
    acc = fmaf(a1.z, blo(w0.w), acc); acc = fmaf(a1.w, bhi(w0.w), acc);
    acc = fmaf(a2.x, blo(w1.x), acc); acc = fmaf(a2.y, bhi(w1.x), acc);
    acc = fmaf(a2.z, blo(w1.y), acc); acc = fmaf(a2.w, bhi(w1.y), acc);
    acc = fmaf(a3.x, blo(w1.z), acc); acc = fmaf(a3.y, bhi(w1.z), acc);
    acc = fmaf(a3.z, blo(w1.w), acc); acc = fmaf(a3.w, bhi(w1.w), acc);
  }
  if (cur >= 0) atomicAdd(&agg[(size_t)cur * 16 + d], acc);
}

// 16 lanes (d) per strip of 16 consecutive edges; per-edge scale broadcast read;
// depth-1 prefetch; sorted edge_dst -> register run accumulation.
__global__ __launch_bounds__(256) void msg_i8_kernel(
    const float* __restrict__ h, int h_ld,
    const unsigned char* __restrict__ W, const unsigned short* __restrict__ S,
    const int* __restrict__ idxn, const int* __restrict__ edst,
    float* __restrict__ agg) {
  int t = blockIdx.x * 256 + threadIdx.x;
  if (t >= NE) return;
  const int g = t >> 4, d = t & 15;
  const int base = threadIdx.x & 48;  // first lane of this 16-group in the wave
  const int e0 = g * 16;

  // per-lane preload of the strip's edge indices (lane d owns edge e0+d)
  int my_dst = edst[e0 + d];
  int my_src = idxn[e0 + d];

  // prefetch edge 0
  int srcn = __shfl(my_src, base);
  const float4* hp = reinterpret_cast<const float4*>(h + (size_t)srcn * h_ld);
  float4 na0 = hp[0], na1 = hp[1], na2 = hp[2], na3 = hp[3];
  uint4 nwv = *reinterpret_cast<const uint4*>(W + ((size_t)e0 << 8) + (d << 4));
  float nsc = bf2f(S[e0]);

  int cur = -1;
  float acc = 0.0f;
#pragma unroll
  for (int s = 0; s < 16; ++s) {
    float4 a0 = na0, a1 = na1, a2 = na2, a3 = na3;
    uint4 wv = nwv;
    float sc = nsc;
    int dst = __shfl(my_dst, base + s);
    if (s < 15) {  // issue next-edge loads before computing (depth-1 pipeline)
      int sn = __shfl(my_src, base + s + 1);
      const float4* hq = reinterpret_cast<const float4*>(h + (size_t)sn * h_ld);
      na0 = hq[0]; na1 = hq[1]; na2 = hq[2]; na3 = hq[3];
      nwv = *reinterpret_cast<const uint4*>(W + ((size_t)(e0 + s + 1) << 8) + (d << 4));
      nsc = bf2f(S[e0 + s + 1]);
    }
    if (dst != cur) {
      if (cur >= 0) atomicAdd(&agg[(size_t)cur * 16 + d], acc);
      cur = dst; acc = 0.0f;
    }
    float r = 0.0f;
    r = fmaf(a0.x, sb2f(wv.x, 0), r); r = fmaf(a0.y, sb2f(wv.x, 1), r);
    r = fmaf(a0.z, sb2f(wv.x, 2), r); r = fmaf(a0.w, sb2f(wv.x, 3), r);
    r = fmaf(a1.x, sb2f(wv.y, 0), r); r = fmaf(a1.y, sb2f(wv.y, 1), r);
    r = fmaf(a1.z, sb2f(wv.y, 2), r); r = fmaf(a1.w, sb2f(wv.y, 3), r);
    r = fmaf(a2.x, sb2f(wv.z, 0), r); r = fmaf(a2.y, sb2f(wv.z, 1), r);
    r = fmaf(a2.z, sb2f(wv.z, 2), r); r = fmaf(a2.w, sb2f(wv.z, 3), r);
    r = fmaf(a3.x, sb2f(wv.w, 0), r); r = fmaf(a3.y, sb2f(wv.w, 1), r);
    r = fmaf(a3.z, sb2f(wv.w, 2), r); r = fmaf(a3.w, sb2f(wv.w, 3), r);
    acc = fmaf(r, sc, acc);
  }
  atomicAdd(&agg[(size_t)cur * 16 + d], acc);
}

// ---------- fused degree-normalize + GRU cell + skip-add + agg re-zero ----------
__global__ __launch_bounds__(256) void cell_kernel(
    float* agg, const float* __restrict__ invd,
    const float* __restrict__ hin, int hin_ld,
    const float* __restrict__ wih, const float* __restrict__ whh,
    const float* __restrict__ bih, const float* __restrict__ bhh,
    float* hout, int hout_ld,
    const float* sprev, int sprev_ld,
    float* sout, int sout_ld) {
  int n = blockIdx.x * 256 + threadIdx.x;
  if (n >= NN) return;
  float x[16], h[16];
  float inv = invd[n];
  float4* ap = reinterpret_cast<float4*>(agg + (size_t)n * 16);
  const float4* hp = reinterpret_cast<const float4*>(hin + (size_t)n * hin_ld);
#pragma unroll
  for (int q = 0; q < 4; ++q) {
    float4 a = ap[q];
    x[4 * q + 0] = a.x * inv; x[4 * q + 1] = a.y * inv;
    x[4 * q + 2] = a.z * inv; x[4 * q + 3] = a.w * inv;
    float4 hv = hp[q];
    h[4 * q + 0] = hv.x; h[4 * q + 1] = hv.y; h[4 * q + 2] = hv.z; h[4 * q + 3] = hv.w;
  }
  float4 zz = make_float4(0.f, 0.f, 0.f, 0.f);
#pragma unroll
  for (int q = 0; q < 4; ++q) ap[q] = zz;  // re-zero for next step
  float r[16], z[16], nn[16];
#pragma unroll
  for (int j = 0; j < 16; ++j) {
    float gi = bih[j], gh = bhh[j];
#pragma unroll
    for (int c = 0; c < 16; ++c) {
      gi = fmaf(x[c], wih[j * 16 + c], gi);
      gh = fmaf(h[c], whh[j * 16 + c], gh);
    }
    r[j] = 1.0f / (1.0f + expf(-(gi + gh)));
  }
#pragma unroll
  for (int j = 0; j < 16; ++j) {
    float gi = bih[16 + j], gh = bhh[16 + j];
#pragma unroll
    for (int c = 0; c < 16; ++c) {
      gi = fmaf(x[c], wih[(16 + j) * 16 + c], gi);
      gh = fmaf(h[c], whh[(16 + j) * 16 + c], gh);
    }
    z[j] = 1.0f / (1.0f + expf(-(gi + gh)));
  }
#pragma unroll
  for (int j = 0; j < 16; ++j) {
    float gi = bih[32 + j], gh = bhh[32 + j];
#pragma unroll
    for (int c = 0; c < 16; ++c) {
      gi = fmaf(x[c], wih[(32 + j) * 16 + c], gi);
      gh = fmaf(h[c], whh[(32 + j) * 16 + c], gh);
    }
    nn[j] = tanhf(gi + r[j] * gh);
  }
  float hv[16];
#pragma unroll
  for (int j = 0; j < 16; ++j) hv[j] = (1.0f - z[j]) * nn[j] + z[j] * h[j];

  float sv[16];
  bool do_s = (sprev != nullptr);
  if (do_s) {
    const float4* pp = reinterpret_cast<const float4*>(sprev + (size_t)n * sprev_ld);
#pragma unroll
    for (int q = 0; q < 4; ++q) {
      float4 p = pp[q];
      sv[4 * q + 0] = hv[4 * q + 0] + p.x; sv[4 * q + 1] = hv[4 * q + 1] + p.y;
      sv[4 * q + 2] = hv[4 * q + 2] + p.z; sv[4 * q + 3] = hv[4 * q + 3] + p.w;
    }
  }
  float4* hop = reinterpret_cast<float4*>(hout + (size_t)n * hout_ld);
#pragma unroll
  for (int q = 0; q < 4; ++q)
    hop[q] = make_float4(hv[4 * q], hv[4 * q + 1], hv[4 * q + 2], hv[4 * q + 3]);
  if (do_s) {
    float4* sp = reinterpret_cast<float4*>(sout + (size_t)n * sout_ld);
#pragma unroll
    for (int q = 0; q < 4; ++q)
      sp[q] = make_float4(sv[4 * q], sv[4 * q + 1], sv[4 * q + 2], sv[4 * q + 3]);
  }
}

extern "C" void kernel_launch(void* const* d_in, const int* in_sizes, int n_in,
                              void* d_out, int out_size, void* d_ws, size_t ws_size,
                              hipStream_t stream) {
  const float* hx   = (const float*)d_in[0];
  const float* ef   = (const float*)d_in[1];
  const int*   idxn = (const int*)d_in[2];
  const int*   edst = (const int*)d_in[3];
  const float* w1   = (const float*)d_in[4];
  const float* b1   = (const float*)d_in[5];
  const float* w2   = (const float*)d_in[6];
  const float* b2   = (const float*)d_in[7];
  const float* wih  = (const float*)d_in[8];
  const float* whh  = (const float*)d_in[9];
  const float* bih  = (const float*)d_in[10];
  const float* bhh  = (const float*)d_in[11];
  float* out = (float*)d_out;

  // workspace: invd | agg | w2f/w2t | W | S (per-edge bf16)
  const size_t INV_OFF = 0;
  const size_t AGG_OFF = 200064;              // NN*4 rounded up to 64
  const size_t W2T_OFF = 3400192;             // agg end rounded up to 256
  const size_t W_OFF   = W2T_OFF + 1048576;   // holds w2t (1MB) or w2f (32KB)
  if (ws_size < W_OFF + 1600 * 512) return;
  char* wsb = (char*)d_ws;
  float* invd = (float*)(wsb + INV_OFF);
  float* agg  = (float*)(wsb + AGG_OFF);
  float* w2t  = (float*)(wsb + W2T_OFF);
  unsigned short* w2f = (unsigned short*)(wsb + W2T_OFF);
  unsigned short* W16 = (unsigned short*)(wsb + W_OFF);
  unsigned char*  W8  = (unsigned char*)(wsb + W_OFF);
  unsigned short* S16 = (unsigned short*)(wsb + W_OFF + (size_t)NE * 256);
  size_t wrem = ws_size - W_OFF;

  int plan;       // 1 = int8 + MFMA fnet, 2 = chunked bf16
  size_t chunk = NE;
  if (wrem >= (size_t)NE * 260) plan = 1;   // W (256B/e) + S (2B/e) + slack
  else {
    plan = 2;
    chunk = (wrem / 512) & ~(size_t)15;
    if (chunk > NE) chunk = NE;
  }

  const int NB = (NN + 255) / 256;
  const int EB = (NE + 255) / 256;

  hipMemsetAsync(invd, 0, (size_t)NN * 4, stream);
  hipMemsetAsync(agg, 0, (size_t)NN * 64, stream);  // once; cell re-zeroes per step
  deg_count_kernel<<<EB, 256, 0, stream>>>(edst, invd);
  deg_inv_kernel<<<NB, 256, 0, stream>>>(invd);
  copy_col0_kernel<<<NB, 256, 0, stream>>>(hx, out);

  if (plan == 1) {
    repack_w2f_kernel<<<64, 256, 0, stream>>>(w2, w2f);
    fnet_mfma_i8_kernel<<<(NE / 16) / 4, 256, 0, stream>>>(ef, w1, b1, w2f, b2, W8, S16);
  } else {
    repack_w2_kernel<<<1024, 256, 0, stream>>>(w2, w2t);
  }

  auto col = [&](int c) { return out + (size_t)c * 16; };

  auto step = [&](const float* hin, int hin_ld, float* hout,
                  const float* sprev, float* sout) {
    if (plan == 1) {
      msg_i8_kernel<<<EB, 256, 0, stream>>>(hin, hin_ld, W8, S16, idxn, edst, agg);
    } else {
      for (size_t e0 = 0; e0 < NE; e0 += chunk) {
        int cnt = (int)(((size_t)NE - e0) < chunk ? ((size_t)NE - e0) : chunk);
        fnet_bf16_kernel<<<(cnt + 255) / 256, 256, 0, stream>>>(ef, w1, b1, w2t, b2, W16,
                                                                (long long)e0, cnt);
        msg_bf16_kernel<<<(cnt + 255) / 256, 256, 0, stream>>>(hin, hin_ld, W16,
                                                               (long long)e0, cnt,
                                                               idxn, edst, agg);
      }
    }
    cell_kernel<<<NB, 256, 0, stream>>>(agg, invd, hin, hin_ld, wih, whh, bih, bhh,
                                        hout, OUTC, sprev, OUTC, sout, OUTC);
  };

  // cols 0..10 = [hx,h1,h2,s1,h4,s2,h6,s3,h8,s4,h10]; col10 is the rotating stash
  // for h3/h5/h7/h9 (each overwritten after last use; h10 lands there finally).
  step(hx,      16,  col(1),  nullptr, nullptr);   // h1
  step(col(1), OUTC, col(2),  nullptr, nullptr);   // h2
  step(col(2), OUTC, col(10), col(1),  col(3));    // h3 -> stash, s1 = h1 + h3
  step(col(3), OUTC, col(4),  nullptr, nullptr);   // h4
  step(col(4), OUTC, col(10), col(10), col(5));    // h5 -> stash, s2 = h3 + h5
  step(col(5), OUTC, col(6),  nullptr, nullptr);   // h6
  step(col(6), OUTC, col(10), col(10), col(7));    // h7 -> stash, s3 = h5 + h7
  step(col(7), OUTC, col(8),  nullptr, nullptr);   // h8
  step(col(8), OUTC, col(10), col(10), col(9));    // h9 -> stash, s4 = h7 + h9
  step(col(9), OUTC, col(10), nullptr, nullptr);   // h10 (final, overwrites stash)
}

// Round 10
// 1053.536 us; speedup vs baseline: 2.8613x; 1.0019x over previous
//
#include <hip/hip_runtime.h>

#define NN 50000
#define NE 800000
#define OUTC 176  // 11 * 16

typedef unsigned int uint32;
typedef short bf16x8 __attribute__((ext_vector_type(8)));
typedef float f32x4 __attribute__((ext_vector_type(4)));

// ---------- bf16 helpers (manual, RNE) ----------
__device__ __forceinline__ uint32 f2bf_rne(float f) {
  union { float f; uint32 u; } v; v.f = f;
  uint32 u = v.u;
  return (u + 0x7FFFu + ((u >> 16) & 1u)) >> 16;
}
__device__ __forceinline__ uint32 packbf2(float a, float b) {
  return f2bf_rne(a) | (f2bf_rne(b) << 16);
}
__device__ __forceinline__ float blo(uint32 u) {
  union { uint32 x; float f; } t; t.x = u << 16; return t.f;
}
__device__ __forceinline__ float bhi(uint32 u) {
  union { uint32 x; float f; } t; t.x = u & 0xFFFF0000u; return t.f;
}
__device__ __forceinline__ float bf2f(unsigned short v) {
  union { uint32 x; float f; } t; t.x = ((uint32)v) << 16; return t.f;
}
// signed byte b (0..3) of packed word -> float
__device__ __forceinline__ float sb2f(uint32 w, int b) {
  return (float)((int)(w << (24 - 8 * b)) >> 24);
}

// ---------- small kernels ----------
__global__ __launch_bounds__(256) void deg_count_kernel(const int* __restrict__ edst,
                                                        float* __restrict__ deg) {
  int e = blockIdx.x * 256 + threadIdx.x;
  if (e < NE) atomicAdd(&deg[edst[e]], 1.0f);
}

__global__ __launch_bounds__(256) void deg_inv_kernel(float* __restrict__ deg) {
  int n = blockIdx.x * 256 + threadIdx.x;
  if (n < NN) deg[n] = 1.0f / fmaxf(deg[n], 1.0f);
}

__global__ __launch_bounds__(256) void copy_col0_kernel(const float* __restrict__ hx,
                                                        float* __restrict__ out) {
  int n = blockIdx.x * 256 + threadIdx.x;
  if (n >= NN) return;
  const float4* s = reinterpret_cast<const float4*>(hx + (size_t)n * 16);
  float4* d = reinterpret_cast<float4*>(out + (size_t)n * OUTC);
  d[0] = s[0]; d[1] = s[1]; d[2] = s[2]; d[3] = s[3];
}

// w2t[d][k][c] = w2[k*256 + c*16 + d]  (for the chunked-bf16 fallback plan)
__global__ __launch_bounds__(256) void repack_w2_kernel(const float* __restrict__ w2,
                                                        float* __restrict__ w2t) {
  int i = blockIdx.x * 256 + threadIdx.x;
  if (i >= 256 * 1024) return;
  int d = i >> 10, r = i & 1023, k = r >> 4, c = r & 15;
  w2t[i] = w2[k * 256 + c * 16 + d];
}

// w2 -> bf16 MFMA B-fragment layout (32 KB)
__global__ __launch_bounds__(256) void repack_w2f_kernel(const float* __restrict__ w2,
                                                         unsigned short* __restrict__ w2f) {
  int i = blockIdx.x * 256 + threadIdx.x;  // 0..16383
  if (i >= 16384) return;
  int jj = i & 7;
  int l = (i >> 3) & 63;
  int nbm = i >> 9;  // nb*2+m
  int m = nbm & 1, nb = nbm >> 1;
  int k = m * 32 + (l >> 4) * 8 + jj;
  int j = nb * 16 + (l & 15);
  w2f[i] = (unsigned short)f2bf_rne(w2[k * 256 + j]);
}

// ---------- MFMA fnet: fused layer1 + 16x256x64 GEMM + int8 quantize ----------
// One wave per 16-edge tile; launched in 4 chunks (wave offset wo) so each
// dispatch is shorter than a msg dispatch (profiling visibility).
__global__ __launch_bounds__(256) void fnet_mfma_i8_kernel(
    const float* __restrict__ ef, const float* __restrict__ w1, const float* __restrict__ b1,
    const unsigned short* __restrict__ w2f, const float* __restrict__ b2,
    unsigned char* __restrict__ W, unsigned short* __restrict__ S, int wo) {
  int wid = wo + ((blockIdx.x * 256 + threadIdx.x) >> 6);
  int l = threadIdx.x & 63;
  if (wid >= NE / 16) return;
  const int d = l & 15, kg = l >> 4;

  // ---- layer1 ----
  size_t e1 = (size_t)wid * 16 + d;
  float f[13];
#pragma unroll
  for (int i = 0; i < 13; ++i) f[i] = ef[e1 * 13 + i];
  float ua[8], ub[8];
#pragma unroll
  for (int j = 0; j < 8; ++j) { ua[j] = b1[kg * 8 + j]; ub[j] = b1[32 + kg * 8 + j]; }
#pragma unroll
  for (int i = 0; i < 13; ++i) {
    const float4* wa = reinterpret_cast<const float4*>(w1 + i * 64 + kg * 8);
    const float4* wb = reinterpret_cast<const float4*>(w1 + i * 64 + 32 + kg * 8);
    float4 a0 = wa[0], a1 = wa[1], c0 = wb[0], c1 = wb[1];
    float fi = f[i];
    ua[0] = fmaf(fi, a0.x, ua[0]); ua[1] = fmaf(fi, a0.y, ua[1]);
    ua[2] = fmaf(fi, a0.z, ua[2]); ua[3] = fmaf(fi, a0.w, ua[3]);
    ua[4] = fmaf(fi, a1.x, ua[4]); ua[5] = fmaf(fi, a1.y, ua[5]);
    ua[6] = fmaf(fi, a1.z, ua[6]); ua[7] = fmaf(fi, a1.w, ua[7]);
    ub[0] = fmaf(fi, c0.x, ub[0]); ub[1] = fmaf(fi, c0.y, ub[1]);
    ub[2] = fmaf(fi, c0.z, ub[2]); ub[3] = fmaf(fi, c0.w, ub[3]);
    ub[4] = fmaf(fi, c1.x, ub[4]); ub[5] = fmaf(fi, c1.y, ub[5]);
    ub[6] = fmaf(fi, c1.z, ub[6]); ub[7] = fmaf(fi, c1.w, ub[7]);
  }
  bf16x8 afrag0, afrag1;
#pragma unroll
  for (int j = 0; j < 8; ++j) {
    afrag0[j] = (short)f2bf_rne(fmaxf(ua[j], 0.0f));
    afrag1[j] = (short)f2bf_rne(fmaxf(ub[j], 0.0f));
  }

  // ---- GEMM: 16 edges x 256 outputs, K=64 ----
  const bf16x8* Bp = reinterpret_cast<const bf16x8*>(w2f);
  f32x4 acc[16];
#pragma unroll
  for (int nb = 0; nb < 16; ++nb) {
    float bias = b2[nb * 16 + d];
    f32x4 c; c[0] = bias; c[1] = bias; c[2] = bias; c[3] = bias;
    bf16x8 bf0 = Bp[(nb * 2 + 0) * 64 + l];
    bf16x8 bf1 = Bp[(nb * 2 + 1) * 64 + l];
    c = __builtin_amdgcn_mfma_f32_16x16x32_bf16(afrag0, bf0, c, 0, 0, 0);
    c = __builtin_amdgcn_mfma_f32_16x16x32_bf16(afrag1, bf1, c, 0, 0, 0);
    acc[nb] = c;
  }

  // ---- per-edge scale (reduce across the 16 d-lanes of this kg-group) ----
  float mx[4];
#pragma unroll
  for (int r = 0; r < 4; ++r) {
    float m = 0.0f;
#pragma unroll
    for (int c = 0; c < 16; ++c) m = fmaxf(m, fabsf(acc[c][r]));
    mx[r] = m;
  }
#pragma unroll
  for (int mask = 1; mask < 16; mask <<= 1) {
#pragma unroll
    for (int r = 0; r < 4; ++r) mx[r] = fmaxf(mx[r], __shfl_xor(mx[r], mask));
  }
  uint32 sb[4]; float sinv[4];
#pragma unroll
  for (int r = 0; r < 4; ++r) {
    sb[r] = f2bf_rne(mx[r] * (1.0f / 127.0f));
    float sd = bf2f((unsigned short)sb[r]);
    sinv[r] = (sd > 0.0f) ? (1.0f / sd) : 0.0f;
  }
  if (d == 0) {  // 4 edge scales (8B) for edges wid*16+kg*4 .. +3
    uint32 lo = sb[0] | (sb[1] << 16), hi = sb[2] | (sb[3] << 16);
    *reinterpret_cast<uint2*>(S + (size_t)wid * 16 + kg * 4) = make_uint2(lo, hi);
  }

  // ---- int8 quantize + store (lane-local rows) ----
#pragma unroll
  for (int r = 0; r < 4; ++r) {
    size_t er = (size_t)wid * 16 + kg * 4 + r;
    uint32 p[4];
#pragma unroll
    for (int q = 0; q < 4; ++q) {
      uint32 wv = 0;
#pragma unroll
      for (int b = 0; b < 4; ++b) {
        float qf = fminf(127.0f, fmaxf(-127.0f, rintf(acc[q * 4 + b][r] * sinv[r])));
        wv |= ((uint32)((int)qf & 255)) << (8 * b);
      }
      p[q] = wv;
    }
    *reinterpret_cast<uint4*>(W + (er << 8) + (d << 4)) = make_uint4(p[0], p[1], p[2], p[3]);
  }
}

// ---------- chunked-bf16 fallback fnet (plan 2) ----------
__device__ __forceinline__ void fnet_layer1(const float* __restrict__ ef, long long e,
                                            const float* __restrict__ w1,
                                            const float* __restrict__ b1,
                                            float* u) {
  float f[13];
#pragma unroll
  for (int i = 0; i < 13; ++i) f[i] = ef[(size_t)e * 13 + i];
#pragma unroll
  for (int k = 0; k < 64; ++k) u[k] = b1[k];
#pragma unroll
  for (int i = 0; i < 13; ++i) {
    float fi = f[i];
#pragma unroll
    for (int k = 0; k < 64; ++k) u[k] = fmaf(fi, w1[i * 64 + k], u[k]);
  }
#pragma unroll
  for (int k = 0; k < 64; ++k) u[k] = fmaxf(u[k], 0.0f);
}

__global__ __launch_bounds__(256) void fnet_bf16_kernel(
    const float* __restrict__ ef, const float* __restrict__ w1, const float* __restrict__ b1,
    const float* __restrict__ w2t, const float* __restrict__ b2,
    unsigned short* __restrict__ W, long long ebase, int ecnt) {
  int t = blockIdx.x * 256 + threadIdx.x;
  if (t >= ecnt) return;
  float u[64];
  fnet_layer1(ef, ebase + t, w1, b1, u);
#pragma unroll 1
  for (int dt = 0; dt < 8; ++dt) {
    uint32 p[16];
#pragma unroll
    for (int dd = 0; dd < 2; ++dd) {
      const int d = dt * 2 + dd;
      const float* wr = w2t + ((size_t)d << 10);
      float acc[16];
#pragma unroll
      for (int c = 0; c < 16; ++c) acc[c] = b2[c * 16 + d];
#pragma unroll
      for (int k = 0; k < 64; ++k) {
        float uk = u[k];
#pragma unroll
        for (int c = 0; c < 16; ++c) acc[c] = fmaf(uk, wr[k * 16 + c], acc[c]);
      }
#pragma unroll
      for (int q = 0; q < 8; ++q) p[dd * 8 + q] = packbf2(acc[2 * q], acc[2 * q + 1]);
    }
    uint4* dp = reinterpret_cast<uint4*>(W + ((size_t)t << 8) + (dt << 5));
    dp[0] = make_uint4(p[0], p[1], p[2], p[3]);
    dp[1] = make_uint4(p[4], p[5], p[6], p[7]);
    dp[2] = make_uint4(p[8], p[9], p[10], p[11]);
    dp[3] = make_uint4(p[12], p[13], p[14], p[15]);
  }
}

// ---------- gconv message + aggregate ----------
__global__ __launch_bounds__(256) void msg_bf16_kernel(
    const float* __restrict__ h, int h_ld,
    const unsigned short* __restrict__ W, long long ebase, int ecnt,
    const int* __restrict__ idxn, const int* __restrict__ edst,
    float* __restrict__ agg) {
  int t = blockIdx.x * 256 + threadIdx.x;
  if (t >= ecnt) return;
  int g = t >> 4, d = t & 15;
  int cur = -1;
  float acc = 0.0f;
  for (int s = 0; s < 16; ++s) {
    int erel = g * 16 + s;
    long long e = ebase + erel;
    int dst = edst[e];
    if (dst != cur) {
      if (cur >= 0) atomicAdd(&agg[(size_t)cur * 16 + d], acc);
      cur = dst; acc = 0.0f;
    }
    int src = idxn[e];
    const float4* hp = reinterpret_cast<const float4*>(h + (size_t)src * h_ld);
    float4 a0 = hp[0], a1 = hp[1], a2 = hp[2], a3 = hp[3];
    const uint4* wp = reinterpret_cast<const uint4*>(W + ((size_t)erel << 8) + (d << 4));
    uint4 w0 = wp[0], w1 = wp[1];
    acc = fmaf(a0.x, blo(w0.x), acc); acc = fmaf(a0.y, bhi(w0.x), acc);
    acc = fmaf(a0.z, blo(w0.y), acc); acc = fmaf(a0.w, bhi(w0.y), acc);
    acc = fmaf(a1.x, blo(w0.z), acc); acc = fmaf(a1.y, bhi(w0.z), acc);
    acc = fmaf(a1.z, blo(w0.w), acc); acc = fmaf(a1.w, bhi(w0.w), acc);
    acc = fmaf(a2.x, blo(w1.x), acc); acc = fmaf(a2.y, bhi(w1.x), acc);
    acc = fmaf(a2.z, blo(w1.y), acc); acc = fmaf(a2.w, bhi(w1.y), acc);
    acc = fmaf(a3.x, blo(w1.z), acc); acc = fmaf(a3.y, bhi(w1.z), acc);
    acc = fmaf(a3.z, blo(w1.w), acc); acc = fmaf(a3.w, bhi(w1.w), acc);
  }
  if (cur >= 0) atomicAdd(&agg[(size_t)cur * 16 + d], acc);
}

// 16 lanes (d) per strip of 16 consecutive edges; h gathered from the DENSE
// hd buffer (3.2MB, L2-resident); per-edge scale broadcast; depth-1 prefetch.
__global__ __launch_bounds__(256) void msg_i8_kernel(
    const float* __restrict__ h, int h_ld,
    const unsigned char* __restrict__ W, const unsigned short* __restrict__ S,
    const int* __restrict__ idxn, const int* __restrict__ edst,
    float* __restrict__ agg) {
  int t = blockIdx.x * 256 + threadIdx.x;
  if (t >= NE) return;
  const int g = t >> 4, d = t & 15;
  const int base = threadIdx.x & 48;  // first lane of this 16-group in the wave
  const int e0 = g * 16;

  int my_dst = edst[e0 + d];
  int my_src = idxn[e0 + d];

  int srcn = __shfl(my_src, base);
  const float4* hp = reinterpret_cast<const float4*>(h + (size_t)srcn * h_ld);
  float4 na0 = hp[0], na1 = hp[1], na2 = hp[2], na3 = hp[3];
  uint4 nwv = *reinterpret_cast<const uint4*>(W + ((size_t)e0 << 8) + (d << 4));
  float nsc = bf2f(S[e0]);

  int cur = -1;
  float acc = 0.0f;
#pragma unroll
  for (int s = 0; s < 16; ++s) {
    float4 a0 = na0, a1 = na1, a2 = na2, a3 = na3;
    uint4 wv = nwv;
    float sc = nsc;
    int dst = __shfl(my_dst, base + s);
    if (s < 15) {
      int sn = __shfl(my_src, base + s + 1);
      const float4* hq = reinterpret_cast<const float4*>(h + (size_t)sn * h_ld);
      na0 = hq[0]; na1 = hq[1]; na2 = hq[2]; na3 = hq[3];
      nwv = *reinterpret_cast<const uint4*>(W + ((size_t)(e0 + s + 1) << 8) + (d << 4));
      nsc = bf2f(S[e0 + s + 1]);
    }
    if (dst != cur) {
      if (cur >= 0) atomicAdd(&agg[(size_t)cur * 16 + d], acc);
      cur = dst; acc = 0.0f;
    }
    float r = 0.0f;
    r = fmaf(a0.x, sb2f(wv.x, 0), r); r = fmaf(a0.y, sb2f(wv.x, 1), r);
    r = fmaf(a0.z, sb2f(wv.x, 2), r); r = fmaf(a0.w, sb2f(wv.x, 3), r);
    r = fmaf(a1.x, sb2f(wv.y, 0), r); r = fmaf(a1.y, sb2f(wv.y, 1), r);
    r = fmaf(a1.z, sb2f(wv.y, 2), r); r = fmaf(a1.w, sb2f(wv.y, 3), r);
    r = fmaf(a2.x, sb2f(wv.z, 0), r); r = fmaf(a2.y, sb2f(wv.z, 1), r);
    r = fmaf(a2.z, sb2f(wv.z, 2), r); r = fmaf(a2.w, sb2f(wv.z, 3), r);
    r = fmaf(a3.x, sb2f(wv.w, 0), r); r = fmaf(a3.y, sb2f(wv.w, 1), r);
    r = fmaf(a3.z, sb2f(wv.w, 2), r); r = fmaf(a3.w, sb2f(wv.w, 3), r);
    acc = fmaf(r, sc, acc);
  }
  atomicAdd(&agg[(size_t)cur * 16 + d], acc);
}

// ---------- fused degree-normalize + GRU cell + skip-add + agg re-zero ----------
// Also writes the NEXT step's msg input (h or s) into the dense hd buffer.
// hout/sprev/hdn may alias buffers read earlier -> reads happen before writes.
__global__ __launch_bounds__(256) void cell_kernel(
    float* agg, const float* __restrict__ invd,
    const float* hin, int hin_ld,
    const float* __restrict__ wih, const float* __restrict__ whh,
    const float* __restrict__ bih, const float* __restrict__ bhh,
    float* hout, int hout_ld,
    const float* sprev, int sprev_ld,
    float* sout, int sout_ld,
    float* hdn) {
  int n = blockIdx.x * 256 + threadIdx.x;
  if (n >= NN) return;
  float x[16], h[16];
  float inv = invd[n];
  float4* ap = reinterpret_cast<float4*>(agg + (size_t)n * 16);
  const float4* hp = reinterpret_cast<const float4*>(hin + (size_t)n * hin_ld);
#pragma unroll
  for (int q = 0; q < 4; ++q) {
    float4 a = ap[q];
    x[4 * q + 0] = a.x * inv; x[4 * q + 1] = a.y * inv;
    x[4 * q + 2] = a.z * inv; x[4 * q + 3] = a.w * inv;
    float4 hv = hp[q];
    h[4 * q + 0] = hv.x; h[4 * q + 1] = hv.y; h[4 * q + 2] = hv.z; h[4 * q + 3] = hv.w;
  }
  float4 zz = make_float4(0.f, 0.f, 0.f, 0.f);
#pragma unroll
  for (int q = 0; q < 4; ++q) ap[q] = zz;  // re-zero for next step
  float r[16], z[16], nn[16];
#pragma unroll
  for (int j = 0; j < 16; ++j) {
    float gi = bih[j], gh = bhh[j];
#pragma unroll
    for (int c = 0; c < 16; ++c) {
      gi = fmaf(x[c], wih[j * 16 + c], gi);
      gh = fmaf(h[c], whh[j * 16 + c], gh);
    }
    r[j] = 1.0f / (1.0f + expf(-(gi + gh)));
  }
#pragma unroll
  for (int j = 0; j < 16; ++j) {
    float gi = bih[16 + j], gh = bhh[16 + j];
#pragma unroll
    for (int c = 0; c < 16; ++c) {
      gi = fmaf(x[c], wih[(16 + j) * 16 + c], gi);
      gh = fmaf(h[c], whh[(16 + j) * 16 + c], gh);
    }
    z[j] = 1.0f / (1.0f + expf(-(gi + gh)));
  }
#pragma unroll
  for (int j = 0; j < 16; ++j) {
    float gi = bih[32 + j], gh = bhh[32 + j];
#pragma unroll
    for (int c = 0; c < 16; ++c) {
      gi = fmaf(x[c], wih[(32 + j) * 16 + c], gi);
      gh = fmaf(h[c], whh[(32 + j) * 16 + c], gh);
    }
    nn[j] = tanhf(gi + r[j] * gh);
  }
  float hv[16];
#pragma unroll
  for (int j = 0; j < 16; ++j) hv[j] = (1.0f - z[j]) * nn[j] + z[j] * h[j];

  float sv[16];
  bool do_s = (sprev != nullptr);
  if (do_s) {
    const float4* pp = reinterpret_cast<const float4*>(sprev + (size_t)n * sprev_ld);
#pragma unroll
    for (int q = 0; q < 4; ++q) {
      float4 p = pp[q];
      sv[4 * q + 0] = hv[4 * q + 0] + p.x; sv[4 * q + 1] = hv[4 * q + 1] + p.y;
      sv[4 * q + 2] = hv[4 * q + 2] + p.z; sv[4 * q + 3] = hv[4 * q + 3] + p.w;
    }
  }
  float4* hop = reinterpret_cast<float4*>(hout + (size_t)n * hout_ld);
#pragma unroll
  for (int q = 0; q < 4; ++q)
    hop[q] = make_float4(hv[4 * q], hv[4 * q + 1], hv[4 * q + 2], hv[4 * q + 3]);
  if (do_s) {
    float4* sp = reinterpret_cast<float4*>(sout + (size_t)n * sout_ld);
#pragma unroll
    for (int q = 0; q < 4; ++q)
      sp[q] = make_float4(sv[4 * q], sv[4 * q + 1], sv[4 * q + 2], sv[4 * q + 3]);
  }
  if (hdn != nullptr) {  // next step's dense input = s (if skip) else h
    float4* dp = reinterpret_cast<float4*>(hdn + (size_t)n * 16);
    if (do_s) {
#pragma unroll
      for (int q = 0; q < 4; ++q)
        dp[q] = make_float4(sv[4 * q], sv[4 * q + 1], sv[4 * q + 2], sv[4 * q + 3]);
    } else {
#pragma unroll
      for (int q = 0; q < 4; ++q)
        dp[q] = make_float4(hv[4 * q], hv[4 * q + 1], hv[4 * q + 2], hv[4 * q + 3]);
    }
  }
}

extern "C" void kernel_launch(void* const* d_in, const int* in_sizes, int n_in,
                              void* d_out, int out_size, void* d_ws, size_t ws_size,
                              hipStream_t stream) {
  const float* hx   = (const float*)d_in[0];
  const float* ef   = (const float*)d_in[1];
  const int*   idxn = (const int*)d_in[2];
  const int*   edst = (const int*)d_in[3];
  const float* w1   = (const float*)d_in[4];
  const float* b1   = (const float*)d_in[5];
  const float* w2   = (const float*)d_in[6];
  const float* b2   = (const float*)d_in[7];
  const float* wih  = (const float*)d_in[8];
  const float* whh  = (const float*)d_in[9];
  const float* bih  = (const float*)d_in[10];
  const float* bhh  = (const float*)d_in[11];
  float* out = (float*)d_out;

  // workspace: invd | agg | w2f/w2t | hd (dense h) | W | S
  const size_t INV_OFF = 0;
  const size_t AGG_OFF = 200064;                // NN*4 rounded up
  const size_t W2T_OFF = 3400192;               // agg end rounded up
  const size_t HD_OFF  = W2T_OFF + 1048576;     // 4,448,768
  const size_t W_OFF   = HD_OFF + (size_t)NN * 64;  // + 3.2MB = 7,648,768
  if (ws_size < W_OFF + 1600 * 512) return;
  char* wsb = (char*)d_ws;
  float* invd = (float*)(wsb + INV_OFF);
  float* agg  = (float*)(wsb + AGG_OFF);
  float* w2t  = (float*)(wsb + W2T_OFF);
  unsigned short* w2f = (unsigned short*)(wsb + W2T_OFF);
  float* hd   = (float*)(wsb + HD_OFF);
  unsigned short* W16 = (unsigned short*)(wsb + W_OFF);
  unsigned char*  W8  = (unsigned char*)(wsb + W_OFF);
  unsigned short* S16 = (unsigned short*)(wsb + W_OFF + (size_t)NE * 256);
  size_t wrem = ws_size - W_OFF;

  int plan;       // 1 = int8 + MFMA fnet, 2 = chunked bf16
  size_t chunk = NE;
  if (wrem >= (size_t)NE * 260) plan = 1;   // W (256B/e) + S (2B/e) + slack
  else {
    plan = 2;
    chunk = (wrem / 512) & ~(size_t)15;
    if (chunk > NE) chunk = NE;
  }

  const int NB = (NN + 255) / 256;
  const int EB = (NE + 255) / 256;

  hipMemsetAsync(invd, 0, (size_t)NN * 4, stream);
  hipMemsetAsync(agg, 0, (size_t)NN * 64, stream);  // once; cell re-zeroes per step
  deg_count_kernel<<<EB, 256, 0, stream>>>(edst, invd);
  deg_inv_kernel<<<NB, 256, 0, stream>>>(invd);
  copy_col0_kernel<<<NB, 256, 0, stream>>>(hx, out);

  if (plan == 1) {
    repack_w2f_kernel<<<64, 256, 0, stream>>>(w2, w2f);
    // 4 chunks of 12500 waves (200K edges) each -> each dispatch ~50us
    for (int c = 0; c < 4; ++c)
      fnet_mfma_i8_kernel<<<3125, 256, 0, stream>>>(ef, w1, b1, w2f, b2, W8, S16,
                                                    c * 12500);
  } else {
    repack_w2_kernel<<<1024, 256, 0, stream>>>(w2, w2t);
  }

  auto col = [&](int c) { return out + (size_t)c * 16; };

  auto step = [&](const float* hin, int hin_ld, float* hout,
                  const float* sprev, float* sout, float* hdn) {
    if (plan == 1) {
      msg_i8_kernel<<<EB, 256, 0, stream>>>(hin, hin_ld, W8, S16, idxn, edst, agg);
    } else {
      for (size_t e0 = 0; e0 < NE; e0 += chunk) {
        int cnt = (int)(((size_t)NE - e0) < chunk ? ((size_t)NE - e0) : chunk);
        fnet_bf16_kernel<<<(cnt + 255) / 256, 256, 0, stream>>>(ef, w1, b1, w2t, b2, W16,
                                                                (long long)e0, cnt);
        msg_bf16_kernel<<<(cnt + 255) / 256, 256, 0, stream>>>(hin, hin_ld, W16,
                                                               (long long)e0, cnt,
                                                               idxn, edst, agg);
      }
    }
    cell_kernel<<<NB, 256, 0, stream>>>(agg, invd, hin, hin_ld, wih, whh, bih, bhh,
                                        hout, OUTC, sprev, OUTC, sout, OUTC, hdn);
  };

  // cols 0..10 = [hx,h1,h2,s1,h4,s2,h6,s3,h8,s4,h10]; col10 = rotating stash for
  // h3/h5/h7/h9. hd always holds the NEXT step's dense input (h or s post-skip).
  step(hx, 16, col(1),  nullptr, nullptr, hd);   // h1 -> hd
  step(hd, 16, col(2),  nullptr, nullptr, hd);   // h2 -> hd
  step(hd, 16, col(10), col(1),  col(3),  hd);   // h3 stash; s1 -> hd
  step(hd, 16, col(4),  nullptr, nullptr, hd);   // h4 -> hd
  step(hd, 16, col(10), col(10), col(5),  hd);   // h5 stash; s2 -> hd
  step(hd, 16, col(6),  nullptr, nullptr, hd);   // h6 -> hd
  step(hd, 16, col(10), col(10), col(7),  hd);   // h7 stash; s3 -> hd
  step(hd, 16, col(8),  nullptr, nullptr, hd);   // h8 -> hd
  step(hd, 16, col(10), col(10), col(9),  hd);   // h9 stash; s4 -> hd
  step(hd, 16, col(10), nullptr, nullptr, nullptr);  // h10 (final)
}

// Round 11
// 1000.736 us; speedup vs baseline: 3.0123x; 1.0528x over previous
//
#include <hip/hip_runtime.h>

#define NN 50000
#define NE 800000
#define OUTC 176  // 11 * 16

typedef unsigned int uint32;
typedef short bf16x8 __attribute__((ext_vector_type(8)));
typedef float f32x4 __attribute__((ext_vector_type(4)));

// ---------- bf16 helpers (manual, RNE) ----------
__device__ __forceinline__ uint32 f2bf_rne(float f) {
  union { float f; uint32 u; } v; v.f = f;
  uint32 u = v.u;
  return (u + 0x7FFFu + ((u >> 16) & 1u)) >> 16;
}
__device__ __forceinline__ uint32 packbf2(float a, float b) {
  return f2bf_rne(a) | (f2bf_rne(b) << 16);
}
__device__ __forceinline__ float blo(uint32 u) {
  union { uint32 x; float f; } t; t.x = u << 16; return t.f;
}
__device__ __forceinline__ float bhi(uint32 u) {
  union { uint32 x; float f; } t; t.x = u & 0xFFFF0000u; return t.f;
}
__device__ __forceinline__ float bf2f(unsigned short v) {
  union { uint32 x; float f; } t; t.x = ((uint32)v) << 16; return t.f;
}
// signed byte b (0..3) of packed word -> float
__device__ __forceinline__ float sb2f(uint32 w, int b) {
  return (float)((int)(w << (24 - 8 * b)) >> 24);
}

// ---------- small kernels ----------
__global__ __launch_bounds__(256) void deg_count_kernel(const int* __restrict__ edst,
                                                        float* __restrict__ deg) {
  int e = blockIdx.x * 256 + threadIdx.x;
  if (e < NE) atomicAdd(&deg[edst[e]], 1.0f);
}

__global__ __launch_bounds__(256) void deg_inv_kernel(float* __restrict__ deg) {
  int n = blockIdx.x * 256 + threadIdx.x;
  if (n < NN) deg[n] = 1.0f / fmaxf(deg[n], 1.0f);
}

__global__ __launch_bounds__(256) void copy_col0_kernel(const float* __restrict__ hx,
                                                        float* __restrict__ out) {
  int n = blockIdx.x * 256 + threadIdx.x;
  if (n >= NN) return;
  const float4* s = reinterpret_cast<const float4*>(hx + (size_t)n * 16);
  float4* d = reinterpret_cast<float4*>(out + (size_t)n * OUTC);
  d[0] = s[0]; d[1] = s[1]; d[2] = s[2]; d[3] = s[3];
}

// w2t[d][k][c] = w2[k*256 + c*16 + d]  (for the chunked-bf16 fallback plan)
__global__ __launch_bounds__(256) void repack_w2_kernel(const float* __restrict__ w2,
                                                        float* __restrict__ w2t) {
  int i = blockIdx.x * 256 + threadIdx.x;
  if (i >= 256 * 1024) return;
  int d = i >> 10, r = i & 1023, k = r >> 4, c = r & 15;
  w2t[i] = w2[k * 256 + c * 16 + d];
}

// w2 -> bf16 MFMA B-fragment layout (32 KB)
__global__ __launch_bounds__(256) void repack_w2f_kernel(const float* __restrict__ w2,
                                                         unsigned short* __restrict__ w2f) {
  int i = blockIdx.x * 256 + threadIdx.x;  // 0..16383
  if (i >= 16384) return;
  int jj = i & 7;
  int l = (i >> 3) & 63;
  int nbm = i >> 9;  // nb*2+m
  int m = nbm & 1, nb = nbm >> 1;
  int k = m * 32 + (l >> 4) * 8 + jj;
  int j = nb * 16 + (l & 15);
  w2f[i] = (unsigned short)f2bf_rne(w2[k * 256 + j]);
}

// ---------- MFMA fnet: fused layer1 + 16x256x64 GEMM + int8 quantize ----------
// One wave per 16-edge tile, 4 waves/block; ef staged via LDS (208 coalesced
// float4 loads/block replaces 13 scattered dword loads/lane -> kills the
// latency chain behind R10's 32% VALUBusy). Chunked by wo for profiling.
__global__ __launch_bounds__(256) void fnet_mfma_i8_kernel(
    const float* __restrict__ ef, const float* __restrict__ w1, const float* __restrict__ b1,
    const unsigned short* __restrict__ w2f, const float* __restrict__ b2,
    unsigned char* __restrict__ W, unsigned short* __restrict__ S, int wo) {
  __shared__ float efs[832];  // 64 edges x 13 feats
  const int wave = threadIdx.x >> 6;
  const int l = threadIdx.x & 63;
  const int wid = wo + blockIdx.x * 4 + wave;  // always < NE/16 (exact chunks)
  const int d = l & 15, kg = l >> 4;

  // stage ef for the block's 64 edges (3328B, 16B-aligned)
  long long E0 = ((long long)wo + (long long)blockIdx.x * 4) * 16;
  if (threadIdx.x < 208) {
    reinterpret_cast<float4*>(efs)[threadIdx.x] =
        reinterpret_cast<const float4*>(ef + E0 * 13)[threadIdx.x];
  }
  __syncthreads();

  // ---- layer1 (f from LDS; stride-13 word reads are conflict-free) ----
  const int eloc = wave * 16 + d;
  float f[13];
#pragma unroll
  for (int i = 0; i < 13; ++i) f[i] = efs[eloc * 13 + i];
  float ua[8], ub[8];
#pragma unroll
  for (int j = 0; j < 8; ++j) { ua[j] = b1[kg * 8 + j]; ub[j] = b1[32 + kg * 8 + j]; }
#pragma unroll
  for (int i = 0; i < 13; ++i) {
    const float4* wa = reinterpret_cast<const float4*>(w1 + i * 64 + kg * 8);
    const float4* wb = reinterpret_cast<const float4*>(w1 + i * 64 + 32 + kg * 8);
    float4 a0 = wa[0], a1 = wa[1], c0 = wb[0], c1 = wb[1];
    float fi = f[i];
    ua[0] = fmaf(fi, a0.x, ua[0]); ua[1] = fmaf(fi, a0.y, ua[1]);
    ua[2] = fmaf(fi, a0.z, ua[2]); ua[3] = fmaf(fi, a0.w, ua[3]);
    ua[4] = fmaf(fi, a1.x, ua[4]); ua[5] = fmaf(fi, a1.y, ua[5]);
    ua[6] = fmaf(fi, a1.z, ua[6]); ua[7] = fmaf(fi, a1.w, ua[7]);
    ub[0] = fmaf(fi, c0.x, ub[0]); ub[1] = fmaf(fi, c0.y, ub[1]);
    ub[2] = fmaf(fi, c0.z, ub[2]); ub[3] = fmaf(fi, c0.w, ub[3]);
    ub[4] = fmaf(fi, c1.x, ub[4]); ub[5] = fmaf(fi, c1.y, ub[5]);
    ub[6] = fmaf(fi, c1.z, ub[6]); ub[7] = fmaf(fi, c1.w, ub[7]);
  }
  bf16x8 afrag0, afrag1;
#pragma unroll
  for (int j = 0; j < 8; ++j) {
    afrag0[j] = (short)f2bf_rne(fmaxf(ua[j], 0.0f));
    afrag1[j] = (short)f2bf_rne(fmaxf(ub[j], 0.0f));
  }

  // ---- GEMM: 16 edges x 256 outputs, K=64 ----
  const bf16x8* Bp = reinterpret_cast<const bf16x8*>(w2f);
  f32x4 acc[16];
#pragma unroll
  for (int nb = 0; nb < 16; ++nb) {
    float bias = b2[nb * 16 + d];
    f32x4 c; c[0] = bias; c[1] = bias; c[2] = bias; c[3] = bias;
    bf16x8 bf0 = Bp[(nb * 2 + 0) * 64 + l];
    bf16x8 bf1 = Bp[(nb * 2 + 1) * 64 + l];
    c = __builtin_amdgcn_mfma_f32_16x16x32_bf16(afrag0, bf0, c, 0, 0, 0);
    c = __builtin_amdgcn_mfma_f32_16x16x32_bf16(afrag1, bf1, c, 0, 0, 0);
    acc[nb] = c;
  }

  // ---- per-edge scale (reduce across the 16 d-lanes of this kg-group) ----
  float mx[4];
#pragma unroll
  for (int r = 0; r < 4; ++r) {
    float m = 0.0f;
#pragma unroll
    for (int c = 0; c < 16; ++c) m = fmaxf(m, fabsf(acc[c][r]));
    mx[r] = m;
  }
#pragma unroll
  for (int mask = 1; mask < 16; mask <<= 1) {
#pragma unroll
    for (int r = 0; r < 4; ++r) mx[r] = fmaxf(mx[r], __shfl_xor(mx[r], mask));
  }
  uint32 sb[4]; float sinv[4];
#pragma unroll
  for (int r = 0; r < 4; ++r) {
    sb[r] = f2bf_rne(mx[r] * (1.0f / 127.0f));
    float sd = bf2f((unsigned short)sb[r]);
    sinv[r] = (sd > 0.0f) ? (1.0f / sd) : 0.0f;
  }
  if (d == 0) {
    uint32 lo = sb[0] | (sb[1] << 16), hi = sb[2] | (sb[3] << 16);
    *reinterpret_cast<uint2*>(S + (size_t)wid * 16 + kg * 4) = make_uint2(lo, hi);
  }

  // ---- int8 quantize + store (lane-local rows) ----
#pragma unroll
  for (int r = 0; r < 4; ++r) {
    size_t er = (size_t)wid * 16 + kg * 4 + r;
    uint32 p[4];
#pragma unroll
    for (int q = 0; q < 4; ++q) {
      uint32 wv = 0;
#pragma unroll
      for (int b = 0; b < 4; ++b) {
        float qf = fminf(127.0f, fmaxf(-127.0f, rintf(acc[q * 4 + b][r] * sinv[r])));
        wv |= ((uint32)((int)qf & 255)) << (8 * b);
      }
      p[q] = wv;
    }
    *reinterpret_cast<uint4*>(W + (er << 8) + (d << 4)) = make_uint4(p[0], p[1], p[2], p[3]);
  }
}

// ---------- chunked-bf16 fallback fnet (plan 2) ----------
__device__ __forceinline__ void fnet_layer1(const float* __restrict__ ef, long long e,
                                            const float* __restrict__ w1,
                                            const float* __restrict__ b1,
                                            float* u) {
  float f[13];
#pragma unroll
  for (int i = 0; i < 13; ++i) f[i] = ef[(size_t)e * 13 + i];
#pragma unroll
  for (int k = 0; k < 64; ++k) u[k] = b1[k];
#pragma unroll
  for (int i = 0; i < 13; ++i) {
    float fi = f[i];
#pragma unroll
    for (int k = 0; k < 64; ++k) u[k] = fmaf(fi, w1[i * 64 + k], u[k]);
  }
#pragma unroll
  for (int k = 0; k < 64; ++k) u[k] = fmaxf(u[k], 0.0f);
}

__global__ __launch_bounds__(256) void fnet_bf16_kernel(
    const float* __restrict__ ef, const float* __restrict__ w1, const float* __restrict__ b1,
    const float* __restrict__ w2t, const float* __restrict__ b2,
    unsigned short* __restrict__ W, long long ebase, int ecnt) {
  int t = blockIdx.x * 256 + threadIdx.x;
  if (t >= ecnt) return;
  float u[64];
  fnet_layer1(ef, ebase + t, w1, b1, u);
#pragma unroll 1
  for (int dt = 0; dt < 8; ++dt) {
    uint32 p[16];
#pragma unroll
    for (int dd = 0; dd < 2; ++dd) {
      const int d = dt * 2 + dd;
      const float* wr = w2t + ((size_t)d << 10);
      float acc[16];
#pragma unroll
      for (int c = 0; c < 16; ++c) acc[c] = b2[c * 16 + d];
#pragma unroll
      for (int k = 0; k < 64; ++k) {
        float uk = u[k];
#pragma unroll
        for (int c = 0; c < 16; ++c) acc[c] = fmaf(uk, wr[k * 16 + c], acc[c]);
      }
#pragma unroll
      for (int q = 0; q < 8; ++q) p[dd * 8 + q] = packbf2(acc[2 * q], acc[2 * q + 1]);
    }
    uint4* dp = reinterpret_cast<uint4*>(W + ((size_t)t << 8) + (dt << 5));
    dp[0] = make_uint4(p[0], p[1], p[2], p[3]);
    dp[1] = make_uint4(p[4], p[5], p[6], p[7]);
    dp[2] = make_uint4(p[8], p[9], p[10], p[11]);
    dp[3] = make_uint4(p[12], p[13], p[14], p[15]);
  }
}

// ---------- gconv message + aggregate ----------
__global__ __launch_bounds__(256) void msg_bf16_kernel(
    const float* __restrict__ h, int h_ld,
    const unsigned short* __restrict__ W, long long ebase, int ecnt,
    const int* __restrict__ idxn, const int* __restrict__ edst,
    float* __restrict__ agg) {
  int t = blockIdx.x * 256 + threadIdx.x;
  if (t >= ecnt) return;
  int g = t >> 4, d = t & 15;
  int cur = -1;
  float acc = 0.0f;
  for (int s = 0; s < 16; ++s) {
    int erel = g * 16 + s;
    long long e = ebase + erel;
    int dst = edst[e];
    if (dst != cur) {
      if (cur >= 0) atomicAdd(&agg[(size_t)cur * 16 + d], acc);
      cur = dst; acc = 0.0f;
    }
    int src = idxn[e];
    const float4* hp = reinterpret_cast<const float4*>(h + (size_t)src * h_ld);
    float4 a0 = hp[0], a1 = hp[1], a2 = hp[2], a3 = hp[3];
    const uint4* wp = reinterpret_cast<const uint4*>(W + ((size_t)erel << 8) + (d << 4));
    uint4 w0 = wp[0], w1 = wp[1];
    acc = fmaf(a0.x, blo(w0.x), acc); acc = fmaf(a0.y, bhi(w0.x), acc);
    acc = fmaf(a0.z, blo(w0.y), acc); acc = fmaf(a0.w, bhi(w0.y), acc);
    acc = fmaf(a1.x, blo(w0.z), acc); acc = fmaf(a1.y, bhi(w0.z), acc);
    acc = fmaf(a1.z, blo(w0.w), acc); acc = fmaf(a1.w, bhi(w0.w), acc);
    acc = fmaf(a2.x, blo(w1.x), acc); acc = fmaf(a2.y, bhi(w1.x), acc);
    acc = fmaf(a2.z, blo(w1.y), acc); acc = fmaf(a2.w, bhi(w1.y), acc);
    acc = fmaf(a3.x, blo(w1.z), acc); acc = fmaf(a3.y, bhi(w1.z), acc);
    acc = fmaf(a3.z, blo(w1.w), acc); acc = fmaf(a3.w, bhi(w1.w), acc);
  }
  if (cur >= 0) atomicAdd(&agg[(size_t)cur * 16 + d], acc);
}

// 16 lanes (d) per strip of 16 consecutive edges; h gathered from dense hd
// (3.2MB, L2-resident); per-edge scale; depth-1 prefetch; run accumulation.
__global__ __launch_bounds__(256) void msg_i8_kernel(
    const float* __restrict__ h, int h_ld,
    const unsigned char* __restrict__ W, const unsigned short* __restrict__ S,
    const int* __restrict__ idxn, const int* __restrict__ edst,
    float* __restrict__ agg) {
  int t = blockIdx.x * 256 + threadIdx.x;
  if (t >= NE) return;
  const int g = t >> 4, d = t & 15;
  const int base = threadIdx.x & 48;
  const int e0 = g * 16;

  int my_dst = edst[e0 + d];
  int my_src = idxn[e0 + d];

  int srcn = __shfl(my_src, base);
  const float4* hp = reinterpret_cast<const float4*>(h + (size_t)srcn * h_ld);
  float4 na0 = hp[0], na1 = hp[1], na2 = hp[2], na3 = hp[3];
  uint4 nwv = *reinterpret_cast<const uint4*>(W + ((size_t)e0 << 8) + (d << 4));
  float nsc = bf2f(S[e0]);

  int cur = -1;
  float acc = 0.0f;
#pragma unroll
  for (int s = 0; s < 16; ++s) {
    float4 a0 = na0, a1 = na1, a2 = na2, a3 = na3;
    uint4 wv = nwv;
    float sc = nsc;
    int dst = __shfl(my_dst, base + s);
    if (s < 15) {
      int sn = __shfl(my_src, base + s + 1);
      const float4* hq = reinterpret_cast<const float4*>(h + (size_t)sn * h_ld);
      na0 = hq[0]; na1 = hq[1]; na2 = hq[2]; na3 = hq[3];
      nwv = *reinterpret_cast<const uint4*>(W + ((size_t)(e0 + s + 1) << 8) + (d << 4));
      nsc = bf2f(S[e0 + s + 1]);
    }
    if (dst != cur) {
      if (cur >= 0) atomicAdd(&agg[(size_t)cur * 16 + d], acc);
      cur = dst; acc = 0.0f;
    }
    float r = 0.0f;
    r = fmaf(a0.x, sb2f(wv.x, 0), r); r = fmaf(a0.y, sb2f(wv.x, 1), r);
    r = fmaf(a0.z, sb2f(wv.x, 2), r); r = fmaf(a0.w, sb2f(wv.x, 3), r);
    r = fmaf(a1.x, sb2f(wv.y, 0), r); r = fmaf(a1.y, sb2f(wv.y, 1), r);
    r = fmaf(a1.z, sb2f(wv.y, 2), r); r = fmaf(a1.w, sb2f(wv.y, 3), r);
    r = fmaf(a2.x, sb2f(wv.z, 0), r); r = fmaf(a2.y, sb2f(wv.z, 1), r);
    r = fmaf(a2.z, sb2f(wv.z, 2), r); r = fmaf(a2.w, sb2f(wv.z, 3), r);
    r = fmaf(a3.x, sb2f(wv.w, 0), r); r = fmaf(a3.y, sb2f(wv.w, 1), r);
    r = fmaf(a3.z, sb2f(wv.w, 2), r); r = fmaf(a3.w, sb2f(wv.w, 3), r);
    acc = fmaf(r, sc, acc);
  }
  atomicAdd(&agg[(size_t)cur * 16 + d], acc);
}

// ---------- GRU cell: 16 lanes per node (800K threads -> latency hidden) ----------
// Lane j of node-group computes gate-row j. hout/sprev may alias (col10 stash):
// each thread reads sprev[n,j] before writing hout[n,j] (same element, same
// thread -> ordered). agg zeroing is done by a separate memset per step.
__global__ __launch_bounds__(256) void cell_kernel(
    const float* __restrict__ agg, const float* __restrict__ invd,
    const float* hin, int hin_ld,
    const float* __restrict__ wih, const float* __restrict__ whh,
    const float* __restrict__ bih, const float* __restrict__ bhh,
    float* hout, int hout_ld,
    const float* sprev, int sprev_ld,
    float* sout, int sout_ld,
    float* hdn) {
  int t = blockIdx.x * 256 + threadIdx.x;
  int n = t >> 4, j = t & 15;
  if (n >= NN) return;
  float inv = invd[n];
  float x[16], h[16];
  const float4* ap = reinterpret_cast<const float4*>(agg + (size_t)n * 16);
  const float4* hp = reinterpret_cast<const float4*>(hin + (size_t)n * hin_ld);
#pragma unroll
  for (int q = 0; q < 4; ++q) {
    float4 a = ap[q];  // broadcast across the 16 lanes of the group
    x[4 * q + 0] = a.x * inv; x[4 * q + 1] = a.y * inv;
    x[4 * q + 2] = a.z * inv; x[4 * q + 3] = a.w * inv;
    float4 hv4 = hp[q];
    h[4 * q + 0] = hv4.x; h[4 * q + 1] = hv4.y;
    h[4 * q + 2] = hv4.z; h[4 * q + 3] = hv4.w;
  }
  const float4* wr4 = reinterpret_cast<const float4*>(wih + j * 16);
  const float4* wz4 = reinterpret_cast<const float4*>(wih + (16 + j) * 16);
  const float4* wn4 = reinterpret_cast<const float4*>(wih + (32 + j) * 16);
  const float4* vr4 = reinterpret_cast<const float4*>(whh + j * 16);
  const float4* vz4 = reinterpret_cast<const float4*>(whh + (16 + j) * 16);
  const float4* vn4 = reinterpret_cast<const float4*>(whh + (32 + j) * 16);
  float gr = bih[j], gz = bih[16 + j], gn = bih[32 + j];
  float hr = bhh[j], hz = bhh[16 + j], hn = bhh[32 + j];
#pragma unroll
  for (int q = 0; q < 4; ++q) {
    float4 wr = wr4[q], wz = wz4[q], wn = wn4[q];
    float4 vr = vr4[q], vz = vz4[q], vn = vn4[q];
    gr = fmaf(x[4 * q + 0], wr.x, gr); gr = fmaf(x[4 * q + 1], wr.y, gr);
    gr = fmaf(x[4 * q + 2], wr.z, gr); gr = fmaf(x[4 * q + 3], wr.w, gr);
    gz = fmaf(x[4 * q + 0], wz.x, gz); gz = fmaf(x[4 * q + 1], wz.y, gz);
    gz = fmaf(x[4 * q + 2], wz.z, gz); gz = fmaf(x[4 * q + 3], wz.w, gz);
    gn = fmaf(x[4 * q + 0], wn.x, gn); gn = fmaf(x[4 * q + 1], wn.y, gn);
    gn = fmaf(x[4 * q + 2], wn.z, gn); gn = fmaf(x[4 * q + 3], wn.w, gn);
    hr = fmaf(h[4 * q + 0], vr.x, hr); hr = fmaf(h[4 * q + 1], vr.y, hr);
    hr = fmaf(h[4 * q + 2], vr.z, hr); hr = fmaf(h[4 * q + 3], vr.w, hr);
    hz = fmaf(h[4 * q + 0], vz.x, hz); hz = fmaf(h[4 * q + 1], vz.y, hz);
    hz = fmaf(h[4 * q + 2], vz.z, hz); hz = fmaf(h[4 * q + 3], vz.w, hz);
    hn = fmaf(h[4 * q + 0], vn.x, hn); hn = fmaf(h[4 * q + 1], vn.y, hn);
    hn = fmaf(h[4 * q + 2], vn.z, hn); hn = fmaf(h[4 * q + 3], vn.w, hn);
  }
  float r = 1.0f / (1.0f + expf(-(gr + hr)));
  float z = 1.0f / (1.0f + expf(-(gz + hz)));
  float nng = tanhf(gn + r * hn);
  float hv = (1.0f - z) * nng + z * h[j];

  bool do_s = (sprev != nullptr);
  float sv = 0.0f;
  if (do_s) sv = hv + sprev[(size_t)n * sprev_ld + j];
  hout[(size_t)n * hout_ld + j] = hv;
  if (do_s) sout[(size_t)n * sout_ld + j] = sv;
  if (hdn != nullptr) hdn[(size_t)n * 16 + j] = do_s ? sv : hv;
}

extern "C" void kernel_launch(void* const* d_in, const int* in_sizes, int n_in,
                              void* d_out, int out_size, void* d_ws, size_t ws_size,
                              hipStream_t stream) {
  const float* hx   = (const float*)d_in[0];
  const float* ef   = (const float*)d_in[1];
  const int*   idxn = (const int*)d_in[2];
  const int*   edst = (const int*)d_in[3];
  const float* w1   = (const float*)d_in[4];
  const float* b1   = (const float*)d_in[5];
  const float* w2   = (const float*)d_in[6];
  const float* b2   = (const float*)d_in[7];
  const float* wih  = (const float*)d_in[8];
  const float* whh  = (const float*)d_in[9];
  const float* bih  = (const float*)d_in[10];
  const float* bhh  = (const float*)d_in[11];
  float* out = (float*)d_out;

  // workspace: invd | agg | w2f/w2t | hd (dense h) | W | S
  const size_t INV_OFF = 0;
  const size_t AGG_OFF = 200064;
  const size_t W2T_OFF = 3400192;
  const size_t HD_OFF  = W2T_OFF + 1048576;
  const size_t W_OFF   = HD_OFF + (size_t)NN * 64;
  if (ws_size < W_OFF + 1600 * 512) return;
  char* wsb = (char*)d_ws;
  float* invd = (float*)(wsb + INV_OFF);
  float* agg  = (float*)(wsb + AGG_OFF);
  float* w2t  = (float*)(wsb + W2T_OFF);
  unsigned short* w2f = (unsigned short*)(wsb + W2T_OFF);
  float* hd   = (float*)(wsb + HD_OFF);
  unsigned short* W16 = (unsigned short*)(wsb + W_OFF);
  unsigned char*  W8  = (unsigned char*)(wsb + W_OFF);
  unsigned short* S16 = (unsigned short*)(wsb + W_OFF + (size_t)NE * 256);
  size_t wrem = ws_size - W_OFF;

  int plan;       // 1 = int8 + MFMA fnet, 2 = chunked bf16
  size_t chunk = NE;
  if (wrem >= (size_t)NE * 260) plan = 1;
  else {
    plan = 2;
    chunk = (wrem / 512) & ~(size_t)15;
    if (chunk > NE) chunk = NE;
  }

  const int NB  = (NN + 255) / 256;
  const int EB  = (NE + 255) / 256;
  const int CB  = (NN * 16 + 255) / 256;  // cell: 16 lanes/node

  hipMemsetAsync(invd, 0, (size_t)NN * 4, stream);
  deg_count_kernel<<<EB, 256, 0, stream>>>(edst, invd);
  deg_inv_kernel<<<NB, 256, 0, stream>>>(invd);
  copy_col0_kernel<<<NB, 256, 0, stream>>>(hx, out);

  if (plan == 1) {
    repack_w2f_kernel<<<64, 256, 0, stream>>>(w2, w2f);
    for (int c = 0; c < 4; ++c)
      fnet_mfma_i8_kernel<<<3125, 256, 0, stream>>>(ef, w1, b1, w2f, b2, W8, S16,
                                                    c * 12500);
  } else {
    repack_w2_kernel<<<1024, 256, 0, stream>>>(w2, w2t);
  }

  auto col = [&](int c) { return out + (size_t)c * 16; };

  auto step = [&](const float* hin, int hin_ld, float* hout,
                  const float* sprev, float* sout, float* hdn) {
    hipMemsetAsync(agg, 0, (size_t)NN * 64, stream);
    if (plan == 1) {
      msg_i8_kernel<<<EB, 256, 0, stream>>>(hin, hin_ld, W8, S16, idxn, edst, agg);
    } else {
      for (size_t e0 = 0; e0 < NE; e0 += chunk) {
        int cnt = (int)(((size_t)NE - e0) < chunk ? ((size_t)NE - e0) : chunk);
        fnet_bf16_kernel<<<(cnt + 255) / 256, 256, 0, stream>>>(ef, w1, b1, w2t, b2, W16,
                                                                (long long)e0, cnt);
        msg_bf16_kernel<<<(cnt + 255) / 256, 256, 0, stream>>>(hin, hin_ld, W16,
                                                               (long long)e0, cnt,
                                                               idxn, edst, agg);
      }
    }
    cell_kernel<<<CB, 256, 0, stream>>>(agg, invd, hin, hin_ld, wih, whh, bih, bhh,
                                        hout, OUTC, sprev, OUTC, sout, OUTC, hdn);
  };

  // cols 0..10 = [hx,h1,h2,s1,h4,s2,h6,s3,h8,s4,h10]; col10 = rotating stash for
  // h3/h5/h7/h9. hd always holds the NEXT step's dense input (h or s post-skip).
  step(hx, 16, col(1),  nullptr, nullptr, hd);   // h1 -> hd
  step(hd, 16, col(2),  nullptr, nullptr, hd);   // h2 -> hd
  step(hd, 16, col(10), col(1),  col(3),  hd);   // h3 stash; s1 -> hd
  step(hd, 16, col(4),  nullptr, nullptr, hd);   // h4 -> hd
  step(hd, 16, col(10), col(10), col(5),  hd);   // h5 stash; s2 -> hd
  step(hd, 16, col(6),  nullptr, nullptr, hd);   // h6 -> hd
  step(hd, 16, col(10), col(10), col(7),  hd);   // h7 stash; s3 -> hd
  step(hd, 16, col(8),  nullptr, nullptr, hd);   // h8 -> hd
  step(hd, 16, col(10), col(10), col(9),  hd);   // h9 stash; s4 -> hd
  step(hd, 16, col(10), nullptr, nullptr, nullptr);  // h10 (final)
}

// Round 12
// 988.264 us; speedup vs baseline: 3.0503x; 1.0126x over previous
//
#include <hip/hip_runtime.h>

#define NN 50000
#define NE 800000
#define OUTC 176  // 11 * 16

typedef unsigned int uint32;
typedef short bf16x8 __attribute__((ext_vector_type(8)));
typedef float f32x4 __attribute__((ext_vector_type(4)));

// ---------- bf16 helpers (manual, RNE) ----------
__device__ __forceinline__ uint32 f2bf_rne(float f) {
  union { float f; uint32 u; } v; v.f = f;
  uint32 u = v.u;
  return (u + 0x7FFFu + ((u >> 16) & 1u)) >> 16;
}
__device__ __forceinline__ uint32 packbf2(float a, float b) {
  return f2bf_rne(a) | (f2bf_rne(b) << 16);
}
__device__ __forceinline__ float blo(uint32 u) {
  union { uint32 x; float f; } t; t.x = u << 16; return t.f;
}
__device__ __forceinline__ float bhi(uint32 u) {
  union { uint32 x; float f; } t; t.x = u & 0xFFFF0000u; return t.f;
}
__device__ __forceinline__ float bf2f(unsigned short v) {
  union { uint32 x; float f; } t; t.x = ((uint32)v) << 16; return t.f;
}
// signed byte b (0..3) of packed word -> float
__device__ __forceinline__ float sb2f(uint32 w, int b) {
  return (float)((int)(w << (24 - 8 * b)) >> 24);
}

// ---------- small kernels ----------
__global__ __launch_bounds__(256) void deg_count_kernel(const int* __restrict__ edst,
                                                        float* __restrict__ deg) {
  int e = blockIdx.x * 256 + threadIdx.x;
  if (e < NE) atomicAdd(&deg[edst[e]], 1.0f);
}

__global__ __launch_bounds__(256) void deg_inv_kernel(float* __restrict__ deg) {
  int n = blockIdx.x * 256 + threadIdx.x;
  if (n < NN) deg[n] = 1.0f / fmaxf(deg[n], 1.0f);
}

__global__ __launch_bounds__(256) void copy_col0_kernel(const float* __restrict__ hx,
                                                        float* __restrict__ out) {
  int n = blockIdx.x * 256 + threadIdx.x;
  if (n >= NN) return;
  const float4* s = reinterpret_cast<const float4*>(hx + (size_t)n * 16);
  float4* d = reinterpret_cast<float4*>(out + (size_t)n * OUTC);
  d[0] = s[0]; d[1] = s[1]; d[2] = s[2]; d[3] = s[3];
}

// w2t[d][k][c] = w2[k*256 + c*16 + d]  (for the chunked-bf16 fallback plan)
__global__ __launch_bounds__(256) void repack_w2_kernel(const float* __restrict__ w2,
                                                        float* __restrict__ w2t) {
  int i = blockIdx.x * 256 + threadIdx.x;
  if (i >= 256 * 1024) return;
  int d = i >> 10, r = i & 1023, k = r >> 4, c = r & 15;
  w2t[i] = w2[k * 256 + c * 16 + d];
}

// w2 -> bf16 MFMA B-fragment layout (32 KB)
__global__ __launch_bounds__(256) void repack_w2f_kernel(const float* __restrict__ w2,
                                                         unsigned short* __restrict__ w2f) {
  int i = blockIdx.x * 256 + threadIdx.x;  // 0..16383
  if (i >= 16384) return;
  int jj = i & 7;
  int l = (i >> 3) & 63;
  int nbm = i >> 9;  // nb*2+m
  int m = nbm & 1, nb = nbm >> 1;
  int k = m * 32 + (l >> 4) * 8 + jj;
  int j = nb * 16 + (l & 15);
  w2f[i] = (unsigned short)f2bf_rne(w2[k * 256 + j]);
}

// ---------- MFMA fnet: fused layer1 + 16x256x64 GEMM + int8 quantize ----------
// One wave per 16-edge tile, 4 waves/block. ef staged in LDS; w2f fragments
// staged in LDS (32KB) so the nb-loop reads ds_read_b128 (fine-pipelined
// lgkmcnt) instead of 32 L2-latency VMEM loads (R11: VALUBusy 33%, 55us).
__global__ __launch_bounds__(256) void fnet_mfma_i8_kernel(
    const float* __restrict__ ef, const float* __restrict__ w1, const float* __restrict__ b1,
    const unsigned short* __restrict__ w2f, const float* __restrict__ b2,
    unsigned char* __restrict__ W, unsigned short* __restrict__ S, int wo) {
  __shared__ float efs[832];          // 64 edges x 13 feats
  __shared__ short w2s[16384];        // full B fragments, 32KB
  const int wave = threadIdx.x >> 6;
  const int l = threadIdx.x & 63;
  const int wid = wo + blockIdx.x * 4 + wave;
  const int d = l & 15, kg = l >> 4;

  // stage w2f (8 x 16B per thread) and ef (3328B)
#pragma unroll
  for (int i = 0; i < 8; ++i)
    reinterpret_cast<uint4*>(w2s)[threadIdx.x + 256 * i] =
        reinterpret_cast<const uint4*>(w2f)[threadIdx.x + 256 * i];
  long long E0 = ((long long)wo + (long long)blockIdx.x * 4) * 16;
  if (threadIdx.x < 208) {
    reinterpret_cast<float4*>(efs)[threadIdx.x] =
        reinterpret_cast<const float4*>(ef + E0 * 13)[threadIdx.x];
  }
  __syncthreads();

  // ---- layer1 (f from LDS) ----
  const int eloc = wave * 16 + d;
  float f[13];
#pragma unroll
  for (int i = 0; i < 13; ++i) f[i] = efs[eloc * 13 + i];
  float ua[8], ub[8];
#pragma unroll
  for (int j = 0; j < 8; ++j) { ua[j] = b1[kg * 8 + j]; ub[j] = b1[32 + kg * 8 + j]; }
#pragma unroll
  for (int i = 0; i < 13; ++i) {
    const float4* wa = reinterpret_cast<const float4*>(w1 + i * 64 + kg * 8);
    const float4* wb = reinterpret_cast<const float4*>(w1 + i * 64 + 32 + kg * 8);
    float4 a0 = wa[0], a1 = wa[1], c0 = wb[0], c1 = wb[1];
    float fi = f[i];
    ua[0] = fmaf(fi, a0.x, ua[0]); ua[1] = fmaf(fi, a0.y, ua[1]);
    ua[2] = fmaf(fi, a0.z, ua[2]); ua[3] = fmaf(fi, a0.w, ua[3]);
    ua[4] = fmaf(fi, a1.x, ua[4]); ua[5] = fmaf(fi, a1.y, ua[5]);
    ua[6] = fmaf(fi, a1.z, ua[6]); ua[7] = fmaf(fi, a1.w, ua[7]);
    ub[0] = fmaf(fi, c0.x, ub[0]); ub[1] = fmaf(fi, c0.y, ub[1]);
    ub[2] = fmaf(fi, c0.z, ub[2]); ub[3] = fmaf(fi, c0.w, ub[3]);
    ub[4] = fmaf(fi, c1.x, ub[4]); ub[5] = fmaf(fi, c1.y, ub[5]);
    ub[6] = fmaf(fi, c1.z, ub[6]); ub[7] = fmaf(fi, c1.w, ub[7]);
  }
  bf16x8 afrag0, afrag1;
#pragma unroll
  for (int j = 0; j < 8; ++j) {
    afrag0[j] = (short)f2bf_rne(fmaxf(ua[j], 0.0f));
    afrag1[j] = (short)f2bf_rne(fmaxf(ub[j], 0.0f));
  }

  // bias row for this lane (16 independent loads, issued upfront)
  float bias[16];
#pragma unroll
  for (int nb = 0; nb < 16; ++nb) bias[nb] = b2[nb * 16 + d];

  // ---- GEMM: 16 edges x 256 outputs, K=64 (B from LDS) ----
  const bf16x8* Bp = reinterpret_cast<const bf16x8*>(w2s);
  f32x4 acc[16];
#pragma unroll
  for (int nb = 0; nb < 16; ++nb) {
    f32x4 c; c[0] = bias[nb]; c[1] = bias[nb]; c[2] = bias[nb]; c[3] = bias[nb];
    bf16x8 bf0 = Bp[(nb * 2 + 0) * 64 + l];
    bf16x8 bf1 = Bp[(nb * 2 + 1) * 64 + l];
    c = __builtin_amdgcn_mfma_f32_16x16x32_bf16(afrag0, bf0, c, 0, 0, 0);
    c = __builtin_amdgcn_mfma_f32_16x16x32_bf16(afrag1, bf1, c, 0, 0, 0);
    acc[nb] = c;
  }

  // ---- per-edge scale (reduce across the 16 d-lanes of this kg-group) ----
  float mx[4];
#pragma unroll
  for (int r = 0; r < 4; ++r) {
    float m = 0.0f;
#pragma unroll
    for (int c = 0; c < 16; ++c) m = fmaxf(m, fabsf(acc[c][r]));
    mx[r] = m;
  }
#pragma unroll
  for (int mask = 1; mask < 16; mask <<= 1) {
#pragma unroll
    for (int r = 0; r < 4; ++r) mx[r] = fmaxf(mx[r], __shfl_xor(mx[r], mask));
  }
  uint32 sb[4]; float sinv[4];
#pragma unroll
  for (int r = 0; r < 4; ++r) {
    sb[r] = f2bf_rne(mx[r] * (1.0f / 127.0f));
    float sd = bf2f((unsigned short)sb[r]);
    sinv[r] = (sd > 0.0f) ? (1.0f / sd) : 0.0f;
  }
  if (d == 0) {
    uint32 lo = sb[0] | (sb[1] << 16), hi = sb[2] | (sb[3] << 16);
    *reinterpret_cast<uint2*>(S + (size_t)wid * 16 + kg * 4) = make_uint2(lo, hi);
  }

  // ---- int8 quantize + store (lane-local rows) ----
#pragma unroll
  for (int r = 0; r < 4; ++r) {
    size_t er = (size_t)wid * 16 + kg * 4 + r;
    uint32 p[4];
#pragma unroll
    for (int q = 0; q < 4; ++q) {
      uint32 wv = 0;
#pragma unroll
      for (int b = 0; b < 4; ++b) {
        float qf = fminf(127.0f, fmaxf(-127.0f, rintf(acc[q * 4 + b][r] * sinv[r])));
        wv |= ((uint32)((int)qf & 255)) << (8 * b);
      }
      p[q] = wv;
    }
    *reinterpret_cast<uint4*>(W + (er << 8) + (d << 4)) = make_uint4(p[0], p[1], p[2], p[3]);
  }
}

// ---------- chunked-bf16 fallback fnet (plan 2) ----------
__device__ __forceinline__ void fnet_layer1(const float* __restrict__ ef, long long e,
                                            const float* __restrict__ w1,
                                            const float* __restrict__ b1,
                                            float* u) {
  float f[13];
#pragma unroll
  for (int i = 0; i < 13; ++i) f[i] = ef[(size_t)e * 13 + i];
#pragma unroll
  for (int k = 0; k < 64; ++k) u[k] = b1[k];
#pragma unroll
  for (int i = 0; i < 13; ++i) {
    float fi = f[i];
#pragma unroll
    for (int k = 0; k < 64; ++k) u[k] = fmaf(fi, w1[i * 64 + k], u[k]);
  }
#pragma unroll
  for (int k = 0; k < 64; ++k) u[k] = fmaxf(u[k], 0.0f);
}

__global__ __launch_bounds__(256) void fnet_bf16_kernel(
    const float* __restrict__ ef, const float* __restrict__ w1, const float* __restrict__ b1,
    const float* __restrict__ w2t, const float* __restrict__ b2,
    unsigned short* __restrict__ W, long long ebase, int ecnt) {
  int t = blockIdx.x * 256 + threadIdx.x;
  if (t >= ecnt) return;
  float u[64];
  fnet_layer1(ef, ebase + t, w1, b1, u);
#pragma unroll 1
  for (int dt = 0; dt < 8; ++dt) {
    uint32 p[16];
#pragma unroll
    for (int dd = 0; dd < 2; ++dd) {
      const int d = dt * 2 + dd;
      const float* wr = w2t + ((size_t)d << 10);
      float acc[16];
#pragma unroll
      for (int c = 0; c < 16; ++c) acc[c] = b2[c * 16 + d];
#pragma unroll
      for (int k = 0; k < 64; ++k) {
        float uk = u[k];
#pragma unroll
        for (int c = 0; c < 16; ++c) acc[c] = fmaf(uk, wr[k * 16 + c], acc[c]);
      }
#pragma unroll
      for (int q = 0; q < 8; ++q) p[dd * 8 + q] = packbf2(acc[2 * q], acc[2 * q + 1]);
    }
    uint4* dp = reinterpret_cast<uint4*>(W + ((size_t)t << 8) + (dt << 5));
    dp[0] = make_uint4(p[0], p[1], p[2], p[3]);
    dp[1] = make_uint4(p[4], p[5], p[6], p[7]);
    dp[2] = make_uint4(p[8], p[9], p[10], p[11]);
    dp[3] = make_uint4(p[12], p[13], p[14], p[15]);
  }
}

// ---------- gconv message + aggregate ----------
__global__ __launch_bounds__(256) void msg_bf16_kernel(
    const float* __restrict__ h, int h_ld,
    const unsigned short* __restrict__ W, long long ebase, int ecnt,
    const int* __restrict__ idxn, const int* __restrict__ edst,
    float* __restrict__ agg) {
  int t = blockIdx.x * 256 + threadIdx.x;
  if (t >= ecnt) return;
  int g = t >> 4, d = t & 15;
  int cur = -1;
  float acc = 0.0f;
  for (int s = 0; s < 16; ++s) {
    int erel = g * 16 + s;
    long long e = ebase + erel;
    int dst = edst[e];
    if (dst != cur) {
      if (cur >= 0) atomicAdd(&agg[(size_t)cur * 16 + d], acc);
      cur = dst; acc = 0.0f;
    }
    int src = idxn[e];
    const float4* hp = reinterpret_cast<const float4*>(h + (size_t)src * h_ld);
    float4 a0 = hp[0], a1 = hp[1], a2 = hp[2], a3 = hp[3];
    const uint4* wp = reinterpret_cast<const uint4*>(W + ((size_t)erel << 8) + (d << 4));
    uint4 w0 = wp[0], w1 = wp[1];
    acc = fmaf(a0.x, blo(w0.x), acc); acc = fmaf(a0.y, bhi(w0.x), acc);
    acc = fmaf(a0.z, blo(w0.y), acc); acc = fmaf(a0.w, bhi(w0.y), acc);
    acc = fmaf(a1.x, blo(w0.z), acc); acc = fmaf(a1.y, bhi(w0.z), acc);
    acc = fmaf(a1.z, blo(w0.w), acc); acc = fmaf(a1.w, bhi(w0.w), acc);
    acc = fmaf(a2.x, blo(w1.x), acc); acc = fmaf(a2.y, bhi(w1.x), acc);
    acc = fmaf(a2.z, blo(w1.y), acc); acc = fmaf(a2.w, bhi(w1.y), acc);
    acc = fmaf(a3.x, blo(w1.z), acc); acc = fmaf(a3.y, bhi(w1.z), acc);
    acc = fmaf(a3.z, blo(w1.w), acc); acc = fmaf(a3.w, bhi(w1.w), acc);
  }
  if (cur >= 0) atomicAdd(&agg[(size_t)cur * 16 + d], acc);
}

// 16 lanes (d) per 32-edge group = TWO independent 16-edge strips processed in
// one interleaved loop (2 dependency chains -> 2x memory-level parallelism;
// R11 showed msg latency-bound at VALUBusy 22%, 2.47 TB/s). h from dense hd.
__device__ __forceinline__ float edge_dot_i8(const float4& a0, const float4& a1,
                                             const float4& a2, const float4& a3,
                                             const uint4& wv) {
  float r = 0.0f;
  r = fmaf(a0.x, sb2f(wv.x, 0), r); r = fmaf(a0.y, sb2f(wv.x, 1), r);
  r = fmaf(a0.z, sb2f(wv.x, 2), r); r = fmaf(a0.w, sb2f(wv.x, 3), r);
  r = fmaf(a1.x, sb2f(wv.y, 0), r); r = fmaf(a1.y, sb2f(wv.y, 1), r);
  r = fmaf(a1.z, sb2f(wv.y, 2), r); r = fmaf(a1.w, sb2f(wv.y, 3), r);
  r = fmaf(a2.x, sb2f(wv.z, 0), r); r = fmaf(a2.y, sb2f(wv.z, 1), r);
  r = fmaf(a2.z, sb2f(wv.z, 2), r); r = fmaf(a2.w, sb2f(wv.z, 3), r);
  r = fmaf(a3.x, sb2f(wv.w, 0), r); r = fmaf(a3.y, sb2f(wv.w, 1), r);
  r = fmaf(a3.z, sb2f(wv.w, 2), r); r = fmaf(a3.w, sb2f(wv.w, 3), r);
  return r;
}

__global__ __launch_bounds__(256) void msg_i8_kernel(
    const float* __restrict__ h, int h_ld,
    const unsigned char* __restrict__ W, const unsigned short* __restrict__ S,
    const int* __restrict__ idxn, const int* __restrict__ edst,
    float* __restrict__ agg) {
  int t = blockIdx.x * 256 + threadIdx.x;
  if (t >= NE / 2) return;
  const int g = t >> 4, d = t & 15;
  const int eA0 = g * 32;        // strip A: eA0..eA0+15
  const int eB0 = g * 32 + 16;   // strip B: eB0..eB0+15

  int curA = -1, curB = -1;
  float accA = 0.0f, accB = 0.0f;
#pragma unroll
  for (int s = 0; s < 16; ++s) {
    int eA = eA0 + s, eB = eB0 + s;
    int dstA = edst[eA], dstB = edst[eB];
    int srcA = idxn[eA], srcB = idxn[eB];
    const float4* hpA = reinterpret_cast<const float4*>(h + (size_t)srcA * h_ld);
    const float4* hpB = reinterpret_cast<const float4*>(h + (size_t)srcB * h_ld);
    float4 a0 = hpA[0], a1 = hpA[1], a2 = hpA[2], a3 = hpA[3];
    float4 b0 = hpB[0], b1 = hpB[1], b2 = hpB[2], b3 = hpB[3];
    uint4 wvA = *reinterpret_cast<const uint4*>(W + ((size_t)eA << 8) + (d << 4));
    uint4 wvB = *reinterpret_cast<const uint4*>(W + ((size_t)eB << 8) + (d << 4));
    float scA = bf2f(S[eA]), scB = bf2f(S[eB]);
    if (dstA != curA) {
      if (curA >= 0) atomicAdd(&agg[(size_t)curA * 16 + d], accA);
      curA = dstA; accA = 0.0f;
    }
    if (dstB != curB) {
      if (curB >= 0) atomicAdd(&agg[(size_t)curB * 16 + d], accB);
      curB = dstB; accB = 0.0f;
    }
    accA = fmaf(edge_dot_i8(a0, a1, a2, a3, wvA), scA, accA);
    accB = fmaf(edge_dot_i8(b0, b1, b2, b3, wvB), scB, accB);
  }
  atomicAdd(&agg[(size_t)curA * 16 + d], accA);
  atomicAdd(&agg[(size_t)curB * 16 + d], accB);
}

// ---------- GRU cell: 16 lanes per node ----------
__global__ __launch_bounds__(256) void cell_kernel(
    const float* __restrict__ agg, const float* __restrict__ invd,
    const float* hin, int hin_ld,
    const float* __restrict__ wih, const float* __restrict__ whh,
    const float* __restrict__ bih, const float* __restrict__ bhh,
    float* hout, int hout_ld,
    const float* sprev, int sprev_ld,
    float* sout, int sout_ld,
    float* hdn) {
  int t = blockIdx.x * 256 + threadIdx.x;
  int n = t >> 4, j = t & 15;
  if (n >= NN) return;
  float inv = invd[n];
  float x[16], h[16];
  const float4* ap = reinterpret_cast<const float4*>(agg + (size_t)n * 16);
  const float4* hp = reinterpret_cast<const float4*>(hin + (size_t)n * hin_ld);
#pragma unroll
  for (int q = 0; q < 4; ++q) {
    float4 a = ap[q];
    x[4 * q + 0] = a.x * inv; x[4 * q + 1] = a.y * inv;
    x[4 * q + 2] = a.z * inv; x[4 * q + 3] = a.w * inv;
    float4 hv4 = hp[q];
    h[4 * q + 0] = hv4.x; h[4 * q + 1] = hv4.y;
    h[4 * q + 2] = hv4.z; h[4 * q + 3] = hv4.w;
  }
  const float4* wr4 = reinterpret_cast<const float4*>(wih + j * 16);
  const float4* wz4 = reinterpret_cast<const float4*>(wih + (16 + j) * 16);
  const float4* wn4 = reinterpret_cast<const float4*>(wih + (32 + j) * 16);
  const float4* vr4 = reinterpret_cast<const float4*>(whh + j * 16);
  const float4* vz4 = reinterpret_cast<const float4*>(whh + (16 + j) * 16);
  const float4* vn4 = reinterpret_cast<const float4*>(whh + (32 + j) * 16);
  float gr = bih[j], gz = bih[16 + j], gn = bih[32 + j];
  float hr = bhh[j], hz = bhh[16 + j], hn = bhh[32 + j];
#pragma unroll
  for (int q = 0; q < 4; ++q) {
    float4 wr = wr4[q], wz = wz4[q], wn = wn4[q];
    float4 vr = vr4[q], vz = vz4[q], vn = vn4[q];
    gr = fmaf(x[4 * q + 0], wr.x, gr); gr = fmaf(x[4 * q + 1], wr.y, gr);
    gr = fmaf(x[4 * q + 2], wr.z, gr); gr = fmaf(x[4 * q + 3], wr.w, gr);
    gz = fmaf(x[4 * q + 0], wz.x, gz); gz = fmaf(x[4 * q + 1], wz.y, gz);
    gz = fmaf(x[4 * q + 2], wz.z, gz); gz = fmaf(x[4 * q + 3], wz.w, gz);
    gn = fmaf(x[4 * q + 0], wn.x, gn); gn = fmaf(x[4 * q + 1], wn.y, gn);
    gn = fmaf(x[4 * q + 2], wn.z, gn); gn = fmaf(x[4 * q + 3], wn.w, gn);
    hr = fmaf(h[4 * q + 0], vr.x, hr); hr = fmaf(h[4 * q + 1], vr.y, hr);
    hr = fmaf(h[4 * q + 2], vr.z, hr); hr = fmaf(h[4 * q + 3], vr.w, hr);
    hz = fmaf(h[4 * q + 0], vz.x, hz); hz = fmaf(h[4 * q + 1], vz.y, hz);
    hz = fmaf(h[4 * q + 2], vz.z, hz); hz = fmaf(h[4 * q + 3], vz.w, hz);
    hn = fmaf(h[4 * q + 0], vn.x, hn); hn = fmaf(h[4 * q + 1], vn.y, hn);
    hn = fmaf(h[4 * q + 2], vn.z, hn); hn = fmaf(h[4 * q + 3], vn.w, hn);
  }
  float r = 1.0f / (1.0f + expf(-(gr + hr)));
  float z = 1.0f / (1.0f + expf(-(gz + hz)));
  float nng = tanhf(gn + r * hn);
  float hv = (1.0f - z) * nng + z * h[j];

  bool do_s = (sprev != nullptr);
  float sv = 0.0f;
  if (do_s) sv = hv + sprev[(size_t)n * sprev_ld + j];
  hout[(size_t)n * hout_ld + j] = hv;
  if (do_s) sout[(size_t)n * sout_ld + j] = sv;
  if (hdn != nullptr) hdn[(size_t)n * 16 + j] = do_s ? sv : hv;
}

extern "C" void kernel_launch(void* const* d_in, const int* in_sizes, int n_in,
                              void* d_out, int out_size, void* d_ws, size_t ws_size,
                              hipStream_t stream) {
  const float* hx   = (const float*)d_in[0];
  const float* ef   = (const float*)d_in[1];
  const int*   idxn = (const int*)d_in[2];
  const int*   edst = (const int*)d_in[3];
  const float* w1   = (const float*)d_in[4];
  const float* b1   = (const float*)d_in[5];
  const float* w2   = (const float*)d_in[6];
  const float* b2   = (const float*)d_in[7];
  const float* wih  = (const float*)d_in[8];
  const float* whh  = (const float*)d_in[9];
  const float* bih  = (const float*)d_in[10];
  const float* bhh  = (const float*)d_in[11];
  float* out = (float*)d_out;

  // workspace: invd | agg | w2f/w2t | hd (dense h) | W | S
  const size_t INV_OFF = 0;
  const size_t AGG_OFF = 200064;
  const size_t W2T_OFF = 3400192;
  const size_t HD_OFF  = W2T_OFF + 1048576;
  const size_t W_OFF   = HD_OFF + (size_t)NN * 64;
  if (ws_size < W_OFF + 1600 * 512) return;
  char* wsb = (char*)d_ws;
  float* invd = (float*)(wsb + INV_OFF);
  float* agg  = (float*)(wsb + AGG_OFF);
  float* w2t  = (float*)(wsb + W2T_OFF);
  unsigned short* w2f = (unsigned short*)(wsb + W2T_OFF);
  float* hd   = (float*)(wsb + HD_OFF);
  unsigned short* W16 = (unsigned short*)(wsb + W_OFF);
  unsigned char*  W8  = (unsigned char*)(wsb + W_OFF);
  unsigned short* S16 = (unsigned short*)(wsb + W_OFF + (size_t)NE * 256);
  size_t wrem = ws_size - W_OFF;

  int plan;       // 1 = int8 + MFMA fnet, 2 = chunked bf16
  size_t chunk = NE;
  if (wrem >= (size_t)NE * 260) plan = 1;
  else {
    plan = 2;
    chunk = (wrem / 512) & ~(size_t)15;
    if (chunk > NE) chunk = NE;
  }

  const int NB  = (NN + 255) / 256;
  const int EB  = (NE + 255) / 256;
  const int MB  = (NE / 2 + 255) / 256;   // msg: 16 lanes per 32 edges
  const int CB  = (NN * 16 + 255) / 256;  // cell: 16 lanes/node

  hipMemsetAsync(invd, 0, (size_t)NN * 4, stream);
  deg_count_kernel<<<EB, 256, 0, stream>>>(edst, invd);
  deg_inv_kernel<<<NB, 256, 0, stream>>>(invd);
  copy_col0_kernel<<<NB, 256, 0, stream>>>(hx, out);

  if (plan == 1) {
    repack_w2f_kernel<<<64, 256, 0, stream>>>(w2, w2f);
    for (int c = 0; c < 4; ++c)
      fnet_mfma_i8_kernel<<<3125, 256, 0, stream>>>(ef, w1, b1, w2f, b2, W8, S16,
                                                    c * 12500);
  } else {
    repack_w2_kernel<<<1024, 256, 0, stream>>>(w2, w2t);
  }

  auto col = [&](int c) { return out + (size_t)c * 16; };

  auto step = [&](const float* hin, int hin_ld, float* hout,
                  const float* sprev, float* sout, float* hdn) {
    hipMemsetAsync(agg, 0, (size_t)NN * 64, stream);
    if (plan == 1) {
      msg_i8_kernel<<<MB, 256, 0, stream>>>(hin, hin_ld, W8, S16, idxn, edst, agg);
    } else {
      for (size_t e0 = 0; e0 < NE; e0 += chunk) {
        int cnt = (int)(((size_t)NE - e0) < chunk ? ((size_t)NE - e0) : chunk);
        fnet_bf16_kernel<<<(cnt + 255) / 256, 256, 0, stream>>>(ef, w1, b1, w2t, b2, W16,
                                                                (long long)e0, cnt);
        msg_bf16_kernel<<<(cnt + 255) / 256, 256, 0, stream>>>(hin, hin_ld, W16,
                                                               (long long)e0, cnt,
                                                               idxn, edst, agg);
      }
    }
    cell_kernel<<<CB, 256, 0, stream>>>(agg, invd, hin, hin_ld, wih, whh, bih, bhh,
                                        hout, OUTC, sprev, OUTC, sout, OUTC, hdn);
  };

  // cols 0..10 = [hx,h1,h2,s1,h4,s2,h6,s3,h8,s4,h10]; col10 = rotating stash for
  // h3/h5/h7/h9. hd always holds the NEXT step's dense input (h or s post-skip).
  step(hx, 16, col(1),  nullptr, nullptr, hd);   // h1 -> hd
  step(hd, 16, col(2),  nullptr, nullptr, hd);   // h2 -> hd
  step(hd, 16, col(10), col(1),  col(3),  hd);   // h3 stash; s1 -> hd
  step(hd, 16, col(4),  nullptr, nullptr, hd);   // h4 -> hd
  step(hd, 16, col(10), col(10), col(5),  hd);   // h5 stash; s2 -> hd
  step(hd, 16, col(6),  nullptr, nullptr, hd);   // h6 -> hd
  step(hd, 16, col(10), col(10), col(7),  hd);   // h7 stash; s3 -> hd
  step(hd, 16, col(8),  nullptr, nullptr, hd);   // h8 -> hd
  step(hd, 16, col(10), col(10), col(9),  hd);   // h9 stash; s4 -> hd
  step(hd, 16, col(10), nullptr, nullptr, nullptr);  // h10 (final)
}

// Round 14
// 963.816 us; speedup vs baseline: 3.1277x; 1.0254x over previous
//
#include <hip/hip_runtime.h>

#define NN 50000
#define NE 800000
#define OUTC 176  // 11 * 16

typedef unsigned int uint32;
typedef short bf16x8 __attribute__((ext_vector_type(8)));
typedef float f32x4 __attribute__((ext_vector_type(4)));
typedef unsigned int uint32x4 __attribute__((ext_vector_type(4)));

// ---------- bf16 helpers (manual, RNE) ----------
__device__ __forceinline__ uint32 f2bf_rne(float f) {
  union { float f; uint32 u; } v; v.f = f;
  uint32 u = v.u;
  return (u + 0x7FFFu + ((u >> 16) & 1u)) >> 16;
}
__device__ __forceinline__ uint32 packbf2(float a, float b) {
  return f2bf_rne(a) | (f2bf_rne(b) << 16);
}
__device__ __forceinline__ float blo(uint32 u) {
  union { uint32 x; float f; } t; t.x = u << 16; return t.f;
}
__device__ __forceinline__ float bhi(uint32 u) {
  union { uint32 x; float f; } t; t.x = u & 0xFFFF0000u; return t.f;
}
__device__ __forceinline__ float bf2f(unsigned short v) {
  union { uint32 x; float f; } t; t.x = ((uint32)v) << 16; return t.f;
}
// signed byte b (0..3) of packed word -> float
__device__ __forceinline__ float sb2f(uint32 w, int b) {
  return (float)((int)(w << (24 - 8 * b)) >> 24);
}

// ---------- small kernels ----------
__global__ __launch_bounds__(256) void deg_count_kernel(const int* __restrict__ edst,
                                                        float* __restrict__ deg) {
  int e = blockIdx.x * 256 + threadIdx.x;
  if (e < NE) atomicAdd(&deg[edst[e]], 1.0f);
}

__global__ __launch_bounds__(256) void deg_inv_kernel(float* __restrict__ deg) {
  int n = blockIdx.x * 256 + threadIdx.x;
  if (n < NN) deg[n] = 1.0f / fmaxf(deg[n], 1.0f);
}

__global__ __launch_bounds__(256) void copy_col0_kernel(const float* __restrict__ hx,
                                                        float* __restrict__ out) {
  int n = blockIdx.x * 256 + threadIdx.x;
  if (n >= NN) return;
  const float4* s = reinterpret_cast<const float4*>(hx + (size_t)n * 16);
  float4* d = reinterpret_cast<float4*>(out + (size_t)n * OUTC);
  d[0] = s[0]; d[1] = s[1]; d[2] = s[2]; d[3] = s[3];
}

// hx (dense f32 [NN,16]) -> hdb (bf16) for step-1 msg gather
__global__ __launch_bounds__(256) void hx2hd_kernel(const float* __restrict__ hx,
                                                    unsigned short* __restrict__ hdb) {
  int t = blockIdx.x * 256 + threadIdx.x;
  if (t < NN * 16) hdb[t] = (unsigned short)f2bf_rne(hx[t]);
}

// w2t[d][k][c] = w2[k*256 + c*16 + d]  (for the chunked-bf16 fallback plan)
__global__ __launch_bounds__(256) void repack_w2_kernel(const float* __restrict__ w2,
                                                        float* __restrict__ w2t) {
  int i = blockIdx.x * 256 + threadIdx.x;
  if (i >= 256 * 1024) return;
  int d = i >> 10, r = i & 1023, k = r >> 4, c = r & 15;
  w2t[i] = w2[k * 256 + c * 16 + d];
}

// w2 -> bf16 MFMA B-fragment layout (32 KB)
__global__ __launch_bounds__(256) void repack_w2f_kernel(const float* __restrict__ w2,
                                                         unsigned short* __restrict__ w2f) {
  int i = blockIdx.x * 256 + threadIdx.x;  // 0..16383
  if (i >= 16384) return;
  int jj = i & 7;
  int l = (i >> 3) & 63;
  int nbm = i >> 9;  // nb*2+m
  int m = nbm & 1, nb = nbm >> 1;
  int k = m * 32 + (l >> 4) * 8 + jj;
  int j = nb * 16 + (l & 15);
  w2f[i] = (unsigned short)f2bf_rne(w2[k * 256 + j]);
}

// ---------- MFMA fnet: fused layer1 + 16x256x64 GEMM + int8 quantize ----------
__global__ __launch_bounds__(256) void fnet_mfma_i8_kernel(
    const float* __restrict__ ef, const float* __restrict__ w1, const float* __restrict__ b1,
    const unsigned short* __restrict__ w2f, const float* __restrict__ b2,
    unsigned char* __restrict__ W, unsigned short* __restrict__ S) {
  __shared__ float efs[832];          // 64 edges x 13 feats
  __shared__ short w2s[16384];        // full B fragments, 32KB
  const int wave = threadIdx.x >> 6;
  const int l = threadIdx.x & 63;
  const int wid = blockIdx.x * 4 + wave;
  const int d = l & 15, kg = l >> 4;

#pragma unroll
  for (int i = 0; i < 8; ++i)
    reinterpret_cast<uint4*>(w2s)[threadIdx.x + 256 * i] =
        reinterpret_cast<const uint4*>(w2f)[threadIdx.x + 256 * i];
  long long E0 = (long long)blockIdx.x * 64;
  if (threadIdx.x < 208) {
    reinterpret_cast<float4*>(efs)[threadIdx.x] =
        reinterpret_cast<const float4*>(ef + E0 * 13)[threadIdx.x];
  }
  __syncthreads();

  // ---- layer1 (f from LDS) ----
  const int eloc = wave * 16 + d;
  float f[13];
#pragma unroll
  for (int i = 0; i < 13; ++i) f[i] = efs[eloc * 13 + i];
  float ua[8], ub[8];
#pragma unroll
  for (int j = 0; j < 8; ++j) { ua[j] = b1[kg * 8 + j]; ub[j] = b1[32 + kg * 8 + j]; }
#pragma unroll
  for (int i = 0; i < 13; ++i) {
    const float4* wa = reinterpret_cast<const float4*>(w1 + i * 64 + kg * 8);
    const float4* wb = reinterpret_cast<const float4*>(w1 + i * 64 + 32 + kg * 8);
    float4 a0 = wa[0], a1 = wa[1], c0 = wb[0], c1 = wb[1];
    float fi = f[i];
    ua[0] = fmaf(fi, a0.x, ua[0]); ua[1] = fmaf(fi, a0.y, ua[1]);
    ua[2] = fmaf(fi, a0.z, ua[2]); ua[3] = fmaf(fi, a0.w, ua[3]);
    ua[4] = fmaf(fi, a1.x, ua[4]); ua[5] = fmaf(fi, a1.y, ua[5]);
    ua[6] = fmaf(fi, a1.z, ua[6]); ua[7] = fmaf(fi, a1.w, ua[7]);
    ub[0] = fmaf(fi, c0.x, ub[0]); ub[1] = fmaf(fi, c0.y, ub[1]);
    ub[2] = fmaf(fi, c0.z, ub[2]); ub[3] = fmaf(fi, c0.w, ub[3]);
    ub[4] = fmaf(fi, c1.x, ub[4]); ub[5] = fmaf(fi, c1.y, ub[5]);
    ub[6] = fmaf(fi, c1.z, ub[6]); ub[7] = fmaf(fi, c1.w, ub[7]);
  }
  bf16x8 afrag0, afrag1;
#pragma unroll
  for (int j = 0; j < 8; ++j) {
    afrag0[j] = (short)f2bf_rne(fmaxf(ua[j], 0.0f));
    afrag1[j] = (short)f2bf_rne(fmaxf(ub[j], 0.0f));
  }

  float bias[16];
#pragma unroll
  for (int nb = 0; nb < 16; ++nb) bias[nb] = b2[nb * 16 + d];

  const bf16x8* Bp = reinterpret_cast<const bf16x8*>(w2s);
  f32x4 acc[16];
#pragma unroll
  for (int nb = 0; nb < 16; ++nb) {
    f32x4 c; c[0] = bias[nb]; c[1] = bias[nb]; c[2] = bias[nb]; c[3] = bias[nb];
    bf16x8 bf0 = Bp[(nb * 2 + 0) * 64 + l];
    bf16x8 bf1 = Bp[(nb * 2 + 1) * 64 + l];
    c = __builtin_amdgcn_mfma_f32_16x16x32_bf16(afrag0, bf0, c, 0, 0, 0);
    c = __builtin_amdgcn_mfma_f32_16x16x32_bf16(afrag1, bf1, c, 0, 0, 0);
    acc[nb] = c;
  }

  // per-edge scale (reduce across 16 d-lanes of this kg-group)
  float mx[4];
#pragma unroll
  for (int r = 0; r < 4; ++r) {
    float m = 0.0f;
#pragma unroll
    for (int c = 0; c < 16; ++c) m = fmaxf(m, fabsf(acc[c][r]));
    mx[r] = m;
  }
#pragma unroll
  for (int mask = 1; mask < 16; mask <<= 1) {
#pragma unroll
    for (int r = 0; r < 4; ++r) mx[r] = fmaxf(mx[r], __shfl_xor(mx[r], mask));
  }
  uint32 sb[4]; float sinv[4];
#pragma unroll
  for (int r = 0; r < 4; ++r) {
    sb[r] = f2bf_rne(mx[r] * (1.0f / 127.0f));
    float sd = bf2f((unsigned short)sb[r]);
    sinv[r] = (sd > 0.0f) ? (1.0f / sd) : 0.0f;
  }
  if (d == 0) {
    uint32 lo = sb[0] | (sb[1] << 16), hi = sb[2] | (sb[3] << 16);
    *reinterpret_cast<uint2*>(S + (size_t)wid * 16 + kg * 4) = make_uint2(lo, hi);
  }

#pragma unroll
  for (int r = 0; r < 4; ++r) {
    size_t er = (size_t)wid * 16 + kg * 4 + r;
    uint32 p[4];
#pragma unroll
    for (int q = 0; q < 4; ++q) {
      uint32 wv = 0;
#pragma unroll
      for (int b = 0; b < 4; ++b) {
        float qf = fminf(127.0f, fmaxf(-127.0f, rintf(acc[q * 4 + b][r] * sinv[r])));
        wv |= ((uint32)((int)qf & 255)) << (8 * b);
      }
      p[q] = wv;
    }
    *reinterpret_cast<uint4*>(W + (er << 8) + (d << 4)) = make_uint4(p[0], p[1], p[2], p[3]);
  }
}

// ---------- chunked-bf16 fallback fnet (plan 2) ----------
__device__ __forceinline__ void fnet_layer1(const float* __restrict__ ef, long long e,
                                            const float* __restrict__ w1,
                                            const float* __restrict__ b1,
                                            float* u) {
  float f[13];
#pragma unroll
  for (int i = 0; i < 13; ++i) f[i] = ef[(size_t)e * 13 + i];
#pragma unroll
  for (int k = 0; k < 64; ++k) u[k] = b1[k];
#pragma unroll
  for (int i = 0; i < 13; ++i) {
    float fi = f[i];
#pragma unroll
    for (int k = 0; k < 64; ++k) u[k] = fmaf(fi, w1[i * 64 + k], u[k]);
  }
#pragma unroll
  for (int k = 0; k < 64; ++k) u[k] = fmaxf(u[k], 0.0f);
}

__global__ __launch_bounds__(256) void fnet_bf16_kernel(
    const float* __restrict__ ef, const float* __restrict__ w1, const float* __restrict__ b1,
    const float* __restrict__ w2t, const float* __restrict__ b2,
    unsigned short* __restrict__ W, long long ebase, int ecnt) {
  int t = blockIdx.x * 256 + threadIdx.x;
  if (t >= ecnt) return;
  float u[64];
  fnet_layer1(ef, ebase + t, w1, b1, u);
#pragma unroll 1
  for (int dt = 0; dt < 8; ++dt) {
    uint32 p[16];
#pragma unroll
    for (int dd = 0; dd < 2; ++dd) {
      const int d = dt * 2 + dd;
      const float* wr = w2t + ((size_t)d << 10);
      float acc[16];
#pragma unroll
      for (int c = 0; c < 16; ++c) acc[c] = b2[c * 16 + d];
#pragma unroll
      for (int k = 0; k < 64; ++k) {
        float uk = u[k];
#pragma unroll
        for (int c = 0; c < 16; ++c) acc[c] = fmaf(uk, wr[k * 16 + c], acc[c]);
      }
#pragma unroll
      for (int q = 0; q < 8; ++q) p[dd * 8 + q] = packbf2(acc[2 * q], acc[2 * q + 1]);
    }
    uint4* dp = reinterpret_cast<uint4*>(W + ((size_t)t << 8) + (dt << 5));
    dp[0] = make_uint4(p[0], p[1], p[2], p[3]);
    dp[1] = make_uint4(p[4], p[5], p[6], p[7]);
    dp[2] = make_uint4(p[8], p[9], p[10], p[11]);
    dp[3] = make_uint4(p[12], p[13], p[14], p[15]);
  }
}

// ---------- gconv message + aggregate ----------
__global__ __launch_bounds__(256) void msg_bf16_kernel(
    const float* __restrict__ h, int h_ld,
    const unsigned short* __restrict__ W, long long ebase, int ecnt,
    const int* __restrict__ idxn, const int* __restrict__ edst,
    float* __restrict__ agg) {
  int t = blockIdx.x * 256 + threadIdx.x;
  if (t >= ecnt) return;
  int g = t >> 4, d = t & 15;
  int cur = -1;
  float acc = 0.0f;
  for (int s = 0; s < 16; ++s) {
    int erel = g * 16 + s;
    long long e = ebase + erel;
    int dst = edst[e];
    if (dst != cur) {
      if (cur >= 0) atomicAdd(&agg[(size_t)cur * 16 + d], acc);
      cur = dst; acc = 0.0f;
    }
    int src = idxn[e];
    const float4* hp = reinterpret_cast<const float4*>(h + (size_t)src * h_ld);
    float4 a0 = hp[0], a1 = hp[1], a2 = hp[2], a3 = hp[3];
    const uint4* wp = reinterpret_cast<const uint4*>(W + ((size_t)erel << 8) + (d << 4));
    uint4 w0 = wp[0], w1 = wp[1];
    acc = fmaf(a0.x, blo(w0.x), acc); acc = fmaf(a0.y, bhi(w0.x), acc);
    acc = fmaf(a0.z, blo(w0.y), acc); acc = fmaf(a0.w, bhi(w0.y), acc);
    acc = fmaf(a1.x, blo(w0.z), acc); acc = fmaf(a1.y, bhi(w0.z), acc);
    acc = fmaf(a1.z, blo(w0.w), acc); acc = fmaf(a1.w, bhi(w0.w), acc);
    acc = fmaf(a2.x, blo(w1.x), acc); acc = fmaf(a2.y, bhi(w1.x), acc);
    acc = fmaf(a2.z, blo(w1.y), acc); acc = fmaf(a2.w, bhi(w1.y), acc);
    acc = fmaf(a3.x, blo(w1.z), acc); acc = fmaf(a3.y, bhi(w1.z), acc);
    acc = fmaf(a3.z, blo(w1.w), acc); acc = fmaf(a3.w, bhi(w1.w), acc);
  }
  if (cur >= 0) atomicAdd(&agg[(size_t)cur * 16 + d], acc);
}

// int8 W (nontemporal stream) x bf16 h (L2-resident hdb). 16 lanes per 32-edge
// group = 2 independent strips (2x MLP). h row = 32B (2 uint4) vs 64B before.
__device__ __forceinline__ float edge_dot_i8bf(const uint32x4& h0, const uint32x4& h1,
                                               const uint32x4& wv) {
  float r = 0.0f;
  r = fmaf(blo(h0[0]), sb2f(wv[0], 0), r); r = fmaf(bhi(h0[0]), sb2f(wv[0], 1), r);
  r = fmaf(blo(h0[1]), sb2f(wv[0], 2), r); r = fmaf(bhi(h0[1]), sb2f(wv[0], 3), r);
  r = fmaf(blo(h0[2]), sb2f(wv[1], 0), r); r = fmaf(bhi(h0[2]), sb2f(wv[1], 1), r);
  r = fmaf(blo(h0[3]), sb2f(wv[1], 2), r); r = fmaf(bhi(h0[3]), sb2f(wv[1], 3), r);
  r = fmaf(blo(h1[0]), sb2f(wv[2], 0), r); r = fmaf(bhi(h1[0]), sb2f(wv[2], 1), r);
  r = fmaf(blo(h1[1]), sb2f(wv[2], 2), r); r = fmaf(bhi(h1[1]), sb2f(wv[2], 3), r);
  r = fmaf(blo(h1[2]), sb2f(wv[3], 0), r); r = fmaf(bhi(h1[2]), sb2f(wv[3], 1), r);
  r = fmaf(blo(h1[3]), sb2f(wv[3], 2), r); r = fmaf(bhi(h1[3]), sb2f(wv[3], 3), r);
  return r;
}

__global__ __launch_bounds__(256) void msg_i8_kernel(
    const unsigned short* __restrict__ hdb,
    const unsigned char* __restrict__ W, const unsigned short* __restrict__ S,
    const int* __restrict__ idxn, const int* __restrict__ edst,
    float* __restrict__ agg) {
  int t = blockIdx.x * 256 + threadIdx.x;
  if (t >= NE / 2) return;
  const int g = t >> 4, d = t & 15;
  const int eA0 = g * 32;
  const int eB0 = g * 32 + 16;

  int curA = -1, curB = -1;
  float accA = 0.0f, accB = 0.0f;
#pragma unroll
  for (int s = 0; s < 16; ++s) {
    int eA = eA0 + s, eB = eB0 + s;
    int dstA = edst[eA], dstB = edst[eB];
    int srcA = idxn[eA], srcB = idxn[eB];
    const uint32x4* hpA = reinterpret_cast<const uint32x4*>(hdb + (size_t)srcA * 16);
    const uint32x4* hpB = reinterpret_cast<const uint32x4*>(hdb + (size_t)srcB * 16);
    uint32x4 ha0 = hpA[0], ha1 = hpA[1];
    uint32x4 hb0 = hpB[0], hb1 = hpB[1];
    uint32x4 wvA = __builtin_nontemporal_load(
        reinterpret_cast<const uint32x4*>(W + ((size_t)eA << 8) + (d << 4)));
    uint32x4 wvB = __builtin_nontemporal_load(
        reinterpret_cast<const uint32x4*>(W + ((size_t)eB << 8) + (d << 4)));
    float scA = bf2f(S[eA]), scB = bf2f(S[eB]);
    if (dstA != curA) {
      if (curA >= 0) atomicAdd(&agg[(size_t)curA * 16 + d], accA);
      curA = dstA; accA = 0.0f;
    }
    if (dstB != curB) {
      if (curB >= 0) atomicAdd(&agg[(size_t)curB * 16 + d], accB);
      curB = dstB; accB = 0.0f;
    }
    accA = fmaf(edge_dot_i8bf(ha0, ha1, wvA), scA, accA);
    accB = fmaf(edge_dot_i8bf(hb0, hb1, wvB), scB, accB);
  }
  atomicAdd(&agg[(size_t)curA * 16 + d], accA);
  atomicAdd(&agg[(size_t)curB * 16 + d], accB);
}

// ---------- GRU cell: 16 lanes per node; re-zeroes agg for the next step ----------
// agg zero-store happens after all agg loads have completed (gate FMAs consume
// them, compiler memory barrier prevents hoisting) -> safe same-wave ordering.
__global__ __launch_bounds__(256) void cell_kernel(
    float* agg, const float* __restrict__ invd,
    const float* hin, int hin_ld,
    const float* __restrict__ wih, const float* __restrict__ whh,
    const float* __restrict__ bih, const float* __restrict__ bhh,
    float* hout, int hout_ld,
    const float* sprev, int sprev_ld,
    float* sout, int sout_ld,
    unsigned short* hdn) {
  int t = blockIdx.x * 256 + threadIdx.x;
  int n = t >> 4, j = t & 15;
  if (n >= NN) return;
  float inv = invd[n];
  float x[16], h[16];
  const float4* ap = reinterpret_cast<const float4*>(agg + (size_t)n * 16);
  const float4* hp = reinterpret_cast<const float4*>(hin + (size_t)n * hin_ld);
#pragma unroll
  for (int q = 0; q < 4; ++q) {
    float4 a = ap[q];
    x[4 * q + 0] = a.x * inv; x[4 * q + 1] = a.y * inv;
    x[4 * q + 2] = a.z * inv; x[4 * q + 3] = a.w * inv;
    float4 hv4 = hp[q];
    h[4 * q + 0] = hv4.x; h[4 * q + 1] = hv4.y;
    h[4 * q + 2] = hv4.z; h[4 * q + 3] = hv4.w;
  }
  const float4* wr4 = reinterpret_cast<const float4*>(wih + j * 16);
  const float4* wz4 = reinterpret_cast<const float4*>(wih + (16 + j) * 16);
  const float4* wn4 = reinterpret_cast<const float4*>(wih + (32 + j) * 16);
  const float4* vr4 = reinterpret_cast<const float4*>(whh + j * 16);
  const float4* vz4 = reinterpret_cast<const float4*>(whh + (16 + j) * 16);
  const float4* vn4 = reinterpret_cast<const float4*>(whh + (32 + j) * 16);
  float gr = bih[j], gz = bih[16 + j], gn = bih[32 + j];
  float hr = bhh[j], hz = bhh[16 + j], hn = bhh[32 + j];
#pragma unroll
  for (int q = 0; q < 4; ++q) {
    float4 wr = wr4[q], wz = wz4[q], wn = wn4[q];
    float4 vr = vr4[q], vz = vz4[q], vn = vn4[q];
    gr = fmaf(x[4 * q + 0], wr.x, gr); gr = fmaf(x[4 * q + 1], wr.y, gr);
    gr = fmaf(x[4 * q + 2], wr.z, gr); gr = fmaf(x[4 * q + 3], wr.w, gr);
    gz = fmaf(x[4 * q + 0], wz.x, gz); gz = fmaf(x[4 * q + 1], wz.y, gz);
    gz = fmaf(x[4 * q + 2], wz.z, gz); gz = fmaf(x[4 * q + 3], wz.w, gz);
    gn = fmaf(x[4 * q + 0], wn.x, gn); gn = fmaf(x[4 * q + 1], wn.y, gn);
    gn = fmaf(x[4 * q + 2], wn.z, gn); gn = fmaf(x[4 * q + 3], wn.w, gn);
    hr = fmaf(h[4 * q + 0], vr.x, hr); hr = fmaf(h[4 * q + 1], vr.y, hr);
    hr = fmaf(h[4 * q + 2], vr.z, hr); hr = fmaf(h[4 * q + 3], vr.w, hr);
    hz = fmaf(h[4 * q + 0], vz.x, hz); hz = fmaf(h[4 * q + 1], vz.y, hz);
    hz = fmaf(h[4 * q + 2], vz.z, hz); hz = fmaf(h[4 * q + 3], vz.w, hz);
    hn = fmaf(h[4 * q + 0], vn.x, hn); hn = fmaf(h[4 * q + 1], vn.y, hn);
    hn = fmaf(h[4 * q + 2], vn.z, hn); hn = fmaf(h[4 * q + 3], vn.w, hn);
  }
  float r = 1.0f / (1.0f + expf(-(gr + hr)));
  float z = 1.0f / (1.0f + expf(-(gz + hz)));
  float nng = tanhf(gn + r * hn);
  float hv = (1.0f - z) * nng + z * h[j];

  bool do_s = (sprev != nullptr);
  float sv = 0.0f;
  if (do_s) sv = hv + sprev[(size_t)n * sprev_ld + j];
  hout[(size_t)n * hout_ld + j] = hv;
  if (do_s) sout[(size_t)n * sout_ld + j] = sv;
  if (hdn != nullptr) hdn[(size_t)n * 16 + j] = (unsigned short)f2bf_rne(do_s ? sv : hv);

  // re-zero agg for the next step's atomics (loads above already consumed)
  asm volatile("" ::: "memory");
  agg[(size_t)n * 16 + j] = 0.0f;
}

extern "C" void kernel_launch(void* const* d_in, const int* in_sizes, int n_in,
                              void* d_out, int out_size, void* d_ws, size_t ws_size,
                              hipStream_t stream) {
  const float* hx   = (const float*)d_in[0];
  const float* ef   = (const float*)d_in[1];
  const int*   idxn = (const int*)d_in[2];
  const int*   edst = (const int*)d_in[3];
  const float* w1   = (const float*)d_in[4];
  const float* b1   = (const float*)d_in[5];
  const float* w2   = (const float*)d_in[6];
  const float* b2   = (const float*)d_in[7];
  const float* wih  = (const float*)d_in[8];
  const float* whh  = (const float*)d_in[9];
  const float* bih  = (const float*)d_in[10];
  const float* bhh  = (const float*)d_in[11];
  float* out = (float*)d_out;

  // workspace: invd | agg | w2f/w2t | hdb (bf16 dense h) | W | S
  const size_t INV_OFF = 0;
  const size_t AGG_OFF = 200064;
  const size_t W2T_OFF = 3400192;
  const size_t HD_OFF  = W2T_OFF + 1048576;
  const size_t W_OFF   = HD_OFF + (size_t)NN * 32;  // hdb = 1.6MB
  if (ws_size < W_OFF + 1600 * 512) return;
  char* wsb = (char*)d_ws;
  float* invd = (float*)(wsb + INV_OFF);
  float* agg  = (float*)(wsb + AGG_OFF);
  float* w2t  = (float*)(wsb + W2T_OFF);
  unsigned short* w2f = (unsigned short*)(wsb + W2T_OFF);
  unsigned short* hdb = (unsigned short*)(wsb + HD_OFF);
  unsigned short* W16 = (unsigned short*)(wsb + W_OFF);
  unsigned char*  W8  = (unsigned char*)(wsb + W_OFF);
  unsigned short* S16 = (unsigned short*)(wsb + W_OFF + (size_t)NE * 256);
  size_t wrem = ws_size - W_OFF;

  int plan;       // 1 = int8 + MFMA fnet, 2 = chunked bf16
  size_t chunk = NE;
  if (wrem >= (size_t)NE * 260) plan = 1;
  else {
    plan = 2;
    chunk = (wrem / 512) & ~(size_t)15;
    if (chunk > NE) chunk = NE;
  }

  const int NB  = (NN + 255) / 256;
  const int EB  = (NE + 255) / 256;
  const int MB  = (NE / 2 + 255) / 256;   // msg: 16 lanes per 32 edges
  const int CB  = (NN * 16 + 255) / 256;  // cell: 16 lanes/node

  hipMemsetAsync(invd, 0, (size_t)NN * 4, stream);
  hipMemsetAsync(agg, 0, (size_t)NN * 64, stream);  // once; cell re-zeroes per step
  deg_count_kernel<<<EB, 256, 0, stream>>>(edst, invd);
  deg_inv_kernel<<<NB, 256, 0, stream>>>(invd);
  copy_col0_kernel<<<NB, 256, 0, stream>>>(hx, out);
  hx2hd_kernel<<<CB, 256, 0, stream>>>(hx, hdb);

  if (plan == 1) {
    repack_w2f_kernel<<<64, 256, 0, stream>>>(w2, w2f);
    fnet_mfma_i8_kernel<<<12500, 256, 0, stream>>>(ef, w1, b1, w2f, b2, W8, S16);
  } else {
    repack_w2_kernel<<<1024, 256, 0, stream>>>(w2, w2t);
  }

  auto col = [&](int c) { return out + (size_t)c * 16; };

  auto step = [&](const float* hinF, int hin_ld, float* hout,
                  const float* sprev, float* sout, unsigned short* hdn) {
    if (plan == 1) {
      msg_i8_kernel<<<MB, 256, 0, stream>>>(hdb, W8, S16, idxn, edst, agg);
    } else {
      hipMemsetAsync(agg, 0, (size_t)NN * 64, stream);
      for (size_t e0 = 0; e0 < NE; e0 += chunk) {
        int cnt = (int)(((size_t)NE - e0) < chunk ? ((size_t)NE - e0) : chunk);
        fnet_bf16_kernel<<<(cnt + 255) / 256, 256, 0, stream>>>(ef, w1, b1, w2t, b2, W16,
                                                                (long long)e0, cnt);
        msg_bf16_kernel<<<(cnt + 255) / 256, 256, 0, stream>>>(hinF, hin_ld, W16,
                                                               (long long)e0, cnt,
                                                               idxn, edst, agg);
      }
    }
    cell_kernel<<<CB, 256, 0, stream>>>(agg, invd, hinF, hin_ld, wih, whh, bih, bhh,
                                        hout, OUTC, sprev, OUTC, sout, OUTC, hdn);
  };

  // cols 0..10 = [hx,h1,h2,s1,h4,s2,h6,s3,h8,s4,h10]; col10 = rotating stash for
  // h3/h5/h7/h9. hdb always holds the NEXT step's bf16 msg input (h or s).
  step(hx,      16,  col(1),  nullptr, nullptr, hdb);  // h1
  step(col(1), OUTC, col(2),  nullptr, nullptr, hdb);  // h2
  step(col(2), OUTC, col(10), col(1),  col(3),  hdb);  // h3 stash; s1
  step(col(3), OUTC, col(4),  nullptr, nullptr, hdb);  // h4
  step(col(4), OUTC, col(10), col(10), col(5),  hdb);  // h5 stash; s2
  step(col(5), OUTC, col(6),  nullptr, nullptr, hdb);  // h6
  step(col(6), OUTC, col(10), col(10), col(7),  hdb);  // h7 stash; s3
  step(col(7), OUTC, col(8),  nullptr, nullptr, hdb);  // h8
  step(col(8), OUTC, col(10), col(10), col(9),  hdb);  // h9 stash; s4
  step(col(9), OUTC, col(10), nullptr, nullptr, nullptr);  // h10 (final)
}

// Round 15
// 880.337 us; speedup vs baseline: 3.4243x; 1.0948x over previous
//
#include <hip/hip_runtime.h>

#define NN 50000
#define NE 800000
#define OUTC 176  // 11 * 16

typedef unsigned int uint32;
typedef short bf16x8 __attribute__((ext_vector_type(8)));
typedef float f32x4 __attribute__((ext_vector_type(4)));
typedef unsigned int uint32x4 __attribute__((ext_vector_type(4)));

// ---------- bf16 helpers (manual, RNE) ----------
__device__ __forceinline__ uint32 f2bf_rne(float f) {
  union { float f; uint32 u; } v; v.f = f;
  uint32 u = v.u;
  return (u + 0x7FFFu + ((u >> 16) & 1u)) >> 16;
}
__device__ __forceinline__ uint32 packbf2(float a, float b) {
  return f2bf_rne(a) | (f2bf_rne(b) << 16);
}
__device__ __forceinline__ float blo(uint32 u) {
  union { uint32 x; float f; } t; t.x = u << 16; return t.f;
}
__device__ __forceinline__ float bhi(uint32 u) {
  union { uint32 x; float f; } t; t.x = u & 0xFFFF0000u; return t.f;
}
__device__ __forceinline__ float bf2f(unsigned short v) {
  union { uint32 x; float f; } t; t.x = ((uint32)v) << 16; return t.f;
}
// signed byte b (0..3) of packed word -> float
__device__ __forceinline__ float sb2f(uint32 w, int b) {
  return (float)((int)(w << (24 - 8 * b)) >> 24);
}

// ---------- small kernels ----------
__global__ __launch_bounds__(256) void deg_count_kernel(const int* __restrict__ edst,
                                                        float* __restrict__ deg) {
  int e = blockIdx.x * 256 + threadIdx.x;
  if (e < NE) atomicAdd(&deg[edst[e]], 1.0f);
}

__global__ __launch_bounds__(256) void deg_inv_kernel(float* __restrict__ deg) {
  int n = blockIdx.x * 256 + threadIdx.x;
  if (n < NN) deg[n] = 1.0f / fmaxf(deg[n], 1.0f);
}

__global__ __launch_bounds__(256) void copy_col0_kernel(const float* __restrict__ hx,
                                                        float* __restrict__ out) {
  int n = blockIdx.x * 256 + threadIdx.x;
  if (n >= NN) return;
  const float4* s = reinterpret_cast<const float4*>(hx + (size_t)n * 16);
  float4* d = reinterpret_cast<float4*>(out + (size_t)n * OUTC);
  d[0] = s[0]; d[1] = s[1]; d[2] = s[2]; d[3] = s[3];
}

// hx (dense f32 [NN,16]) -> hdb (bf16) for step-1 msg gather
__global__ __launch_bounds__(256) void hx2hd_kernel(const float* __restrict__ hx,
                                                    unsigned short* __restrict__ hdb) {
  int t = blockIdx.x * 256 + threadIdx.x;
  if (t < NN * 16) hdb[t] = (unsigned short)f2bf_rne(hx[t]);
}

// w2t[d][k][c] = w2[k*256 + c*16 + d]  (for the chunked-bf16 fallback plan)
__global__ __launch_bounds__(256) void repack_w2_kernel(const float* __restrict__ w2,
                                                        float* __restrict__ w2t) {
  int i = blockIdx.x * 256 + threadIdx.x;
  if (i >= 256 * 1024) return;
  int d = i >> 10, r = i & 1023, k = r >> 4, c = r & 15;
  w2t[i] = w2[k * 256 + c * 16 + d];
}

// w2 -> bf16 MFMA B-fragment layout (32 KB)
__global__ __launch_bounds__(256) void repack_w2f_kernel(const float* __restrict__ w2,
                                                         unsigned short* __restrict__ w2f) {
  int i = blockIdx.x * 256 + threadIdx.x;  // 0..16383
  if (i >= 16384) return;
  int jj = i & 7;
  int l = (i >> 3) & 63;
  int nbm = i >> 9;  // nb*2+m
  int m = nbm & 1, nb = nbm >> 1;
  int k = m * 32 + (l >> 4) * 8 + jj;
  int j = nb * 16 + (l & 15);
  w2f[i] = (unsigned short)f2bf_rne(w2[k * 256 + j]);
}

// ---------- MFMA fnet: fused layer1 + 16x256x64 GEMM + int8 quantize ----------
// W stores are nontemporal: 201MB streaming write never re-read before eviction.
__global__ __launch_bounds__(256) void fnet_mfma_i8_kernel(
    const float* __restrict__ ef, const float* __restrict__ w1, const float* __restrict__ b1,
    const unsigned short* __restrict__ w2f, const float* __restrict__ b2,
    unsigned char* __restrict__ W, unsigned short* __restrict__ S) {
  __shared__ float efs[832];          // 64 edges x 13 feats
  __shared__ short w2s[16384];        // full B fragments, 32KB
  const int wave = threadIdx.x >> 6;
  const int l = threadIdx.x & 63;
  const int wid = blockIdx.x * 4 + wave;
  const int d = l & 15, kg = l >> 4;

#pragma unroll
  for (int i = 0; i < 8; ++i)
    reinterpret_cast<uint4*>(w2s)[threadIdx.x + 256 * i] =
        reinterpret_cast<const uint4*>(w2f)[threadIdx.x + 256 * i];
  long long E0 = (long long)blockIdx.x * 64;
  if (threadIdx.x < 208) {
    reinterpret_cast<float4*>(efs)[threadIdx.x] =
        reinterpret_cast<const float4*>(ef + E0 * 13)[threadIdx.x];
  }
  __syncthreads();

  // ---- layer1 (f from LDS) ----
  const int eloc = wave * 16 + d;
  float f[13];
#pragma unroll
  for (int i = 0; i < 13; ++i) f[i] = efs[eloc * 13 + i];
  float ua[8], ub[8];
#pragma unroll
  for (int j = 0; j < 8; ++j) { ua[j] = b1[kg * 8 + j]; ub[j] = b1[32 + kg * 8 + j]; }
#pragma unroll
  for (int i = 0; i < 13; ++i) {
    const float4* wa = reinterpret_cast<const float4*>(w1 + i * 64 + kg * 8);
    const float4* wb = reinterpret_cast<const float4*>(w1 + i * 64 + 32 + kg * 8);
    float4 a0 = wa[0], a1 = wa[1], c0 = wb[0], c1 = wb[1];
    float fi = f[i];
    ua[0] = fmaf(fi, a0.x, ua[0]); ua[1] = fmaf(fi, a0.y, ua[1]);
    ua[2] = fmaf(fi, a0.z, ua[2]); ua[3] = fmaf(fi, a0.w, ua[3]);
    ua[4] = fmaf(fi, a1.x, ua[4]); ua[5] = fmaf(fi, a1.y, ua[5]);
    ua[6] = fmaf(fi, a1.z, ua[6]); ua[7] = fmaf(fi, a1.w, ua[7]);
    ub[0] = fmaf(fi, c0.x, ub[0]); ub[1] = fmaf(fi, c0.y, ub[1]);
    ub[2] = fmaf(fi, c0.z, ub[2]); ub[3] = fmaf(fi, c0.w, ub[3]);
    ub[4] = fmaf(fi, c1.x, ub[4]); ub[5] = fmaf(fi, c1.y, ub[5]);
    ub[6] = fmaf(fi, c1.z, ub[6]); ub[7] = fmaf(fi, c1.w, ub[7]);
  }
  bf16x8 afrag0, afrag1;
#pragma unroll
  for (int j = 0; j < 8; ++j) {
    afrag0[j] = (short)f2bf_rne(fmaxf(ua[j], 0.0f));
    afrag1[j] = (short)f2bf_rne(fmaxf(ub[j], 0.0f));
  }

  float bias[16];
#pragma unroll
  for (int nb = 0; nb < 16; ++nb) bias[nb] = b2[nb * 16 + d];

  const bf16x8* Bp = reinterpret_cast<const bf16x8*>(w2s);
  f32x4 acc[16];
#pragma unroll
  for (int nb = 0; nb < 16; ++nb) {
    f32x4 c; c[0] = bias[nb]; c[1] = bias[nb]; c[2] = bias[nb]; c[3] = bias[nb];
    bf16x8 bf0 = Bp[(nb * 2 + 0) * 64 + l];
    bf16x8 bf1 = Bp[(nb * 2 + 1) * 64 + l];
    c = __builtin_amdgcn_mfma_f32_16x16x32_bf16(afrag0, bf0, c, 0, 0, 0);
    c = __builtin_amdgcn_mfma_f32_16x16x32_bf16(afrag1, bf1, c, 0, 0, 0);
    acc[nb] = c;
  }

  // per-edge scale (reduce across 16 d-lanes of this kg-group)
  float mx[4];
#pragma unroll
  for (int r = 0; r < 4; ++r) {
    float m = 0.0f;
#pragma unroll
    for (int c = 0; c < 16; ++c) m = fmaxf(m, fabsf(acc[c][r]));
    mx[r] = m;
  }
#pragma unroll
  for (int mask = 1; mask < 16; mask <<= 1) {
#pragma unroll
    for (int r = 0; r < 4; ++r) mx[r] = fmaxf(mx[r], __shfl_xor(mx[r], mask));
  }
  uint32 sb[4]; float sinv[4];
#pragma unroll
  for (int r = 0; r < 4; ++r) {
    sb[r] = f2bf_rne(mx[r] * (1.0f / 127.0f));
    float sd = bf2f((unsigned short)sb[r]);
    sinv[r] = (sd > 0.0f) ? (1.0f / sd) : 0.0f;
  }
  if (d == 0) {
    uint32 lo = sb[0] | (sb[1] << 16), hi = sb[2] | (sb[3] << 16);
    *reinterpret_cast<uint2*>(S + (size_t)wid * 16 + kg * 4) = make_uint2(lo, hi);
  }

#pragma unroll
  for (int r = 0; r < 4; ++r) {
    size_t er = (size_t)wid * 16 + kg * 4 + r;
    uint32 p[4];
#pragma unroll
    for (int q = 0; q < 4; ++q) {
      uint32 wv = 0;
#pragma unroll
      for (int b = 0; b < 4; ++b) {
        float qf = fminf(127.0f, fmaxf(-127.0f, rintf(acc[q * 4 + b][r] * sinv[r])));
        wv |= ((uint32)((int)qf & 255)) << (8 * b);
      }
      p[q] = wv;
    }
    uint32x4 pv; pv[0] = p[0]; pv[1] = p[1]; pv[2] = p[2]; pv[3] = p[3];
    __builtin_nontemporal_store(pv,
        reinterpret_cast<uint32x4*>(W + (er << 8) + (d << 4)));
  }
}

// ---------- chunked-bf16 fallback fnet (plan 2) ----------
__device__ __forceinline__ void fnet_layer1(const float* __restrict__ ef, long long e,
                                            const float* __restrict__ w1,
                                            const float* __restrict__ b1,
                                            float* u) {
  float f[13];
#pragma unroll
  for (int i = 0; i < 13; ++i) f[i] = ef[(size_t)e * 13 + i];
#pragma unroll
  for (int k = 0; k < 64; ++k) u[k] = b1[k];
#pragma unroll
  for (int i = 0; i < 13; ++i) {
    float fi = f[i];
#pragma unroll
    for (int k = 0; k < 64; ++k) u[k] = fmaf(fi, w1[i * 64 + k], u[k]);
  }
#pragma unroll
  for (int k = 0; k < 64; ++k) u[k] = fmaxf(u[k], 0.0f);
}

__global__ __launch_bounds__(256) void fnet_bf16_kernel(
    const float* __restrict__ ef, const float* __restrict__ w1, const float* __restrict__ b1,
    const float* __restrict__ w2t, const float* __restrict__ b2,
    unsigned short* __restrict__ W, long long ebase, int ecnt) {
  int t = blockIdx.x * 256 + threadIdx.x;
  if (t >= ecnt) return;
  float u[64];
  fnet_layer1(ef, ebase + t, w1, b1, u);
#pragma unroll 1
  for (int dt = 0; dt < 8; ++dt) {
    uint32 p[16];
#pragma unroll
    for (int dd = 0; dd < 2; ++dd) {
      const int d = dt * 2 + dd;
      const float* wr = w2t + ((size_t)d << 10);
      float acc[16];
#pragma unroll
      for (int c = 0; c < 16; ++c) acc[c] = b2[c * 16 + d];
#pragma unroll
      for (int k = 0; k < 64; ++k) {
        float uk = u[k];
#pragma unroll
        for (int c = 0; c < 16; ++c) acc[c] = fmaf(uk, wr[k * 16 + c], acc[c]);
      }
#pragma unroll
      for (int q = 0; q < 8; ++q) p[dd * 8 + q] = packbf2(acc[2 * q], acc[2 * q + 1]);
    }
    uint4* dp = reinterpret_cast<uint4*>(W + ((size_t)t << 8) + (dt << 5));
    dp[0] = make_uint4(p[0], p[1], p[2], p[3]);
    dp[1] = make_uint4(p[4], p[5], p[6], p[7]);
    dp[2] = make_uint4(p[8], p[9], p[10], p[11]);
    dp[3] = make_uint4(p[12], p[13], p[14], p[15]);
  }
}

// ---------- gconv message + aggregate ----------
__global__ __launch_bounds__(256) void msg_bf16_kernel(
    const float* __restrict__ h, int h_ld,
    const unsigned short* __restrict__ W, long long ebase, int ecnt,
    const int* __restrict__ idxn, const int* __restrict__ edst,
    float* __restrict__ agg) {
  int t = blockIdx.x * 256 + threadIdx.x;
  if (t >= ecnt) return;
  int g = t >> 4, d = t & 15;
  int cur = -1;
  float acc = 0.0f;
  for (int s = 0; s < 16; ++s) {
    int erel = g * 16 + s;
    long long e = ebase + erel;
    int dst = edst[e];
    if (dst != cur) {
      if (cur >= 0) atomicAdd(&agg[(size_t)cur * 16 + d], acc);
      cur = dst; acc = 0.0f;
    }
    int src = idxn[e];
    const float4* hp = reinterpret_cast<const float4*>(h + (size_t)src * h_ld);
    float4 a0 = hp[0], a1 = hp[1], a2 = hp[2], a3 = hp[3];
    const uint4* wp = reinterpret_cast<const uint4*>(W + ((size_t)erel << 8) + (d << 4));
    uint4 w0 = wp[0], w1 = wp[1];
    acc = fmaf(a0.x, blo(w0.x), acc); acc = fmaf(a0.y, bhi(w0.x), acc);
    acc = fmaf(a0.z, blo(w0.y), acc); acc = fmaf(a0.w, bhi(w0.y), acc);
    acc = fmaf(a1.x, blo(w0.z), acc); acc = fmaf(a1.y, bhi(w0.z), acc);
    acc = fmaf(a1.z, blo(w0.w), acc); acc = fmaf(a1.w, bhi(w0.w), acc);
    acc = fmaf(a2.x, blo(w1.x), acc); acc = fmaf(a2.y, bhi(w1.x), acc);
    acc = fmaf(a2.z, blo(w1.y), acc); acc = fmaf(a2.w, bhi(w1.y), acc);
    acc = fmaf(a3.x, blo(w1.z), acc); acc = fmaf(a3.y, bhi(w1.z), acc);
    acc = fmaf(a3.z, blo(w1.w), acc); acc = fmaf(a3.w, bhi(w1.w), acc);
  }
  if (cur >= 0) atomicAdd(&agg[(size_t)cur * 16 + d], acc);
}

// int8 W x bf16 h (L2-resident hdb). 16 lanes per 32-edge group (2 strips).
// edst/idxn for the whole 32-edge group vector-preloaded upfront (8 int4 each)
// so the per-iteration critical path is ONLY the h gather; all 32 gathers can
// be in flight together (R11/R12: msg latency-bound at VALUBusy 22-24%).
__device__ __forceinline__ float edge_dot_i8bf(const uint32x4& h0, const uint32x4& h1,
                                               const uint32x4& wv) {
  float r = 0.0f;
  r = fmaf(blo(h0[0]), sb2f(wv[0], 0), r); r = fmaf(bhi(h0[0]), sb2f(wv[0], 1), r);
  r = fmaf(blo(h0[1]), sb2f(wv[0], 2), r); r = fmaf(bhi(h0[1]), sb2f(wv[0], 3), r);
  r = fmaf(blo(h0[2]), sb2f(wv[1], 0), r); r = fmaf(bhi(h0[2]), sb2f(wv[1], 1), r);
  r = fmaf(blo(h0[3]), sb2f(wv[1], 2), r); r = fmaf(bhi(h0[3]), sb2f(wv[1], 3), r);
  r = fmaf(blo(h1[0]), sb2f(wv[2], 0), r); r = fmaf(bhi(h1[0]), sb2f(wv[2], 1), r);
  r = fmaf(blo(h1[1]), sb2f(wv[2], 2), r); r = fmaf(bhi(h1[1]), sb2f(wv[2], 3), r);
  r = fmaf(blo(h1[2]), sb2f(wv[3], 0), r); r = fmaf(bhi(h1[2]), sb2f(wv[3], 1), r);
  r = fmaf(blo(h1[3]), sb2f(wv[3], 2), r); r = fmaf(bhi(h1[3]), sb2f(wv[3], 3), r);
  return r;
}

#define GET4(v, idx) ((idx) == 0 ? (v).x : (idx) == 1 ? (v).y : (idx) == 2 ? (v).z : (v).w)

__global__ __launch_bounds__(256) void msg_i8_kernel(
    const unsigned short* __restrict__ hdb,
    const unsigned char* __restrict__ W, const unsigned short* __restrict__ S,
    const int* __restrict__ idxn, const int* __restrict__ edst,
    float* __restrict__ agg) {
  int t = blockIdx.x * 256 + threadIdx.x;
  if (t >= NE / 2) return;
  const int g = t >> 4, d = t & 15;
  const int e0 = g * 32;  // strips: A = e0..e0+15, B = e0+16..e0+31

  // vector preload of the group's 32 edge indices (128B each, 128B-aligned)
  int4 dv[8], sv[8];
  const int4* dp4 = reinterpret_cast<const int4*>(edst + e0);
  const int4* sp4 = reinterpret_cast<const int4*>(idxn + e0);
#pragma unroll
  for (int i = 0; i < 8; ++i) { dv[i] = dp4[i]; sv[i] = sp4[i]; }

  int curA = -1, curB = -1;
  float accA = 0.0f, accB = 0.0f;
#pragma unroll
  for (int s = 0; s < 16; ++s) {
    const int q = s >> 2, r4 = s & 3;
    int dstA = GET4(dv[q], r4),     srcA = GET4(sv[q], r4);
    int dstB = GET4(dv[4 + q], r4), srcB = GET4(sv[4 + q], r4);
    int eA = e0 + s, eB = e0 + 16 + s;
    const uint32x4* hpA = reinterpret_cast<const uint32x4*>(hdb + (size_t)srcA * 16);
    const uint32x4* hpB = reinterpret_cast<const uint32x4*>(hdb + (size_t)srcB * 16);
    uint32x4 ha0 = hpA[0], ha1 = hpA[1];
    uint32x4 hb0 = hpB[0], hb1 = hpB[1];
    uint32x4 wvA = *reinterpret_cast<const uint32x4*>(W + ((size_t)eA << 8) + (d << 4));
    uint32x4 wvB = *reinterpret_cast<const uint32x4*>(W + ((size_t)eB << 8) + (d << 4));
    float scA = bf2f(S[eA]), scB = bf2f(S[eB]);
    if (dstA != curA) {
      if (curA >= 0) atomicAdd(&agg[(size_t)curA * 16 + d], accA);
      curA = dstA; accA = 0.0f;
    }
    if (dstB != curB) {
      if (curB >= 0) atomicAdd(&agg[(size_t)curB * 16 + d], accB);
      curB = dstB; accB = 0.0f;
    }
    accA = fmaf(edge_dot_i8bf(ha0, ha1, wvA), scA, accA);
    accB = fmaf(edge_dot_i8bf(hb0, hb1, wvB), scB, accB);
  }
  atomicAdd(&agg[(size_t)curA * 16 + d], accA);
  atomicAdd(&agg[(size_t)curB * 16 + d], accB);
}

// ---------- GRU cell: 16 lanes per node; re-zeroes agg for the next step ----------
__global__ __launch_bounds__(256) void cell_kernel(
    float* agg, const float* __restrict__ invd,
    const float* hin, int hin_ld,
    const float* __restrict__ wih, const float* __restrict__ whh,
    const float* __restrict__ bih, const float* __restrict__ bhh,
    float* hout, int hout_ld,
    const float* sprev, int sprev_ld,
    float* sout, int sout_ld,
    unsigned short* hdn) {
  int t = blockIdx.x * 256 + threadIdx.x;
  int n = t >> 4, j = t & 15;
  if (n >= NN) return;
  float inv = invd[n];
  float x[16], h[16];
  const float4* ap = reinterpret_cast<const float4*>(agg + (size_t)n * 16);
  const float4* hp = reinterpret_cast<const float4*>(hin + (size_t)n * hin_ld);
#pragma unroll
  for (int q = 0; q < 4; ++q) {
    float4 a = ap[q];
    x[4 * q + 0] = a.x * inv; x[4 * q + 1] = a.y * inv;
    x[4 * q + 2] = a.z * inv; x[4 * q + 3] = a.w * inv;
    float4 hv4 = hp[q];
    h[4 * q + 0] = hv4.x; h[4 * q + 1] = hv4.y;
    h[4 * q + 2] = hv4.z; h[4 * q + 3] = hv4.w;
  }
  const float4* wr4 = reinterpret_cast<const float4*>(wih + j * 16);
  const float4* wz4 = reinterpret_cast<const float4*>(wih + (16 + j) * 16);
  const float4* wn4 = reinterpret_cast<const float4*>(wih + (32 + j) * 16);
  const float4* vr4 = reinterpret_cast<const float4*>(whh + j * 16);
  const float4* vz4 = reinterpret_cast<const float4*>(whh + (16 + j) * 16);
  const float4* vn4 = reinterpret_cast<const float4*>(whh + (32 + j) * 16);
  float gr = bih[j], gz = bih[16 + j], gn = bih[32 + j];
  float hr = bhh[j], hz = bhh[16 + j], hn = bhh[32 + j];
#pragma unroll
  for (int q = 0; q < 4; ++q) {
    float4 wr = wr4[q], wz = wz4[q], wn = wn4[q];
    float4 vr = vr4[q], vz = vz4[q], vn = vn4[q];
    gr = fmaf(x[4 * q + 0], wr.x, gr); gr = fmaf(x[4 * q + 1], wr.y, gr);
    gr = fmaf(x[4 * q + 2], wr.z, gr); gr = fmaf(x[4 * q + 3], wr.w, gr);
    gz = fmaf(x[4 * q + 0], wz.x, gz); gz = fmaf(x[4 * q + 1], wz.y, gz);
    gz = fmaf(x[4 * q + 2], wz.z, gz); gz = fmaf(x[4 * q + 3], wz.w, gz);
    gn = fmaf(x[4 * q + 0], wn.x, gn); gn = fmaf(x[4 * q + 1], wn.y, gn);
    gn = fmaf(x[4 * q + 2], wn.z, gn); gn = fmaf(x[4 * q + 3], wn.w, gn);
    hr = fmaf(h[4 * q + 0], vr.x, hr); hr = fmaf(h[4 * q + 1], vr.y, hr);
    hr = fmaf(h[4 * q + 2], vr.z, hr); hr = fmaf(h[4 * q + 3], vr.w, hr);
    hz = fmaf(h[4 * q + 0], vz.x, hz); hz = fmaf(h[4 * q + 1], vz.y, hz);
    hz = fmaf(h[4 * q + 2], vz.z, hz); hz = fmaf(h[4 * q + 3], vz.w, hz);
    hn = fmaf(h[4 * q + 0], vn.x, hn); hn = fmaf(h[4 * q + 1], vn.y, hn);
    hn = fmaf(h[4 * q + 2], vn.z, hn); hn = fmaf(h[4 * q + 3], vn.w, hn);
  }
  float r = 1.0f / (1.0f + expf(-(gr + hr)));
  float z = 1.0f / (1.0f + expf(-(gz + hz)));
  float nng = tanhf(gn + r * hn);
  float hv = (1.0f - z) * nng + z * h[j];

  bool do_s = (sprev != nullptr);
  float sv = 0.0f;
  if (do_s) sv = hv + sprev[(size_t)n * sprev_ld + j];
  hout[(size_t)n * hout_ld + j] = hv;
  if (do_s) sout[(size_t)n * sout_ld + j] = sv;
  if (hdn != nullptr) hdn[(size_t)n * 16 + j] = (unsigned short)f2bf_rne(do_s ? sv : hv);

  // re-zero agg for the next step's atomics (loads above already consumed)
  asm volatile("" ::: "memory");
  agg[(size_t)n * 16 + j] = 0.0f;
}

extern "C" void kernel_launch(void* const* d_in, const int* in_sizes, int n_in,
                              void* d_out, int out_size, void* d_ws, size_t ws_size,
                              hipStream_t stream) {
  const float* hx   = (const float*)d_in[0];
  const float* ef   = (const float*)d_in[1];
  const int*   idxn = (const int*)d_in[2];
  const int*   edst = (const int*)d_in[3];
  const float* w1   = (const float*)d_in[4];
  const float* b1   = (const float*)d_in[5];
  const float* w2   = (const float*)d_in[6];
  const float* b2   = (const float*)d_in[7];
  const float* wih  = (const float*)d_in[8];
  const float* whh  = (const float*)d_in[9];
  const float* bih  = (const float*)d_in[10];
  const float* bhh  = (const float*)d_in[11];
  float* out = (float*)d_out;

  // workspace: invd | agg | w2f/w2t | hdb (bf16 dense h) | W | S
  const size_t INV_OFF = 0;
  const size_t AGG_OFF = 200064;
  const size_t W2T_OFF = 3400192;
  const size_t HD_OFF  = W2T_OFF + 1048576;
  const size_t W_OFF   = HD_OFF + (size_t)NN * 32;  // hdb = 1.6MB
  if (ws_size < W_OFF + 1600 * 512) return;
  char* wsb = (char*)d_ws;
  float* invd = (float*)(wsb + INV_OFF);
  float* agg  = (float*)(wsb + AGG_OFF);
  float* w2t  = (float*)(wsb + W2T_OFF);
  unsigned short* w2f = (unsigned short*)(wsb + W2T_OFF);
  unsigned short* hdb = (unsigned short*)(wsb + HD_OFF);
  unsigned short* W16 = (unsigned short*)(wsb + W_OFF);
  unsigned char*  W8  = (unsigned char*)(wsb + W_OFF);
  unsigned short* S16 = (unsigned short*)(wsb + W_OFF + (size_t)NE * 256);
  size_t wrem = ws_size - W_OFF;

  int plan;       // 1 = int8 + MFMA fnet, 2 = chunked bf16
  size_t chunk = NE;
  if (wrem >= (size_t)NE * 260) plan = 1;
  else {
    plan = 2;
    chunk = (wrem / 512) & ~(size_t)15;
    if (chunk > NE) chunk = NE;
  }

  const int NB  = (NN + 255) / 256;
  const int EB  = (NE + 255) / 256;
  const int MB  = (NE / 2 + 255) / 256;   // msg: 16 lanes per 32 edges
  const int CB  = (NN * 16 + 255) / 256;  // cell: 16 lanes/node

  hipMemsetAsync(invd, 0, (size_t)NN * 4, stream);
  hipMemsetAsync(agg, 0, (size_t)NN * 64, stream);  // once; cell re-zeroes per step
  deg_count_kernel<<<EB, 256, 0, stream>>>(edst, invd);
  deg_inv_kernel<<<NB, 256, 0, stream>>>(invd);
  copy_col0_kernel<<<NB, 256, 0, stream>>>(hx, out);
  hx2hd_kernel<<<CB, 256, 0, stream>>>(hx, hdb);

  if (plan == 1) {
    repack_w2f_kernel<<<64, 256, 0, stream>>>(w2, w2f);
    fnet_mfma_i8_kernel<<<12500, 256, 0, stream>>>(ef, w1, b1, w2f, b2, W8, S16);
  } else {
    repack_w2_kernel<<<1024, 256, 0, stream>>>(w2, w2t);
  }

  auto col = [&](int c) { return out + (size_t)c * 16; };

  auto step = [&](const float* hinF, int hin_ld, float* hout,
                  const float* sprev, float* sout, unsigned short* hdn) {
    if (plan == 1) {
      msg_i8_kernel<<<MB, 256, 0, stream>>>(hdb, W8, S16, idxn, edst, agg);
    } else {
      hipMemsetAsync(agg, 0, (size_t)NN * 64, stream);
      for (size_t e0 = 0; e0 < NE; e0 += chunk) {
        int cnt = (int)(((size_t)NE - e0) < chunk ? ((size_t)NE - e0) : chunk);
        fnet_bf16_kernel<<<(cnt + 255) / 256, 256, 0, stream>>>(ef, w1, b1, w2t, b2, W16,
                                                                (long long)e0, cnt);
        msg_bf16_kernel<<<(cnt + 255) / 256, 256, 0, stream>>>(hinF, hin_ld, W16,
                                                               (long long)e0, cnt,
                                                               idxn, edst, agg);
      }
    }
    cell_kernel<<<CB, 256, 0, stream>>>(agg, invd, hinF, hin_ld, wih, whh, bih, bhh,
                                        hout, OUTC, sprev, OUTC, sout, OUTC, hdn);
  };

  // cols 0..10 = [hx,h1,h2,s1,h4,s2,h6,s3,h8,s4,h10]; col10 = rotating stash for
  // h3/h5/h7/h9. hdb always holds the NEXT step's bf16 msg input (h or s).
  step(hx,      16,  col(1),  nullptr, nullptr, hdb);  // h1
  step(col(1), OUTC, col(2),  nullptr, nullptr, hdb);  // h2
  step(col(2), OUTC, col(10), col(1),  col(3),  hdb);  // h3 stash; s1
  step(col(3), OUTC, col(4),  nullptr, nullptr, hdb);  // h4
  step(col(4), OUTC, col(10), col(10), col(5),  hdb);  // h5 stash; s2
  step(col(5), OUTC, col(6),  nullptr, nullptr, hdb);  // h6
  step(col(6), OUTC, col(10), col(10), col(7),  hdb);  // h7 stash; s3
  step(col(7), OUTC, col(8),  nullptr, nullptr, hdb);  // h8
  step(col(8), OUTC, col(10), col(10), col(9),  hdb);  // h9 stash; s4
  step(col(9), OUTC, col(10), nullptr, nullptr, nullptr);  // h10 (final)
}

// Round 16
// 857.944 us; speedup vs baseline: 3.5136x; 1.0261x over previous
//
#include <hip/hip_runtime.h>

#define NN 50000
#define NE 800000
#define OUTC 176  // 11 * 16

typedef unsigned int uint32;
typedef short bf16x8 __attribute__((ext_vector_type(8)));
typedef float f32x4 __attribute__((ext_vector_type(4)));
typedef unsigned int uint32x4 __attribute__((ext_vector_type(4)));

// ---------- bf16 helpers (manual, RNE) ----------
__device__ __forceinline__ uint32 f2bf_rne(float f) {
  union { float f; uint32 u; } v; v.f = f;
  uint32 u = v.u;
  return (u + 0x7FFFu + ((u >> 16) & 1u)) >> 16;
}
__device__ __forceinline__ uint32 packbf2(float a, float b) {
  return f2bf_rne(a) | (f2bf_rne(b) << 16);
}
__device__ __forceinline__ float blo(uint32 u) {
  union { uint32 x; float f; } t; t.x = u << 16; return t.f;
}
__device__ __forceinline__ float bhi(uint32 u) {
  union { uint32 x; float f; } t; t.x = u & 0xFFFF0000u; return t.f;
}
__device__ __forceinline__ float bf2f(unsigned short v) {
  union { uint32 x; float f; } t; t.x = ((uint32)v) << 16; return t.f;
}
// signed byte b (0..3) of packed word -> float
__device__ __forceinline__ float sb2f(uint32 w, int b) {
  return (float)((int)(w << (24 - 8 * b)) >> 24);
}

// ---------- small kernels ----------
__global__ __launch_bounds__(256) void deg_count_kernel(const int* __restrict__ edst,
                                                        float* __restrict__ deg) {
  int e = blockIdx.x * 256 + threadIdx.x;
  if (e < NE) atomicAdd(&deg[edst[e]], 1.0f);
}

__global__ __launch_bounds__(256) void deg_inv_kernel(float* __restrict__ deg) {
  int n = blockIdx.x * 256 + threadIdx.x;
  if (n < NN) deg[n] = 1.0f / fmaxf(deg[n], 1.0f);
}

__global__ __launch_bounds__(256) void copy_col0_kernel(const float* __restrict__ hx,
                                                        float* __restrict__ out) {
  int n = blockIdx.x * 256 + threadIdx.x;
  if (n >= NN) return;
  const float4* s = reinterpret_cast<const float4*>(hx + (size_t)n * 16);
  float4* d = reinterpret_cast<float4*>(out + (size_t)n * OUTC);
  d[0] = s[0]; d[1] = s[1]; d[2] = s[2]; d[3] = s[3];
}

// hx (dense f32 [NN,16]) -> hdb (bf16) for step-1 msg gather
__global__ __launch_bounds__(256) void hx2hd_kernel(const float* __restrict__ hx,
                                                    unsigned short* __restrict__ hdb) {
  int t = blockIdx.x * 256 + threadIdx.x;
  if (t < NN * 16) hdb[t] = (unsigned short)f2bf_rne(hx[t]);
}

// w2t[d][k][c] = w2[k*256 + c*16 + d]  (for the chunked-bf16 fallback plan)
__global__ __launch_bounds__(256) void repack_w2_kernel(const float* __restrict__ w2,
                                                        float* __restrict__ w2t) {
  int i = blockIdx.x * 256 + threadIdx.x;
  if (i >= 256 * 1024) return;
  int d = i >> 10, r = i & 1023, k = r >> 4, c = r & 15;
  w2t[i] = w2[k * 256 + c * 16 + d];
}

// w2 -> bf16 MFMA B-fragment layout (32 KB)
__global__ __launch_bounds__(256) void repack_w2f_kernel(const float* __restrict__ w2,
                                                         unsigned short* __restrict__ w2f) {
  int i = blockIdx.x * 256 + threadIdx.x;  // 0..16383
  if (i >= 16384) return;
  int jj = i & 7;
  int l = (i >> 3) & 63;
  int nbm = i >> 9;  // nb*2+m
  int m = nbm & 1, nb = nbm >> 1;
  int k = m * 32 + (l >> 4) * 8 + jj;
  int j = nb * 16 + (l & 15);
  w2f[i] = (unsigned short)f2bf_rne(w2[k * 256 + j]);
}

// ---------- MFMA fnet: fused layer1 + 16x256x64 GEMM + int8 quantize ----------
// 512-thread blocks: 8 waves share one 32KB w2s copy -> 4 blocks/CU = 32
// waves/CU (R15: 256-thr blocks capped occupancy at 50%, measured 31%).
__global__ __launch_bounds__(512) void fnet_mfma_i8_kernel(
    const float* __restrict__ ef, const float* __restrict__ w1, const float* __restrict__ b1,
    const unsigned short* __restrict__ w2f, const float* __restrict__ b2,
    unsigned char* __restrict__ W, unsigned short* __restrict__ S) {
  __shared__ float efs[1664];         // 128 edges x 13 feats
  __shared__ short w2s[16384];        // full B fragments, 32KB
  const int wave = threadIdx.x >> 6;  // 0..7
  const int l = threadIdx.x & 63;
  const int wid = blockIdx.x * 8 + wave;
  const int d = l & 15, kg = l >> 4;

#pragma unroll
  for (int i = 0; i < 4; ++i)
    reinterpret_cast<uint4*>(w2s)[threadIdx.x + 512 * i] =
        reinterpret_cast<const uint4*>(w2f)[threadIdx.x + 512 * i];
  long long E0 = (long long)blockIdx.x * 128;
  if (threadIdx.x < 416) {
    reinterpret_cast<float4*>(efs)[threadIdx.x] =
        reinterpret_cast<const float4*>(ef + E0 * 13)[threadIdx.x];
  }
  __syncthreads();

  // ---- layer1 (f from LDS) ----
  const int eloc = wave * 16 + d;
  float f[13];
#pragma unroll
  for (int i = 0; i < 13; ++i) f[i] = efs[eloc * 13 + i];
  float ua[8], ub[8];
#pragma unroll
  for (int j = 0; j < 8; ++j) { ua[j] = b1[kg * 8 + j]; ub[j] = b1[32 + kg * 8 + j]; }
#pragma unroll
  for (int i = 0; i < 13; ++i) {
    const float4* wa = reinterpret_cast<const float4*>(w1 + i * 64 + kg * 8);
    const float4* wb = reinterpret_cast<const float4*>(w1 + i * 64 + 32 + kg * 8);
    float4 a0 = wa[0], a1 = wa[1], c0 = wb[0], c1 = wb[1];
    float fi = f[i];
    ua[0] = fmaf(fi, a0.x, ua[0]); ua[1] = fmaf(fi, a0.y, ua[1]);
    ua[2] = fmaf(fi, a0.z, ua[2]); ua[3] = fmaf(fi, a0.w, ua[3]);
    ua[4] = fmaf(fi, a1.x, ua[4]); ua[5] = fmaf(fi, a1.y, ua[5]);
    ua[6] = fmaf(fi, a1.z, ua[6]); ua[7] = fmaf(fi, a1.w, ua[7]);
    ub[0] = fmaf(fi, c0.x, ub[0]); ub[1] = fmaf(fi, c0.y, ub[1]);
    ub[2] = fmaf(fi, c0.z, ub[2]); ub[3] = fmaf(fi, c0.w, ub[3]);
    ub[4] = fmaf(fi, c1.x, ub[4]); ub[5] = fmaf(fi, c1.y, ub[5]);
    ub[6] = fmaf(fi, c1.z, ub[6]); ub[7] = fmaf(fi, c1.w, ub[7]);
  }
  bf16x8 afrag0, afrag1;
#pragma unroll
  for (int j = 0; j < 8; ++j) {
    afrag0[j] = (short)f2bf_rne(fmaxf(ua[j], 0.0f));
    afrag1[j] = (short)f2bf_rne(fmaxf(ub[j], 0.0f));
  }

  float bias[16];
#pragma unroll
  for (int nb = 0; nb < 16; ++nb) bias[nb] = b2[nb * 16 + d];

  const bf16x8* Bp = reinterpret_cast<const bf16x8*>(w2s);
  f32x4 acc[16];
#pragma unroll
  for (int nb = 0; nb < 16; ++nb) {
    f32x4 c; c[0] = bias[nb]; c[1] = bias[nb]; c[2] = bias[nb]; c[3] = bias[nb];
    bf16x8 bf0 = Bp[(nb * 2 + 0) * 64 + l];
    bf16x8 bf1 = Bp[(nb * 2 + 1) * 64 + l];
    c = __builtin_amdgcn_mfma_f32_16x16x32_bf16(afrag0, bf0, c, 0, 0, 0);
    c = __builtin_amdgcn_mfma_f32_16x16x32_bf16(afrag1, bf1, c, 0, 0, 0);
    acc[nb] = c;
  }

  // per-edge scale (reduce across 16 d-lanes of this kg-group)
  float mx[4];
#pragma unroll
  for (int r = 0; r < 4; ++r) {
    float m = 0.0f;
#pragma unroll
    for (int c = 0; c < 16; ++c) m = fmaxf(m, fabsf(acc[c][r]));
    mx[r] = m;
  }
#pragma unroll
  for (int mask = 1; mask < 16; mask <<= 1) {
#pragma unroll
    for (int r = 0; r < 4; ++r) mx[r] = fmaxf(mx[r], __shfl_xor(mx[r], mask));
  }
  uint32 sb[4]; float sinv[4];
#pragma unroll
  for (int r = 0; r < 4; ++r) {
    sb[r] = f2bf_rne(mx[r] * (1.0f / 127.0f));
    float sd = bf2f((unsigned short)sb[r]);
    sinv[r] = (sd > 0.0f) ? (1.0f / sd) : 0.0f;
  }
  if (d == 0) {
    uint32 lo = sb[0] | (sb[1] << 16), hi = sb[2] | (sb[3] << 16);
    *reinterpret_cast<uint2*>(S + (size_t)wid * 16 + kg * 4) = make_uint2(lo, hi);
  }

#pragma unroll
  for (int r = 0; r < 4; ++r) {
    size_t er = (size_t)wid * 16 + kg * 4 + r;
    uint32 p[4];
#pragma unroll
    for (int q = 0; q < 4; ++q) {
      uint32 wv = 0;
#pragma unroll
      for (int b = 0; b < 4; ++b) {
        float qf = fminf(127.0f, fmaxf(-127.0f, rintf(acc[q * 4 + b][r] * sinv[r])));
        wv |= ((uint32)((int)qf & 255)) << (8 * b);
      }
      p[q] = wv;
    }
    uint32x4 pv; pv[0] = p[0]; pv[1] = p[1]; pv[2] = p[2]; pv[3] = p[3];
    __builtin_nontemporal_store(pv,
        reinterpret_cast<uint32x4*>(W + (er << 8) + (d << 4)));
  }
}

// ---------- chunked-bf16 fallback fnet (plan 2) ----------
__device__ __forceinline__ void fnet_layer1(const float* __restrict__ ef, long long e,
                                            const float* __restrict__ w1,
                                            const float* __restrict__ b1,
                                            float* u) {
  float f[13];
#pragma unroll
  for (int i = 0; i < 13; ++i) f[i] = ef[(size_t)e * 13 + i];
#pragma unroll
  for (int k = 0; k < 64; ++k) u[k] = b1[k];
#pragma unroll
  for (int i = 0; i < 13; ++i) {
    float fi = f[i];
#pragma unroll
    for (int k = 0; k < 64; ++k) u[k] = fmaf(fi, w1[i * 64 + k], u[k]);
  }
#pragma unroll
  for (int k = 0; k < 64; ++k) u[k] = fmaxf(u[k], 0.0f);
}

__global__ __launch_bounds__(256) void fnet_bf16_kernel(
    const float* __restrict__ ef, const float* __restrict__ w1, const float* __restrict__ b1,
    const float* __restrict__ w2t, const float* __restrict__ b2,
    unsigned short* __restrict__ W, long long ebase, int ecnt) {
  int t = blockIdx.x * 256 + threadIdx.x;
  if (t >= ecnt) return;
  float u[64];
  fnet_layer1(ef, ebase + t, w1, b1, u);
#pragma unroll 1
  for (int dt = 0; dt < 8; ++dt) {
    uint32 p[16];
#pragma unroll
    for (int dd = 0; dd < 2; ++dd) {
      const int d = dt * 2 + dd;
      const float* wr = w2t + ((size_t)d << 10);
      float acc[16];
#pragma unroll
      for (int c = 0; c < 16; ++c) acc[c] = b2[c * 16 + d];
#pragma unroll
      for (int k = 0; k < 64; ++k) {
        float uk = u[k];
#pragma unroll
        for (int c = 0; c < 16; ++c) acc[c] = fmaf(uk, wr[k * 16 + c], acc[c]);
      }
#pragma unroll
      for (int q = 0; q < 8; ++q) p[dd * 8 + q] = packbf2(acc[2 * q], acc[2 * q + 1]);
    }
    uint4* dp = reinterpret_cast<uint4*>(W + ((size_t)t << 8) + (dt << 5));
    dp[0] = make_uint4(p[0], p[1], p[2], p[3]);
    dp[1] = make_uint4(p[4], p[5], p[6], p[7]);
    dp[2] = make_uint4(p[8], p[9], p[10], p[11]);
    dp[3] = make_uint4(p[12], p[13], p[14], p[15]);
  }
}

// ---------- gconv message + aggregate ----------
__global__ __launch_bounds__(256) void msg_bf16_kernel(
    const float* __restrict__ h, int h_ld,
    const unsigned short* __restrict__ W, long long ebase, int ecnt,
    const int* __restrict__ idxn, const int* __restrict__ edst,
    float* __restrict__ agg) {
  int t = blockIdx.x * 256 + threadIdx.x;
  if (t >= ecnt) return;
  int g = t >> 4, d = t & 15;
  int cur = -1;
  float acc = 0.0f;
  for (int s = 0; s < 16; ++s) {
    int erel = g * 16 + s;
    long long e = ebase + erel;
    int dst = edst[e];
    if (dst != cur) {
      if (cur >= 0) atomicAdd(&agg[(size_t)cur * 16 + d], acc);
      cur = dst; acc = 0.0f;
    }
    int src = idxn[e];
    const float4* hp = reinterpret_cast<const float4*>(h + (size_t)src * h_ld);
    float4 a0 = hp[0], a1 = hp[1], a2 = hp[2], a3 = hp[3];
    const uint4* wp = reinterpret_cast<const uint4*>(W + ((size_t)erel << 8) + (d << 4));
    uint4 w0 = wp[0], w1 = wp[1];
    acc = fmaf(a0.x, blo(w0.x), acc); acc = fmaf(a0.y, bhi(w0.x), acc);
    acc = fmaf(a0.z, blo(w0.y), acc); acc = fmaf(a0.w, bhi(w0.y), acc);
    acc = fmaf(a1.x, blo(w0.z), acc); acc = fmaf(a1.y, bhi(w0.z), acc);
    acc = fmaf(a1.z, blo(w0.w), acc); acc = fmaf(a1.w, bhi(w0.w), acc);
    acc = fmaf(a2.x, blo(w1.x), acc); acc = fmaf(a2.y, bhi(w1.x), acc);
    acc = fmaf(a2.z, blo(w1.y), acc); acc = fmaf(a2.w, bhi(w1.y), acc);
    acc = fmaf(a3.x, blo(w1.z), acc); acc = fmaf(a3.y, bhi(w1.z), acc);
    acc = fmaf(a3.z, blo(w1.w), acc); acc = fmaf(a3.w, bhi(w1.w), acc);
  }
  if (cur >= 0) atomicAdd(&agg[(size_t)cur * 16 + d], acc);
}

// int8 W x bf16 h (L2-resident hdb). 16 lanes per 32-edge group (2 strips).
// edst/idxn/S for the whole group vector-preloaded upfront -> per-iteration
// critical path is ONLY the h gather; all 32 gathers can overlap.
__device__ __forceinline__ float edge_dot_i8bf(const uint32x4& h0, const uint32x4& h1,
                                               const uint32x4& wv) {
  float r = 0.0f;
  r = fmaf(blo(h0[0]), sb2f(wv[0], 0), r); r = fmaf(bhi(h0[0]), sb2f(wv[0], 1), r);
  r = fmaf(blo(h0[1]), sb2f(wv[0], 2), r); r = fmaf(bhi(h0[1]), sb2f(wv[0], 3), r);
  r = fmaf(blo(h0[2]), sb2f(wv[1], 0), r); r = fmaf(bhi(h0[2]), sb2f(wv[1], 1), r);
  r = fmaf(blo(h0[3]), sb2f(wv[1], 2), r); r = fmaf(bhi(h0[3]), sb2f(wv[1], 3), r);
  r = fmaf(blo(h1[0]), sb2f(wv[2], 0), r); r = fmaf(bhi(h1[0]), sb2f(wv[2], 1), r);
  r = fmaf(blo(h1[1]), sb2f(wv[2], 2), r); r = fmaf(bhi(h1[1]), sb2f(wv[2], 3), r);
  r = fmaf(blo(h1[2]), sb2f(wv[3], 0), r); r = fmaf(bhi(h1[2]), sb2f(wv[3], 1), r);
  r = fmaf(blo(h1[3]), sb2f(wv[3], 2), r); r = fmaf(bhi(h1[3]), sb2f(wv[3], 3), r);
  return r;
}

#define GET4(v, idx) ((idx) == 0 ? (v).x : (idx) == 1 ? (v).y : (idx) == 2 ? (v).z : (v).w)

__global__ __launch_bounds__(256) void msg_i8_kernel(
    const unsigned short* __restrict__ hdb,
    const unsigned char* __restrict__ W, const unsigned short* __restrict__ S,
    const int* __restrict__ idxn, const int* __restrict__ edst,
    float* __restrict__ agg) {
  int t = blockIdx.x * 256 + threadIdx.x;
  if (t >= NE / 2) return;
  const int g = t >> 4, d = t & 15;
  const int e0 = g * 32;  // strips: A = e0..e0+15, B = e0+16..e0+31

  // vector preload of the group's 32 edge indices + 32 scales
  int4 dv[8], sv[8];
  const int4* dp4 = reinterpret_cast<const int4*>(edst + e0);
  const int4* sp4 = reinterpret_cast<const int4*>(idxn + e0);
#pragma unroll
  for (int i = 0; i < 8; ++i) { dv[i] = dp4[i]; sv[i] = sp4[i]; }
  uint32x4 scv[4];
  const uint32x4* scp = reinterpret_cast<const uint32x4*>(S + e0);
#pragma unroll
  for (int i = 0; i < 4; ++i) scv[i] = scp[i];

  int curA = -1, curB = -1;
  float accA = 0.0f, accB = 0.0f;
#pragma unroll
  for (int s = 0; s < 16; ++s) {
    const int q = s >> 2, r4 = s & 3;
    int dstA = GET4(dv[q], r4),     srcA = GET4(sv[q], r4);
    int dstB = GET4(dv[4 + q], r4), srcB = GET4(sv[4 + q], r4);
    int eA = e0 + s, eB = e0 + 16 + s;
    const uint32x4* hpA = reinterpret_cast<const uint32x4*>(hdb + (size_t)srcA * 16);
    const uint32x4* hpB = reinterpret_cast<const uint32x4*>(hdb + (size_t)srcB * 16);
    uint32x4 ha0 = hpA[0], ha1 = hpA[1];
    uint32x4 hb0 = hpB[0], hb1 = hpB[1];
    uint32x4 wvA = *reinterpret_cast<const uint32x4*>(W + ((size_t)eA << 8) + (d << 4));
    uint32x4 wvB = *reinterpret_cast<const uint32x4*>(W + ((size_t)eB << 8) + (d << 4));
    // scales: word w = s>>1 (A) / 8+(s>>1) (B); half = s&1 (compile-time)
    uint32 swA = scv[s >> 3][(s >> 1) & 3];
    uint32 swB = scv[2 + (s >> 3)][(s >> 1) & 3];
    float scA = bf2f((unsigned short)((s & 1) ? (swA >> 16) : (swA & 0xFFFF)));
    float scB = bf2f((unsigned short)((s & 1) ? (swB >> 16) : (swB & 0xFFFF)));
    if (dstA != curA) {
      if (curA >= 0) atomicAdd(&agg[(size_t)curA * 16 + d], accA);
      curA = dstA; accA = 0.0f;
    }
    if (dstB != curB) {
      if (curB >= 0) atomicAdd(&agg[(size_t)curB * 16 + d], accB);
      curB = dstB; accB = 0.0f;
    }
    accA = fmaf(edge_dot_i8bf(ha0, ha1, wvA), scA, accA);
    accB = fmaf(edge_dot_i8bf(hb0, hb1, wvB), scB, accB);
  }
  atomicAdd(&agg[(size_t)curA * 16 + d], accA);
  atomicAdd(&agg[(size_t)curB * 16 + d], accB);
}

// ---------- GRU cell: 16 lanes per node; re-zeroes agg for the next step ----------
__global__ __launch_bounds__(256) void cell_kernel(
    float* agg, const float* __restrict__ invd,
    const float* hin, int hin_ld,
    const float* __restrict__ wih, const float* __restrict__ whh,
    const float* __restrict__ bih, const float* __restrict__ bhh,
    float* hout, int hout_ld,
    const float* sprev, int sprev_ld,
    float* sout, int sout_ld,
    unsigned short* hdn) {
  int t = blockIdx.x * 256 + threadIdx.x;
  int n = t >> 4, j = t & 15;
  if (n >= NN) return;
  float inv = invd[n];
  float x[16], h[16];
  const float4* ap = reinterpret_cast<const float4*>(agg + (size_t)n * 16);
  const float4* hp = reinterpret_cast<const float4*>(hin + (size_t)n * hin_ld);
#pragma unroll
  for (int q = 0; q < 4; ++q) {
    float4 a = ap[q];
    x[4 * q + 0] = a.x * inv; x[4 * q + 1] = a.y * inv;
    x[4 * q + 2] = a.z * inv; x[4 * q + 3] = a.w * inv;
    float4 hv4 = hp[q];
    h[4 * q + 0] = hv4.x; h[4 * q + 1] = hv4.y;
    h[4 * q + 2] = hv4.z; h[4 * q + 3] = hv4.w;
  }
  const float4* wr4 = reinterpret_cast<const float4*>(wih + j * 16);
  const float4* wz4 = reinterpret_cast<const float4*>(wih + (16 + j) * 16);
  const float4* wn4 = reinterpret_cast<const float4*>(wih + (32 + j) * 16);
  const float4* vr4 = reinterpret_cast<const float4*>(whh + j * 16);
  const float4* vz4 = reinterpret_cast<const float4*>(whh + (16 + j) * 16);
  const float4* vn4 = reinterpret_cast<const float4*>(whh + (32 + j) * 16);
  float gr = bih[j], gz = bih[16 + j], gn = bih[32 + j];
  float hr = bhh[j], hz = bhh[16 + j], hn = bhh[32 + j];
#pragma unroll
  for (int q = 0; q < 4; ++q) {
    float4 wr = wr4[q], wz = wz4[q], wn = wn4[q];
    float4 vr = vr4[q], vz = vz4[q], vn = vn4[q];
    gr = fmaf(x[4 * q + 0], wr.x, gr); gr = fmaf(x[4 * q + 1], wr.y, gr);
    gr = fmaf(x[4 * q + 2], wr.z, gr); gr = fmaf(x[4 * q + 3], wr.w, gr);
    gz = fmaf(x[4 * q + 0], wz.x, gz); gz = fmaf(x[4 * q + 1], wz.y, gz);
    gz = fmaf(x[4 * q + 2], wz.z, gz); gz = fmaf(x[4 * q + 3], wz.w, gz);
    gn = fmaf(x[4 * q + 0], wn.x, gn); gn = fmaf(x[4 * q + 1], wn.y, gn);
    gn = fmaf(x[4 * q + 2], wn.z, gn); gn = fmaf(x[4 * q + 3], wn.w, gn);
    hr = fmaf(h[4 * q + 0], vr.x, hr); hr = fmaf(h[4 * q + 1], vr.y, hr);
    hr = fmaf(h[4 * q + 2], vr.z, hr); hr = fmaf(h[4 * q + 3], vr.w, hr);
    hz = fmaf(h[4 * q + 0], vz.x, hz); hz = fmaf(h[4 * q + 1], vz.y, hz);
    hz = fmaf(h[4 * q + 2], vz.z, hz); hz = fmaf(h[4 * q + 3], vz.w, hz);
    hn = fmaf(h[4 * q + 0], vn.x, hn); hn = fmaf(h[4 * q + 1], vn.y, hn);
    hn = fmaf(h[4 * q + 2], vn.z, hn); hn = fmaf(h[4 * q + 3], vn.w, hn);
  }
  float r = 1.0f / (1.0f + expf(-(gr + hr)));
  float z = 1.0f / (1.0f + expf(-(gz + hz)));
  float nng = tanhf(gn + r * hn);
  float hv = (1.0f - z) * nng + z * h[j];

  bool do_s = (sprev != nullptr);
  float sv = 0.0f;
  if (do_s) sv = hv + sprev[(size_t)n * sprev_ld + j];
  hout[(size_t)n * hout_ld + j] = hv;
  if (do_s) sout[(size_t)n * sout_ld + j] = sv;
  if (hdn != nullptr) hdn[(size_t)n * 16 + j] = (unsigned short)f2bf_rne(do_s ? sv : hv);

  // re-zero agg for the next step's atomics (loads above already consumed)
  asm volatile("" ::: "memory");
  agg[(size_t)n * 16 + j] = 0.0f;
}

extern "C" void kernel_launch(void* const* d_in, const int* in_sizes, int n_in,
                              void* d_out, int out_size, void* d_ws, size_t ws_size,
                              hipStream_t stream) {
  const float* hx   = (const float*)d_in[0];
  const float* ef   = (const float*)d_in[1];
  const int*   idxn = (const int*)d_in[2];
  const int*   edst = (const int*)d_in[3];
  const float* w1   = (const float*)d_in[4];
  const float* b1   = (const float*)d_in[5];
  const float* w2   = (const float*)d_in[6];
  const float* b2   = (const float*)d_in[7];
  const float* wih  = (const float*)d_in[8];
  const float* whh  = (const float*)d_in[9];
  const float* bih  = (const float*)d_in[10];
  const float* bhh  = (const float*)d_in[11];
  float* out = (float*)d_out;

  // workspace: invd | agg | w2f/w2t | hdb (bf16 dense h) | W | S
  const size_t INV_OFF = 0;
  const size_t AGG_OFF = 200064;
  const size_t W2T_OFF = 3400192;
  const size_t HD_OFF  = W2T_OFF + 1048576;
  const size_t W_OFF   = HD_OFF + (size_t)NN * 32;  // hdb = 1.6MB
  if (ws_size < W_OFF + 1600 * 512) return;
  char* wsb = (char*)d_ws;
  float* invd = (float*)(wsb + INV_OFF);
  float* agg  = (float*)(wsb + AGG_OFF);
  float* w2t  = (float*)(wsb + W2T_OFF);
  unsigned short* w2f = (unsigned short*)(wsb + W2T_OFF);
  unsigned short* hdb = (unsigned short*)(wsb + HD_OFF);
  unsigned short* W16 = (unsigned short*)(wsb + W_OFF);
  unsigned char*  W8  = (unsigned char*)(wsb + W_OFF);
  unsigned short* S16 = (unsigned short*)(wsb + W_OFF + (size_t)NE * 256);
  size_t wrem = ws_size - W_OFF;

  int plan;       // 1 = int8 + MFMA fnet, 2 = chunked bf16
  size_t chunk = NE;
  if (wrem >= (size_t)NE * 260) plan = 1;
  else {
    plan = 2;
    chunk = (wrem / 512) & ~(size_t)15;
    if (chunk > NE) chunk = NE;
  }

  const int NB  = (NN + 255) / 256;
  const int EB  = (NE + 255) / 256;
  const int MB  = (NE / 2 + 255) / 256;   // msg: 16 lanes per 32 edges
  const int CB  = (NN * 16 + 255) / 256;  // cell: 16 lanes/node

  hipMemsetAsync(invd, 0, (size_t)NN * 4, stream);
  hipMemsetAsync(agg, 0, (size_t)NN * 64, stream);  // once; cell re-zeroes per step
  deg_count_kernel<<<EB, 256, 0, stream>>>(edst, invd);
  deg_inv_kernel<<<NB, 256, 0, stream>>>(invd);
  copy_col0_kernel<<<NB, 256, 0, stream>>>(hx, out);
  hx2hd_kernel<<<CB, 256, 0, stream>>>(hx, hdb);

  if (plan == 1) {
    repack_w2f_kernel<<<64, 256, 0, stream>>>(w2, w2f);
    fnet_mfma_i8_kernel<<<6250, 512, 0, stream>>>(ef, w1, b1, w2f, b2, W8, S16);
  } else {
    repack_w2_kernel<<<1024, 256, 0, stream>>>(w2, w2t);
  }

  auto col = [&](int c) { return out + (size_t)c * 16; };

  auto step = [&](const float* hinF, int hin_ld, float* hout,
                  const float* sprev, float* sout, unsigned short* hdn) {
    if (plan == 1) {
      msg_i8_kernel<<<MB, 256, 0, stream>>>(hdb, W8, S16, idxn, edst, agg);
    } else {
      hipMemsetAsync(agg, 0, (size_t)NN * 64, stream);
      for (size_t e0 = 0; e0 < NE; e0 += chunk) {
        int cnt = (int)(((size_t)NE - e0) < chunk ? ((size_t)NE - e0) : chunk);
        fnet_bf16_kernel<<<(cnt + 255) / 256, 256, 0, stream>>>(ef, w1, b1, w2t, b2, W16,
                                                                (long long)e0, cnt);
        msg_bf16_kernel<<<(cnt + 255) / 256, 256, 0, stream>>>(hinF, hin_ld, W16,
                                                               (long long)e0, cnt,
                                                               idxn, edst, agg);
      }
    }
    cell_kernel<<<CB, 256, 0, stream>>>(agg, invd, hinF, hin_ld, wih, whh, bih, bhh,
                                        hout, OUTC, sprev, OUTC, sout, OUTC, hdn);
  };

  // cols 0..10 = [hx,h1,h2,s1,h4,s2,h6,s3,h8,s4,h10]; col10 = rotating stash for
  // h3/h5/h7/h9. hdb always holds the NEXT step's bf16 msg input (h or s).
  step(hx,      16,  col(1),  nullptr, nullptr, hdb);  // h1
  step(col(1), OUTC, col(2),  nullptr, nullptr, hdb);  // h2
  step(col(2), OUTC, col(10), col(1),  col(3),  hdb);  // h3 stash; s1
  step(col(3), OUTC, col(4),  nullptr, nullptr, hdb);  // h4
  step(col(4), OUTC, col(10), col(10), col(5),  hdb);  // h5 stash; s2
  step(col(5), OUTC, col(6),  nullptr, nullptr, hdb);  // h6
  step(col(6), OUTC, col(10), col(10), col(7),  hdb);  // h7 stash; s3
  step(col(7), OUTC, col(8),  nullptr, nullptr, hdb);  // h8
  step(col(8), OUTC, col(10), col(10), col(9),  hdb);  // h9 stash; s4
  step(col(9), OUTC, col(10), nullptr, nullptr, nullptr);  // h10 (final)
}